// Round 1
// baseline (1171.235 us; speedup 1.0000x reference)
//
#include <hip/hip_runtime.h>
#include <math.h>

// Shapes (fixed)
#define S_  2048
#define B_  2
#define D_  512
#define H_  8
#define DH_ 64
#define E_  8
#define F_  1024
#define N_  4096   // S_*B_
#define NPAIR_ 8192 // N_*TOPK

// ---------------------------------------------------------------------------
// Shared 64x64x16 f32 tile GEMM core. 256 threads, 4x4 micro-tile.
// As stored transposed [k][m], Bs [k][n], leading dim 68 (float4-aligned pad).
// ---------------------------------------------------------------------------
__device__ __forceinline__ void mm_step(const float (*As)[68], const float (*Bs)[68],
                                        int g, int xx, float acc[4][4]) {
#pragma unroll
  for (int kk = 0; kk < 16; ++kk) {
    float4 a4 = *(const float4*)&As[kk][4 * g];
    float4 b4 = *(const float4*)&Bs[kk][4 * xx];
    float a[4] = {a4.x, a4.y, a4.z, a4.w};
    float b[4] = {b4.x, b4.y, b4.z, b4.w};
#pragma unroll
    for (int i = 0; i < 4; ++i)
#pragma unroll
      for (int j = 0; j < 4; ++j)
        acc[i][j] += a[i] * b[j];
  }
}

// C[M,N] = A[M,K] @ W[K,N] + bias.  M multiple of 64, N multiple of 64, K mult of 16.
__global__ __launch_bounds__(256) void gemm_bias(const float* __restrict__ A,
                                                 const float* __restrict__ W,
                                                 const float* __restrict__ bias,
                                                 float* __restrict__ C,
                                                 int M, int Nn, int K) {
  __shared__ __align__(16) float As[16][68];
  __shared__ __align__(16) float Bs[16][68];
  int tid = threadIdx.x;
  int m0 = blockIdx.x * 64, n0 = blockIdx.y * 64;
  int g = tid >> 4, xx = tid & 15;
  int la_r = tid >> 2, la_k = (tid & 3) * 4;
  int lb_k = tid >> 4, lb_n = (tid & 15) * 4;
  float acc[4][4] = {};
  for (int k0 = 0; k0 < K; k0 += 16) {
    float4 av = *(const float4*)&A[(size_t)(m0 + la_r) * K + k0 + la_k];
    float4 bv = *(const float4*)&W[(size_t)(k0 + lb_k) * Nn + n0 + lb_n];
    __syncthreads();
    As[la_k + 0][la_r] = av.x; As[la_k + 1][la_r] = av.y;
    As[la_k + 2][la_r] = av.z; As[la_k + 3][la_r] = av.w;
    *(float4*)&Bs[lb_k][lb_n] = bv;
    __syncthreads();
    mm_step(As, Bs, g, xx, acc);
  }
#pragma unroll
  for (int i = 0; i < 4; ++i) {
    int m = m0 + 4 * g + i;
    int n = n0 + 4 * xx;
    float4 o;
    o.x = acc[i][0] + bias[n + 0];
    o.y = acc[i][1] + bias[n + 1];
    o.z = acc[i][2] + bias[n + 2];
    o.w = acc[i][3] + bias[n + 3];
    *(float4*)&C[(size_t)m * Nn + n] = o;
  }
}

// ---------------------------------------------------------------------------
// RoPE in-place on q and k buffers, layout (S,B,H,DH) flattened rows n=s*B+b.
// ---------------------------------------------------------------------------
__global__ __launch_bounds__(256) void rope_k(float* __restrict__ q, float* __restrict__ k,
                                              const float* __restrict__ cosb,
                                              const float* __restrict__ sinb) {
  int idx = blockIdx.x * 256 + threadIdx.x;   // 2^21 total
  int tsel = idx >> 20;
  int r = idx & ((1 << 20) - 1);
  int n = r >> 8;           // token row
  int h = (r >> 5) & 7;
  int d0 = r & 31;
  int s = n >> 1;           // n = s*B + b, B=2
  size_t base = (size_t)n * D_ + h * DH_ + d0;
  float c = cosb[s * DH_ + d0];
  float sn = sinb[s * DH_ + d0];
  float* buf = tsel ? k : q;
  float a = buf[base], b = buf[base + 32];
  buf[base]      = a * c - b * sn;
  buf[base + 32] = b * c + a * sn;
}

// ---------------------------------------------------------------------------
// Flash attention: block = (q-tile of 64) x (b,h). 256 threads.
// rows per thread: 4g..4g+3 ; cols/dims per thread: xx+16j (conflict-free).
// ---------------------------------------------------------------------------
__global__ __launch_bounds__(256) void attn_flash(const float* __restrict__ q,
                                                  const float* __restrict__ k,
                                                  const float* __restrict__ v,
                                                  float* __restrict__ ctx) {
  __shared__ __align__(16) float Qs[64][68];
  __shared__ __align__(16) float Ks[64][68];
  __shared__ __align__(16) float Vs[64][68];
  __shared__ __align__(16) float Ps[64][68];
  int tid = threadIdx.x;
  int qt = blockIdx.x, bh = blockIdx.y;
  int b = bh >> 3, h = bh & 7;
  int g = tid >> 4, xx = tid & 15;
  float m_run[4], l_run[4], acc[4][4];
#pragma unroll
  for (int i = 0; i < 4; ++i) {
    m_run[i] = -1e30f; l_run[i] = 0.f;
#pragma unroll
    for (int j = 0; j < 4; ++j) acc[i][j] = 0.f;
  }
#pragma unroll
  for (int i = 0; i < 16; ++i) {
    int idx = tid + i * 256, r = idx >> 6, d = idx & 63;
    int s = qt * 64 + r;
    Qs[r][d] = q[(size_t)(s * 2 + b) * D_ + h * DH_ + d] * 0.125f;  // 1/sqrt(64)
  }
  for (int t0 = 0; t0 < S_; t0 += 64) {
    __syncthreads();
#pragma unroll
    for (int i = 0; i < 16; ++i) {
      int idx = tid + i * 256, r = idx >> 6, d = idx & 63;
      size_t ga = (size_t)((t0 + r) * 2 + b) * D_ + h * DH_ + d;
      Ks[r][d] = k[ga];
      Vs[r][d] = v[ga];
    }
    __syncthreads();
    float sc[4][4] = {};
#pragma unroll
    for (int d4 = 0; d4 < 16; ++d4) {
      float qa[4][4], ka[4][4];
#pragma unroll
      for (int i = 0; i < 4; ++i) {
        float4 t = *(const float4*)&Qs[4 * g + i][4 * d4];
        qa[i][0] = t.x; qa[i][1] = t.y; qa[i][2] = t.z; qa[i][3] = t.w;
      }
#pragma unroll
      for (int j = 0; j < 4; ++j) {
        float4 t = *(const float4*)&Ks[xx + 16 * j][4 * d4];
        ka[j][0] = t.x; ka[j][1] = t.y; ka[j][2] = t.z; ka[j][3] = t.w;
      }
#pragma unroll
      for (int i = 0; i < 4; ++i)
#pragma unroll
        for (int j = 0; j < 4; ++j)
#pragma unroll
          for (int d = 0; d < 4; ++d)
            sc[i][j] += qa[i][d] * ka[j][d];
    }
    // online softmax
#pragma unroll
    for (int i = 0; i < 4; ++i) {
      float tm = fmaxf(fmaxf(sc[i][0], sc[i][1]), fmaxf(sc[i][2], sc[i][3]));
      tm = fmaxf(tm, __shfl_xor(tm, 1));
      tm = fmaxf(tm, __shfl_xor(tm, 2));
      tm = fmaxf(tm, __shfl_xor(tm, 4));
      tm = fmaxf(tm, __shfl_xor(tm, 8));
      float mn = fmaxf(m_run[i], tm);
      float corr = __expf(m_run[i] - mn);
      m_run[i] = mn;
      float pr[4], ts = 0.f;
#pragma unroll
      for (int j = 0; j < 4; ++j) { pr[j] = __expf(sc[i][j] - mn); ts += pr[j]; }
      ts += __shfl_xor(ts, 1);
      ts += __shfl_xor(ts, 2);
      ts += __shfl_xor(ts, 4);
      ts += __shfl_xor(ts, 8);
      l_run[i] = l_run[i] * corr + ts;
#pragma unroll
      for (int j = 0; j < 4; ++j) acc[i][j] *= corr;
#pragma unroll
      for (int j = 0; j < 4; ++j) Ps[4 * g + i][xx + 16 * j] = pr[j];
    }
    __syncthreads();
    // PV accumulate
#pragma unroll
    for (int c4 = 0; c4 < 16; ++c4) {
      float pa[4][4];
#pragma unroll
      for (int i = 0; i < 4; ++i) {
        float4 t = *(const float4*)&Ps[4 * g + i][4 * c4];
        pa[i][0] = t.x; pa[i][1] = t.y; pa[i][2] = t.z; pa[i][3] = t.w;
      }
#pragma unroll
      for (int cc = 0; cc < 4; ++cc) {
        float vv[4];
#pragma unroll
        for (int j = 0; j < 4; ++j) vv[j] = Vs[4 * c4 + cc][xx + 16 * j];
#pragma unroll
        for (int i = 0; i < 4; ++i)
#pragma unroll
          for (int j = 0; j < 4; ++j)
            acc[i][j] += pa[i][cc] * vv[j];
      }
    }
  }
#pragma unroll
  for (int i = 0; i < 4; ++i) {
    float inv = 1.f / l_run[i];
    int s = qt * 64 + 4 * g + i;
#pragma unroll
    for (int j = 0; j < 4; ++j)
      ctx[(size_t)(s * 2 + b) * D_ + h * DH_ + xx + 16 * j] = acc[i][j] * inv;
  }
}

// ---------------------------------------------------------------------------
// LayerNorm with residual: out = LN(a + b), one wave per row.
// ---------------------------------------------------------------------------
__global__ __launch_bounds__(256) void ln_res(const float* __restrict__ a,
                                              const float* __restrict__ b,
                                              const float* __restrict__ g,
                                              const float* __restrict__ beta,
                                              float* __restrict__ out) {
  int n = blockIdx.x * 4 + (threadIdx.x >> 6);
  int lane = threadIdx.x & 63;
  float v[8];
  float s = 0.f;
#pragma unroll
  for (int i = 0; i < 8; ++i) {
    int d = lane + 64 * i;
    v[i] = a[(size_t)n * D_ + d] + b[(size_t)n * D_ + d];
    s += v[i];
  }
#pragma unroll
  for (int m = 32; m; m >>= 1) s += __shfl_xor(s, m);
  float mean = s * (1.f / D_);
  float s2 = 0.f;
#pragma unroll
  for (int i = 0; i < 8; ++i) { float t = v[i] - mean; s2 += t * t; }
#pragma unroll
  for (int m = 32; m; m >>= 1) s2 += __shfl_xor(s2, m);
  float r = rsqrtf(s2 * (1.f / D_) + 1e-5f);
#pragma unroll
  for (int i = 0; i < 8; ++i) {
    int d = lane + 64 * i;
    out[(size_t)n * D_ + d] = (v[i] - mean) * r * g[d] + beta[d];
  }
}

// Final: out = LN(x + mp[2n] + mp[2n+1])
__global__ __launch_bounds__(256) void ln2_final(const float* __restrict__ x,
                                                 const float* __restrict__ mp,
                                                 const float* __restrict__ g,
                                                 const float* __restrict__ beta,
                                                 float* __restrict__ out) {
  int n = blockIdx.x * 4 + (threadIdx.x >> 6);
  int lane = threadIdx.x & 63;
  float v[8];
  float s = 0.f;
#pragma unroll
  for (int i = 0; i < 8; ++i) {
    int d = lane + 64 * i;
    v[i] = x[(size_t)n * D_ + d] + mp[(size_t)(2 * n) * D_ + d] + mp[(size_t)(2 * n + 1) * D_ + d];
    s += v[i];
  }
#pragma unroll
  for (int m = 32; m; m >>= 1) s += __shfl_xor(s, m);
  float mean = s * (1.f / D_);
  float s2 = 0.f;
#pragma unroll
  for (int i = 0; i < 8; ++i) { float t = v[i] - mean; s2 += t * t; }
#pragma unroll
  for (int m = 32; m; m >>= 1) s2 += __shfl_xor(s2, m);
  float r = rsqrtf(s2 * (1.f / D_) + 1e-5f);
#pragma unroll
  for (int i = 0; i < 8; ++i) {
    int d = lane + 64 * i;
    out[(size_t)n * D_ + d] = (v[i] - mean) * r * g[d] + beta[d];
  }
}

// ---------------------------------------------------------------------------
// Gate + top-2 routing. One wave per token.
// list entry = pair id p = n*2 + k ; gp[p] = normalized gate weight.
// ---------------------------------------------------------------------------
__global__ __launch_bounds__(256) void gate_route(const float* __restrict__ x,
                                                  const float* __restrict__ Wg,
                                                  float* __restrict__ gp,
                                                  int* __restrict__ cnt,
                                                  int* __restrict__ lst) {
  int n = blockIdx.x * 4 + (threadIdx.x >> 6);
  int lane = threadIdx.x & 63;
  float p[E_] = {};
  for (int d = lane; d < D_; d += 64) {
    float xv = x[(size_t)n * D_ + d];
    const float* wr = &Wg[(size_t)d * E_];
#pragma unroll
    for (int e = 0; e < E_; ++e) p[e] += xv * wr[e];
  }
#pragma unroll
  for (int e = 0; e < E_; ++e)
#pragma unroll
    for (int m = 32; m; m >>= 1) p[e] += __shfl_xor(p[e], m);
  if (lane == 0) {
    float mx = p[0];
#pragma unroll
    for (int e = 1; e < E_; ++e) mx = fmaxf(mx, p[e]);
    float q[E_];
#pragma unroll
    for (int e = 0; e < E_; ++e) q[e] = expf(p[e] - mx);
    int e1 = 0;
#pragma unroll
    for (int e = 1; e < E_; ++e) if (q[e] > q[e1]) e1 = e;
    int e2 = (e1 == 0) ? 1 : 0;
#pragma unroll
    for (int e = 0; e < E_; ++e) if (e != e1 && q[e] > q[e2]) e2 = e;
    float denom = q[e1] + q[e2];
    float w1 = q[e1] / denom, w2 = q[e2] / denom;
    int s1 = atomicAdd(&cnt[e1], 1);
    lst[e1 * N_ + s1] = n * 2;
    int s2 = atomicAdd(&cnt[e2], 1);
    lst[e2 * N_ + s2] = n * 2 + 1;
    gp[n * 2] = w1;
    gp[n * 2 + 1] = w2;
  }
}

// ---------------------------------------------------------------------------
// MoE stage A: h[off(e)+i, :] = relu(x[tok(i)] @ W1[e] + B1[e]) for i < cnt[e]
// ---------------------------------------------------------------------------
__global__ __launch_bounds__(256) void moe_gemm1(const float* __restrict__ x,
                                                 const float* __restrict__ W1,
                                                 const float* __restrict__ B1,
                                                 float* __restrict__ hbuf,
                                                 const int* __restrict__ cnt,
                                                 const int* __restrict__ lst) {
  int e = blockIdx.z;
  int c = cnt[e];
  int m0 = blockIdx.x * 64;
  if (m0 >= c) return;
  int off = 0;
#pragma unroll
  for (int i = 0; i < E_; ++i) if (i < e) off += cnt[i];
  int n0 = blockIdx.y * 64;
  __shared__ __align__(16) float As[16][68];
  __shared__ __align__(16) float Bs[16][68];
  int tid = threadIdx.x;
  int g = tid >> 4, xx = tid & 15;
  int la_r = tid >> 2, la_k = (tid & 3) * 4;
  int lb_k = tid >> 4, lb_n = (tid & 15) * 4;
  int arow = m0 + la_r;
  const float* Aptr = (arow < c) ? &x[(size_t)(lst[e * N_ + arow] >> 1) * D_] : nullptr;
  const float* Wb = &W1[(size_t)e * D_ * F_];
  float acc[4][4] = {};
  for (int k0 = 0; k0 < D_; k0 += 16) {
    float4 av = make_float4(0.f, 0.f, 0.f, 0.f);
    if (Aptr) av = *(const float4*)&Aptr[k0 + la_k];
    float4 bv = *(const float4*)&Wb[(size_t)(k0 + lb_k) * F_ + n0 + lb_n];
    __syncthreads();
    As[la_k + 0][la_r] = av.x; As[la_k + 1][la_r] = av.y;
    As[la_k + 2][la_r] = av.z; As[la_k + 3][la_r] = av.w;
    *(float4*)&Bs[lb_k][lb_n] = bv;
    __syncthreads();
    mm_step(As, Bs, g, xx, acc);
  }
#pragma unroll
  for (int i = 0; i < 4; ++i) {
    int r = m0 + 4 * g + i;
    if (r < c) {
      int n = n0 + 4 * xx;
      float4 o;
      o.x = fmaxf(acc[i][0] + B1[e * F_ + n + 0], 0.f);
      o.y = fmaxf(acc[i][1] + B1[e * F_ + n + 1], 0.f);
      o.z = fmaxf(acc[i][2] + B1[e * F_ + n + 2], 0.f);
      o.w = fmaxf(acc[i][3] + B1[e * F_ + n + 3], 0.f);
      *(float4*)&hbuf[(size_t)(off + r) * F_ + n] = o;
    }
  }
}

// ---------------------------------------------------------------------------
// MoE stage B: mp[p, :] = gp[p] * (h[off(e)+i] @ W2[e] + B2[e]),  p = lst[e][i]
// ---------------------------------------------------------------------------
__global__ __launch_bounds__(256) void moe_gemm2(const float* __restrict__ hbuf,
                                                 const float* __restrict__ W2,
                                                 const float* __restrict__ B2,
                                                 const float* __restrict__ gp,
                                                 float* __restrict__ mp,
                                                 const int* __restrict__ cnt,
                                                 const int* __restrict__ lst) {
  int e = blockIdx.z;
  int c = cnt[e];
  int m0 = blockIdx.x * 64;
  if (m0 >= c) return;
  int off = 0;
#pragma unroll
  for (int i = 0; i < E_; ++i) if (i < e) off += cnt[i];
  int n0 = blockIdx.y * 64;
  __shared__ __align__(16) float As[16][68];
  __shared__ __align__(16) float Bs[16][68];
  int tid = threadIdx.x;
  int g = tid >> 4, xx = tid & 15;
  int la_r = tid >> 2, la_k = (tid & 3) * 4;
  int lb_k = tid >> 4, lb_n = (tid & 15) * 4;
  int arow = m0 + la_r;
  const float* Aptr = (arow < c) ? &hbuf[(size_t)(off + arow) * F_] : nullptr;
  const float* Wb = &W2[(size_t)e * F_ * D_];
  float acc[4][4] = {};
  for (int k0 = 0; k0 < F_; k0 += 16) {
    float4 av = make_float4(0.f, 0.f, 0.f, 0.f);
    if (Aptr) av = *(const float4*)&Aptr[k0 + la_k];
    float4 bv = *(const float4*)&Wb[(size_t)(k0 + lb_k) * D_ + n0 + lb_n];
    __syncthreads();
    As[la_k + 0][la_r] = av.x; As[la_k + 1][la_r] = av.y;
    As[la_k + 2][la_r] = av.z; As[la_k + 3][la_r] = av.w;
    *(float4*)&Bs[lb_k][lb_n] = bv;
    __syncthreads();
    mm_step(As, Bs, g, xx, acc);
  }
#pragma unroll
  for (int i = 0; i < 4; ++i) {
    int r = m0 + 4 * g + i;
    if (r < c) {
      int p = lst[e * N_ + r];
      float w = gp[p];
      int n = n0 + 4 * xx;
      float4 o;
      o.x = w * (acc[i][0] + B2[e * D_ + n + 0]);
      o.y = w * (acc[i][1] + B2[e * D_ + n + 1]);
      o.z = w * (acc[i][2] + B2[e * D_ + n + 2]);
      o.w = w * (acc[i][3] + B2[e * D_ + n + 3]);
      *(float4*)&mp[(size_t)p * D_ + n] = o;
    }
  }
}

// ---------------------------------------------------------------------------
extern "C" void kernel_launch(void* const* d_in, const int* in_sizes, int n_in,
                              void* d_out, int out_size, void* d_ws, size_t ws_size,
                              hipStream_t stream) {
  const float* src  = (const float*)d_in[0];
  const float* cosb = (const float*)d_in[1];
  const float* sinb = (const float*)d_in[2];
  const float* Wq   = (const float*)d_in[3];
  const float* bq   = (const float*)d_in[4];
  const float* Wk   = (const float*)d_in[5];
  const float* bk   = (const float*)d_in[6];
  const float* Wv   = (const float*)d_in[7];
  const float* bv   = (const float*)d_in[8];
  const float* Wo   = (const float*)d_in[9];
  const float* bo   = (const float*)d_in[10];
  const float* ln1g = (const float*)d_in[11];
  const float* ln1b = (const float*)d_in[12];
  const float* ln2g = (const float*)d_in[13];
  const float* ln2b = (const float*)d_in[14];
  const float* Wg   = (const float*)d_in[15];
  const float* W1   = (const float*)d_in[16];
  const float* B1   = (const float*)d_in[17];
  const float* W2   = (const float*)d_in[18];
  const float* B2   = (const float*)d_in[19];
  float* out = (float*)d_out;
  float* ws = (float*)d_ws;

  // Workspace layout (floats). ~59 MB total.
  const size_t ND = (size_t)N_ * D_;       // 2,097,152
  float* qb   = ws;                        // [0, ND)      q ; later attn_out
  float* kb   = ws + ND;                   // [ND, 2ND)    k
  float* vb   = ws + 2 * ND;               // [2ND,3ND)    v
  float* ctxb = ws + 3 * ND;               // [3ND,4ND)    ctx
  float* aob  = qb;                        // attn_out aliases q (q dead after attn)
  float* xb   = ws + 4 * ND;               // [4ND,5ND)    LN1 output
  float* hbuf = ws;                        // [0,4ND)      MoE hidden (aliases q,k,v,ctx)
  float* mp   = ws + 5 * ND;               // [5ND,7ND)    per-pair MoE outputs
  float* gp   = ws + 7 * ND;               // 8192 gate weights
  int* cnt    = (int*)(ws + 7 * ND + NPAIR_);
  int* lst    = cnt + 8;                   // 8*4096 ints

  hipMemsetAsync(cnt, 0, 8 * sizeof(int), stream);

  dim3 blk(256);
  // QKV projections
  gemm_bias<<<dim3(64, 8), blk, 0, stream>>>(src, Wq, bq, qb, N_, D_, D_);
  gemm_bias<<<dim3(64, 8), blk, 0, stream>>>(src, Wk, bk, kb, N_, D_, D_);
  gemm_bias<<<dim3(64, 8), blk, 0, stream>>>(src, Wv, bv, vb, N_, D_, D_);
  // RoPE on q,k
  rope_k<<<dim3(8192), blk, 0, stream>>>(qb, kb, cosb, sinb);
  // Attention
  attn_flash<<<dim3(S_ / 64, B_ * H_), blk, 0, stream>>>(qb, kb, vb, ctxb);
  // Output projection (writes over q region)
  gemm_bias<<<dim3(64, 8), blk, 0, stream>>>(ctxb, Wo, bo, aob, N_, D_, D_);
  // LN1 with residual
  ln_res<<<dim3(1024), blk, 0, stream>>>(src, aob, ln1g, ln1b, xb);
  // Gate + route
  gate_route<<<dim3(1024), blk, 0, stream>>>(xb, Wg, gp, cnt, lst);
  // MoE expert GEMMs (sparse: only routed tokens)
  moe_gemm1<<<dim3(64, F_ / 64, E_), blk, 0, stream>>>(xb, W1, B1, hbuf, cnt, lst);
  moe_gemm2<<<dim3(64, D_ / 64, E_), blk, 0, stream>>>(hbuf, W2, B2, gp, mp, cnt, lst);
  // Final LN
  ln2_final<<<dim3(1024), blk, 0, stream>>>(xb, mp, ln2g, ln2b, out);
}

// Round 2
// 1035.650 us; speedup vs baseline: 1.1309x; 1.1309x over previous
//
#include <hip/hip_runtime.h>
#include <math.h>

// Shapes (fixed)
#define S_  2048
#define B_  2
#define D_  512
#define H_  8
#define DH_ 64
#define E_  8
#define F_  1024
#define N_  4096   // S_*B_
#define NPAIR_ 8192 // N_*TOPK

typedef __attribute__((ext_vector_type(4))) float f32x4;
typedef __attribute__((ext_vector_type(8))) short short8;

__device__ __forceinline__ unsigned short f2bf(float f) {
  unsigned u = __builtin_bit_cast(unsigned, f);
  u += 0x7fffu + ((u >> 16) & 1u);
  return (unsigned short)(u >> 16);
}
__device__ __forceinline__ float bf2f(unsigned short h) {
  unsigned u = ((unsigned)h) << 16;
  return __builtin_bit_cast(float, u);
}

// ---------------------------------------------------------------------------
// f32 64x64x16 tile GEMM (kept for the precision-critical pre-gate path).
// ---------------------------------------------------------------------------
__device__ __forceinline__ void mm_step(const float (*As)[68], const float (*Bs)[68],
                                        int g, int xx, float acc[4][4]) {
#pragma unroll
  for (int kk = 0; kk < 16; ++kk) {
    float4 a4 = *(const float4*)&As[kk][4 * g];
    float4 b4 = *(const float4*)&Bs[kk][4 * xx];
    float a[4] = {a4.x, a4.y, a4.z, a4.w};
    float b[4] = {b4.x, b4.y, b4.z, b4.w};
#pragma unroll
    for (int i = 0; i < 4; ++i)
#pragma unroll
      for (int j = 0; j < 4; ++j)
        acc[i][j] += a[i] * b[j];
  }
}

__global__ __launch_bounds__(256) void gemm_bias(const float* __restrict__ A,
                                                 const float* __restrict__ W,
                                                 const float* __restrict__ bias,
                                                 float* __restrict__ C,
                                                 int M, int Nn, int K) {
  __shared__ __align__(16) float As[16][68];
  __shared__ __align__(16) float Bs[16][68];
  int tid = threadIdx.x;
  int m0 = blockIdx.x * 64, n0 = blockIdx.y * 64;
  int g = tid >> 4, xx = tid & 15;
  int la_r = tid >> 2, la_k = (tid & 3) * 4;
  int lb_k = tid >> 4, lb_n = (tid & 15) * 4;
  float acc[4][4] = {};
  for (int k0 = 0; k0 < K; k0 += 16) {
    float4 av = *(const float4*)&A[(size_t)(m0 + la_r) * K + k0 + la_k];
    float4 bv = *(const float4*)&W[(size_t)(k0 + lb_k) * Nn + n0 + lb_n];
    __syncthreads();
    As[la_k + 0][la_r] = av.x; As[la_k + 1][la_r] = av.y;
    As[la_k + 2][la_r] = av.z; As[la_k + 3][la_r] = av.w;
    *(float4*)&Bs[lb_k][lb_n] = bv;
    __syncthreads();
    mm_step(As, Bs, g, xx, acc);
  }
#pragma unroll
  for (int i = 0; i < 4; ++i) {
    int m = m0 + 4 * g + i;
    int n = n0 + 4 * xx;
    float4 o;
    o.x = acc[i][0] + bias[n + 0];
    o.y = acc[i][1] + bias[n + 1];
    o.z = acc[i][2] + bias[n + 2];
    o.w = acc[i][3] + bias[n + 3];
    *(float4*)&C[(size_t)m * Nn + n] = o;
  }
}

// ---------------------------------------------------------------------------
// RoPE in-place on q and k (f32), layout (S,B,H,DH), rows n=s*B+b.
// ---------------------------------------------------------------------------
__global__ __launch_bounds__(256) void rope_k(float* __restrict__ q, float* __restrict__ k,
                                              const float* __restrict__ cosb,
                                              const float* __restrict__ sinb) {
  int idx = blockIdx.x * 256 + threadIdx.x;
  int tsel = idx >> 20;
  int r = idx & ((1 << 20) - 1);
  int n = r >> 8;
  int h = (r >> 5) & 7;
  int d0 = r & 31;
  int s = n >> 1;
  size_t base = (size_t)n * D_ + h * DH_ + d0;
  float c = cosb[s * DH_ + d0];
  float sn = sinb[s * DH_ + d0];
  float* buf = tsel ? k : q;
  float a = buf[base], b = buf[base + 32];
  buf[base]      = a * c - b * sn;
  buf[base + 32] = b * c + a * sn;
}

// ---------------------------------------------------------------------------
// Flash attention f32, QT=64, KT=64, KV-split=2. V transposed in LDS so the
// PV loop is all float4. Ps is wave-local (rows 16w..16w+15) -> one barrier
// pair per tile. Writes UNNORMALIZED partial O + (m,l) per row.
// ---------------------------------------------------------------------------
__global__ __launch_bounds__(256) void attn_flash2(const float* __restrict__ q,
                                                   const float* __restrict__ k,
                                                   const float* __restrict__ v,
                                                   float* __restrict__ po,
                                                   float* __restrict__ pml) {
  __shared__ __align__(16) float Qs[64][68];
  __shared__ __align__(16) float Ks[64][68];
  __shared__ __align__(16) float Vst[64][68];   // [dh][kv]
  __shared__ __align__(16) float Ps[64][68];
  int tid = threadIdx.x;
  int qt = blockIdx.x;       // 0..31
  int bh = blockIdx.y;       // 0..15
  int kvh = blockIdx.z;      // 0..1
  int b = bh >> 3, h = bh & 7;
  int g = tid >> 4, xx = tid & 15;
  {
    int r = tid >> 2, c0 = (tid & 3) * 16;
    const float* qp = &q[(size_t)((qt * 64 + r) * 2 + b) * D_ + h * DH_ + c0];
#pragma unroll
    for (int c = 0; c < 16; c += 4) {
      float4 t = *(const float4*)&qp[c];
      t.x *= 0.125f; t.y *= 0.125f; t.z *= 0.125f; t.w *= 0.125f;
      *(float4*)&Qs[r][c0 + c] = t;
    }
  }
  float m_run[4], l_run[4], acc[4][4];
#pragma unroll
  for (int i = 0; i < 4; ++i) {
    m_run[i] = -1e30f; l_run[i] = 0.f;
#pragma unroll
    for (int j = 0; j < 4; ++j) acc[i][j] = 0.f;
  }
  int vr = tid & 63, vd0 = (tid >> 6) * 16;    // conflict-free Vst scatter
  int kr = tid >> 2, kc0 = (tid & 3) * 16;
  for (int tt = 0; tt < 1024; tt += 64) {
    int t0 = kvh * 1024 + tt;
    __syncthreads();
    {
      const float* kp = &k[(size_t)((t0 + kr) * 2 + b) * D_ + h * DH_ + kc0];
#pragma unroll
      for (int c = 0; c < 16; c += 4)
        *(float4*)&Ks[kr][kc0 + c] = *(const float4*)&kp[c];
      const float* vp = &v[(size_t)((t0 + vr) * 2 + b) * D_ + h * DH_ + vd0];
#pragma unroll
      for (int c = 0; c < 16; c += 4) {
        float4 t = *(const float4*)&vp[c];
        Vst[vd0 + c + 0][vr] = t.x;
        Vst[vd0 + c + 1][vr] = t.y;
        Vst[vd0 + c + 2][vr] = t.z;
        Vst[vd0 + c + 3][vr] = t.w;
      }
    }
    __syncthreads();
    float sc[4][4];
#pragma unroll
    for (int i = 0; i < 4; ++i)
#pragma unroll
      for (int j = 0; j < 4; ++j) sc[i][j] = 0.f;
#pragma unroll
    for (int d4 = 0; d4 < 16; ++d4) {
      float4 qa[4], kb4[4];
#pragma unroll
      for (int i = 0; i < 4; ++i) qa[i] = *(const float4*)&Qs[4 * g + i][4 * d4];
#pragma unroll
      for (int j = 0; j < 4; ++j) kb4[j] = *(const float4*)&Ks[xx + 16 * j][4 * d4];
#pragma unroll
      for (int i = 0; i < 4; ++i)
#pragma unroll
        for (int j = 0; j < 4; ++j)
          sc[i][j] += qa[i].x * kb4[j].x + qa[i].y * kb4[j].y +
                      qa[i].z * kb4[j].z + qa[i].w * kb4[j].w;
    }
#pragma unroll
    for (int i = 0; i < 4; ++i) {
      float tm = fmaxf(fmaxf(sc[i][0], sc[i][1]), fmaxf(sc[i][2], sc[i][3]));
      tm = fmaxf(tm, __shfl_xor(tm, 1));
      tm = fmaxf(tm, __shfl_xor(tm, 2));
      tm = fmaxf(tm, __shfl_xor(tm, 4));
      tm = fmaxf(tm, __shfl_xor(tm, 8));
      float mn = fmaxf(m_run[i], tm);
      float corr = __expf(m_run[i] - mn);
      m_run[i] = mn;
      float p0 = __expf(sc[i][0] - mn), p1 = __expf(sc[i][1] - mn);
      float p2 = __expf(sc[i][2] - mn), p3 = __expf(sc[i][3] - mn);
      float ts = p0 + p1 + p2 + p3;
      ts += __shfl_xor(ts, 1); ts += __shfl_xor(ts, 2);
      ts += __shfl_xor(ts, 4); ts += __shfl_xor(ts, 8);
      l_run[i] = l_run[i] * corr + ts;
#pragma unroll
      for (int j = 0; j < 4; ++j) acc[i][j] *= corr;
      Ps[4 * g + i][xx]      = p0;
      Ps[4 * g + i][xx + 16] = p1;
      Ps[4 * g + i][xx + 32] = p2;
      Ps[4 * g + i][xx + 48] = p3;
    }
    // PV: Ps rows are wave-local, Vst protected by the loop barriers.
#pragma unroll
    for (int kc = 0; kc < 64; kc += 4) {
      float4 pa[4];
#pragma unroll
      for (int i = 0; i < 4; ++i) pa[i] = *(const float4*)&Ps[4 * g + i][kc];
#pragma unroll
      for (int j = 0; j < 4; ++j) {
        float4 vt = *(const float4*)&Vst[xx + 16 * j][kc];
#pragma unroll
        for (int i = 0; i < 4; ++i)
          acc[i][j] += pa[i].x * vt.x + pa[i].y * vt.y + pa[i].z * vt.z + pa[i].w * vt.w;
      }
    }
  }
#pragma unroll
  for (int i = 0; i < 4; ++i) {
    int s = qt * 64 + 4 * g + i;
    size_t base = (size_t)kvh * ((size_t)N_ * D_) + (size_t)(s * 2 + b) * D_ + h * DH_;
#pragma unroll
    for (int j = 0; j < 4; ++j)
      po[base + xx + 16 * j] = acc[i][j];
    if (xx == 0) {
      int u = (s * 2 + b) * 8 + h;
      pml[(size_t)kvh * 65536 + u * 2 + 0] = m_run[i];
      pml[(size_t)kvh * 65536 + u * 2 + 1] = l_run[i];
    }
  }
}

__global__ __launch_bounds__(256) void merge_attn(const float* __restrict__ po,
                                                  const float* __restrict__ pml,
                                                  float* __restrict__ ctx) {
  int u = blockIdx.x * 4 + (threadIdx.x >> 6);
  int lane = threadIdx.x & 63;
  float m0 = pml[u * 2], l0 = pml[u * 2 + 1];
  float m1 = pml[65536 + u * 2], l1 = pml[65536 + u * 2 + 1];
  float m = fmaxf(m0, m1);
  float e0 = __expf(m0 - m), e1 = __expf(m1 - m);
  float inv = 1.f / (l0 * e0 + l1 * e1);
  int n = u >> 3, h = u & 7;
  size_t base = (size_t)n * D_ + h * DH_ + lane;
  const size_t PO1 = (size_t)N_ * D_;
  ctx[base] = (po[base] * e0 + po[PO1 + base] * e1) * inv;
}

// ---------------------------------------------------------------------------
// LayerNorm with residual: out = LN(a + b) (f32) + bf16 copy for MoE.
// ---------------------------------------------------------------------------
__global__ __launch_bounds__(256) void ln_res(const float* __restrict__ a,
                                              const float* __restrict__ b,
                                              const float* __restrict__ g,
                                              const float* __restrict__ beta,
                                              float* __restrict__ out,
                                              unsigned short* __restrict__ obf) {
  int n = blockIdx.x * 4 + (threadIdx.x >> 6);
  int lane = threadIdx.x & 63;
  float v[8];
  float s = 0.f;
#pragma unroll
  for (int i = 0; i < 8; ++i) {
    int d = lane + 64 * i;
    v[i] = a[(size_t)n * D_ + d] + b[(size_t)n * D_ + d];
    s += v[i];
  }
#pragma unroll
  for (int m = 32; m; m >>= 1) s += __shfl_xor(s, m);
  float mean = s * (1.f / D_);
  float s2 = 0.f;
#pragma unroll
  for (int i = 0; i < 8; ++i) { float t = v[i] - mean; s2 += t * t; }
#pragma unroll
  for (int m = 32; m; m >>= 1) s2 += __shfl_xor(s2, m);
  float r = rsqrtf(s2 * (1.f / D_) + 1e-5f);
#pragma unroll
  for (int i = 0; i < 8; ++i) {
    int d = lane + 64 * i;
    float val = (v[i] - mean) * r * g[d] + beta[d];
    out[(size_t)n * D_ + d] = val;
    obf[(size_t)n * D_ + d] = f2bf(val);
  }
}

// Final: out = LN(x + mp[2n] + mp[2n+1]), mp is bf16.
__global__ __launch_bounds__(256) void ln2_final(const float* __restrict__ x,
                                                 const unsigned short* __restrict__ mp,
                                                 const float* __restrict__ g,
                                                 const float* __restrict__ beta,
                                                 float* __restrict__ out) {
  int n = blockIdx.x * 4 + (threadIdx.x >> 6);
  int lane = threadIdx.x & 63;
  float v[8];
  float s = 0.f;
#pragma unroll
  for (int i = 0; i < 8; ++i) {
    int d = lane + 64 * i;
    v[i] = x[(size_t)n * D_ + d] + bf2f(mp[(size_t)(2 * n) * D_ + d]) +
           bf2f(mp[(size_t)(2 * n + 1) * D_ + d]);
    s += v[i];
  }
#pragma unroll
  for (int m = 32; m; m >>= 1) s += __shfl_xor(s, m);
  float mean = s * (1.f / D_);
  float s2 = 0.f;
#pragma unroll
  for (int i = 0; i < 8; ++i) { float t = v[i] - mean; s2 += t * t; }
#pragma unroll
  for (int m = 32; m; m >>= 1) s2 += __shfl_xor(s2, m);
  float r = rsqrtf(s2 * (1.f / D_) + 1e-5f);
#pragma unroll
  for (int i = 0; i < 8; ++i) {
    int d = lane + 64 * i;
    out[(size_t)n * D_ + d] = (v[i] - mean) * r * g[d] + beta[d];
  }
}

// ---------------------------------------------------------------------------
// Gate + top-2 routing (f32 — decision-critical).
// ---------------------------------------------------------------------------
__global__ __launch_bounds__(256) void gate_route(const float* __restrict__ x,
                                                  const float* __restrict__ Wg,
                                                  float* __restrict__ gp,
                                                  int* __restrict__ cnt,
                                                  int* __restrict__ lst) {
  int n = blockIdx.x * 4 + (threadIdx.x >> 6);
  int lane = threadIdx.x & 63;
  float p[E_] = {};
  for (int d = lane; d < D_; d += 64) {
    float xv = x[(size_t)n * D_ + d];
    const float* wr = &Wg[(size_t)d * E_];
#pragma unroll
    for (int e = 0; e < E_; ++e) p[e] += xv * wr[e];
  }
#pragma unroll
  for (int e = 0; e < E_; ++e)
#pragma unroll
    for (int m = 32; m; m >>= 1) p[e] += __shfl_xor(p[e], m);
  if (lane == 0) {
    float mx = p[0];
#pragma unroll
    for (int e = 1; e < E_; ++e) mx = fmaxf(mx, p[e]);
    float q[E_];
#pragma unroll
    for (int e = 0; e < E_; ++e) q[e] = expf(p[e] - mx);
    int e1 = 0;
#pragma unroll
    for (int e = 1; e < E_; ++e) if (q[e] > q[e1]) e1 = e;
    int e2 = (e1 == 0) ? 1 : 0;
#pragma unroll
    for (int e = 0; e < E_; ++e) if (e != e1 && q[e] > q[e2]) e2 = e;
    float denom = q[e1] + q[e2];
    float w1 = q[e1] / denom, w2 = q[e2] / denom;
    int s1 = atomicAdd(&cnt[e1], 1);
    lst[e1 * N_ + s1] = n * 2;
    int s2 = atomicAdd(&cnt[e2], 1);
    lst[e2 * N_ + s2] = n * 2 + 1;
    gp[n * 2] = w1;
    gp[n * 2 + 1] = w2;
  }
}

// ---------------------------------------------------------------------------
// Weight transpose + f32->bf16: Wt[n][k] = bf16(W[k][n]). grid z = expert.
// ---------------------------------------------------------------------------
__global__ __launch_bounds__(256) void wtrans(const float* __restrict__ W,
                                              unsigned short* __restrict__ Wt,
                                              int K, int Nn) {
  size_t eo = (size_t)blockIdx.z * K * Nn;
  __shared__ unsigned short T[64][72];
  int kb = blockIdx.y * 64, nb = blockIdx.x * 64;
  int r = threadIdx.x >> 2, c0 = (threadIdx.x & 3) * 16;
  const float* wp = &W[eo + (size_t)(kb + r) * Nn + nb + c0];
#pragma unroll
  for (int c = 0; c < 16; c += 4) {
    float4 t = *(const float4*)&wp[c];
    T[r][c0 + c + 0] = f2bf(t.x);
    T[r][c0 + c + 1] = f2bf(t.y);
    T[r][c0 + c + 2] = f2bf(t.z);
    T[r][c0 + c + 3] = f2bf(t.w);
  }
  __syncthreads();
  unsigned short o[16];
#pragma unroll
  for (int j = 0; j < 16; ++j) o[j] = T[c0 + j][r];
  short8 s0, s1;
#pragma unroll
  for (int j = 0; j < 8; ++j) { s0[j] = (short)o[j]; s1[j] = (short)o[j + 8]; }
  *(short8*)&Wt[eo + (size_t)(nb + r) * K + kb + c0] = s0;
  *(short8*)&Wt[eo + (size_t)(nb + r) * K + kb + c0 + 8] = s1;
}

// ---------------------------------------------------------------------------
// bf16 MFMA MoE GEMM, 128x128 tile, BK=32, 4 waves (2x2), 4x4 16x16 frags.
// MODE 0: h = relu(gather(x) @ W1t^T + B1) -> bf16
// MODE 1: mp[p] = gp[p] * (h @ W2t^T + B2) -> bf16, scatter by pair id
// ---------------------------------------------------------------------------
template <int MODE>
__global__ __launch_bounds__(256) void moe_mfma(const unsigned short* __restrict__ Abase,
                                                const unsigned short* __restrict__ Wt,
                                                const float* __restrict__ bias,
                                                const float* __restrict__ gp,
                                                unsigned short* __restrict__ outp,
                                                const int* __restrict__ cnt,
                                                const int* __restrict__ lst) {
  constexpr int K  = MODE ? 1024 : 512;
  constexpr int Nn = MODE ? 512 : 1024;
  int e = blockIdx.z;
  int c = cnt[e];
  int m0 = blockIdx.x * 128;
  if (m0 >= c) return;
  int off = 0;
#pragma unroll
  for (int i = 0; i < E_; ++i) if (i < e) off += cnt[i];
  int n0 = blockIdx.y * 128;
  __shared__ unsigned short As[128][40];
  __shared__ unsigned short Bs[128][40];
  int tid = threadIdx.x;
  int w = tid >> 6, l = tid & 63;
  int wr = w >> 1, wc = w & 1;
  int sr = tid >> 1, sh = (tid & 1) * 16;
  int ar = m0 + sr; if (ar > c - 1) ar = c - 1;
  const unsigned short* Ap;
  if (MODE == 0) Ap = Abase + (size_t)(lst[e * N_ + ar] >> 1) * 512;
  else           Ap = Abase + (size_t)(off + ar) * 1024;
  const unsigned short* Bp = Wt + (size_t)e * K * Nn + (size_t)(n0 + sr) * K;
  f32x4 acc[4][4];
#pragma unroll
  for (int m = 0; m < 4; ++m)
#pragma unroll
    for (int n = 0; n < 4; ++n) acc[m][n] = (f32x4){0.f, 0.f, 0.f, 0.f};
  for (int k0 = 0; k0 < K; k0 += 32) {
    short8 av0 = *(const short8*)&Ap[k0 + sh];
    short8 av1 = *(const short8*)&Ap[k0 + sh + 8];
    short8 bv0 = *(const short8*)&Bp[k0 + sh];
    short8 bv1 = *(const short8*)&Bp[k0 + sh + 8];
    __syncthreads();
    *(short8*)&As[sr][sh] = av0;
    *(short8*)&As[sr][sh + 8] = av1;
    *(short8*)&Bs[sr][sh] = bv0;
    *(short8*)&Bs[sr][sh + 8] = bv1;
    __syncthreads();
    short8 a[4], bfr[4];
#pragma unroll
    for (int m = 0; m < 4; ++m)
      a[m] = *(const short8*)&As[wr * 64 + m * 16 + (l & 15)][(l >> 4) * 8];
#pragma unroll
    for (int n = 0; n < 4; ++n)
      bfr[n] = *(const short8*)&Bs[wc * 64 + n * 16 + (l & 15)][(l >> 4) * 8];
#pragma unroll
    for (int m = 0; m < 4; ++m)
#pragma unroll
      for (int n = 0; n < 4; ++n)
        acc[m][n] = __builtin_amdgcn_mfma_f32_16x16x32_bf16(a[m], bfr[n], acc[m][n], 0, 0, 0);
  }
#pragma unroll
  for (int m = 0; m < 4; ++m)
#pragma unroll
    for (int n = 0; n < 4; ++n)
#pragma unroll
      for (int i = 0; i < 4; ++i) {
        int r = m0 + wr * 64 + m * 16 + (l >> 4) * 4 + i;
        if (r < c) {
          int col = n0 + wc * 64 + n * 16 + (l & 15);
          float val = acc[m][n][i] + bias[e * Nn + col];
          if (MODE == 0) {
            val = fmaxf(val, 0.f);
            outp[(size_t)(off + r) * 1024 + col] = f2bf(val);
          } else {
            int p = lst[e * N_ + r];
            outp[(size_t)p * 512 + col] = f2bf(gp[p] * val);
          }
        }
      }
}

// ---------------------------------------------------------------------------
extern "C" void kernel_launch(void* const* d_in, const int* in_sizes, int n_in,
                              void* d_out, int out_size, void* d_ws, size_t ws_size,
                              hipStream_t stream) {
  const float* src  = (const float*)d_in[0];
  const float* cosb = (const float*)d_in[1];
  const float* sinb = (const float*)d_in[2];
  const float* Wq   = (const float*)d_in[3];
  const float* bq   = (const float*)d_in[4];
  const float* Wk   = (const float*)d_in[5];
  const float* bk   = (const float*)d_in[6];
  const float* Wv   = (const float*)d_in[7];
  const float* bv   = (const float*)d_in[8];
  const float* Wo   = (const float*)d_in[9];
  const float* bo   = (const float*)d_in[10];
  const float* ln1g = (const float*)d_in[11];
  const float* ln1b = (const float*)d_in[12];
  const float* ln2g = (const float*)d_in[13];
  const float* ln2b = (const float*)d_in[14];
  const float* Wg   = (const float*)d_in[15];
  const float* W1   = (const float*)d_in[16];
  const float* B1   = (const float*)d_in[17];
  const float* W2   = (const float*)d_in[18];
  const float* B2   = (const float*)d_in[19];
  float* out = (float*)d_out;
  float* ws = (float*)d_ws;

  const size_t ND = (size_t)N_ * D_;  // 2,097,152 floats
  // Workspace (floats). ~60.7 MB high-water with aliasing:
  float* qb   = ws;                        // [0,2M)   q f32; later attn_out
  float* kb   = ws + ND;                   // [2M,4M)
  float* vb   = ws + 2 * ND;               // [4M,6M)
  float* ctxb = ws + 3 * ND;               // [6M,8M)  ctx f32; later mp (bf16)
  float* aob  = qb;
  unsigned short* mp = (unsigned short*)(ws + 3 * ND);
  float* xb   = ws + 4 * ND;               // [8M,10M) LN1 out f32
  unsigned short* xbf = (unsigned short*)(ws + 5 * ND);            // [10M,11M)
  unsigned short* W1t = (unsigned short*)(ws + 5 * ND + ND / 2);   // [11M,13M)
  unsigned short* W2t = (unsigned short*)(ws + 6 * ND + ND / 2);   // [13M,15M)
  float* po   = ws + 5 * ND + ND / 2;      // [11M,15M) attn partials (alias W1t/W2t, dead before wtrans)
  float* pml  = ws + 7 * ND + ND / 2;      // [15M, +131072)
  float* gpb  = ws + 7 * ND + ND / 2 + 131072;
  int*   cnt  = (int*)(gpb + NPAIR_);
  int*   lst  = cnt + 16;
  unsigned short* hbf = (unsigned short*)(ws + ND);  // [2M,6M) alias kb/vb, after attn

  hipMemsetAsync(cnt, 0, 16 * sizeof(int), stream);

  dim3 blk(256);
  // QKV projections (f32 — precision-critical)
  gemm_bias<<<dim3(64, 8), blk, 0, stream>>>(src, Wq, bq, qb, N_, D_, D_);
  gemm_bias<<<dim3(64, 8), blk, 0, stream>>>(src, Wk, bk, kb, N_, D_, D_);
  gemm_bias<<<dim3(64, 8), blk, 0, stream>>>(src, Wv, bv, vb, N_, D_, D_);
  rope_k<<<dim3(8192), blk, 0, stream>>>(qb, kb, cosb, sinb);
  // Attention (f32, KV-split=2) + merge
  attn_flash2<<<dim3(32, 16, 2), blk, 0, stream>>>(qb, kb, vb, po, pml);
  merge_attn<<<dim3(8192), blk, 0, stream>>>(po, pml, ctxb);
  // Output projection (f32)
  gemm_bias<<<dim3(64, 8), blk, 0, stream>>>(ctxb, Wo, bo, aob, N_, D_, D_);
  // LN1 (+bf16 copy of x)
  ln_res<<<dim3(1024), blk, 0, stream>>>(src, aob, ln1g, ln1b, xb, xbf);
  // MoE weight transposes to bf16 (po/pml dead by now)
  wtrans<<<dim3(16, 8, 8), blk, 0, stream>>>(W1, W1t, 512, 1024);
  wtrans<<<dim3(8, 16, 8), blk, 0, stream>>>(W2, W2t, 1024, 512);
  // Gate + route (f32)
  gate_route<<<dim3(1024), blk, 0, stream>>>(xb, Wg, gpb, cnt, lst);
  // Sparse MoE expert GEMMs — bf16 MFMA
  moe_mfma<0><<<dim3(32, 8, 8), blk, 0, stream>>>(xbf, W1t, B1, gpb, hbf, cnt, lst);
  moe_mfma<1><<<dim3(32, 4, 8), blk, 0, stream>>>(hbf, W2t, B2, gpb, mp, cnt, lst);
  // Final LN
  ln2_final<<<dim3(1024), blk, 0, stream>>>(xb, mp, ln2g, ln2b, out);
}

// Round 3
// 576.496 us; speedup vs baseline: 2.0316x; 1.7965x over previous
//
#include <hip/hip_runtime.h>
#include <math.h>

// Shapes (fixed)
#define S_  2048
#define B_  2
#define D_  512
#define H_  8
#define DH_ 64
#define E_  8
#define F_  1024
#define N_  4096   // S_*B_
#define NPAIR_ 8192 // N_*TOPK

typedef __attribute__((ext_vector_type(4))) float f32x4;
typedef __attribute__((ext_vector_type(8))) short short8;

__device__ __forceinline__ unsigned short f2bf(float f) {
  unsigned u = __builtin_bit_cast(unsigned, f);
  u += 0x7fffu + ((u >> 16) & 1u);
  return (unsigned short)(u >> 16);
}
__device__ __forceinline__ float bf2f(unsigned short h) {
  unsigned u = ((unsigned)h) << 16;
  return __builtin_bit_cast(float, u);
}

// ---------------------------------------------------------------------------
// f32 64x64x16 tile GEMM (precision-critical pre-gate path).
// ---------------------------------------------------------------------------
__device__ __forceinline__ void mm_step(const float (*As)[68], const float (*Bs)[68],
                                        int g, int xx, float acc[4][4]) {
#pragma unroll
  for (int kk = 0; kk < 16; ++kk) {
    float4 a4 = *(const float4*)&As[kk][4 * g];
    float4 b4 = *(const float4*)&Bs[kk][4 * xx];
    float a[4] = {a4.x, a4.y, a4.z, a4.w};
    float b[4] = {b4.x, b4.y, b4.z, b4.w};
#pragma unroll
    for (int i = 0; i < 4; ++i)
#pragma unroll
      for (int j = 0; j < 4; ++j)
        acc[i][j] += a[i] * b[j];
  }
}

__global__ __launch_bounds__(256) void gemm_bias(const float* __restrict__ A,
                                                 const float* __restrict__ W,
                                                 const float* __restrict__ bias,
                                                 float* __restrict__ C,
                                                 int M, int Nn, int K) {
  __shared__ __align__(16) float As[16][68];
  __shared__ __align__(16) float Bs[16][68];
  int tid = threadIdx.x;
  int m0 = blockIdx.x * 64, n0 = blockIdx.y * 64;
  int g = tid >> 4, xx = tid & 15;
  int la_r = tid >> 2, la_k = (tid & 3) * 4;
  int lb_k = tid >> 4, lb_n = (tid & 15) * 4;
  float acc[4][4] = {};
  for (int k0 = 0; k0 < K; k0 += 16) {
    float4 av = *(const float4*)&A[(size_t)(m0 + la_r) * K + k0 + la_k];
    float4 bv = *(const float4*)&W[(size_t)(k0 + lb_k) * Nn + n0 + lb_n];
    __syncthreads();
    As[la_k + 0][la_r] = av.x; As[la_k + 1][la_r] = av.y;
    As[la_k + 2][la_r] = av.z; As[la_k + 3][la_r] = av.w;
    *(float4*)&Bs[lb_k][lb_n] = bv;
    __syncthreads();
    mm_step(As, Bs, g, xx, acc);
  }
#pragma unroll
  for (int i = 0; i < 4; ++i) {
    int m = m0 + 4 * g + i;
    int n = n0 + 4 * xx;
    float4 o;
    o.x = acc[i][0] + bias[n + 0];
    o.y = acc[i][1] + bias[n + 1];
    o.z = acc[i][2] + bias[n + 2];
    o.w = acc[i][3] + bias[n + 3];
    *(float4*)&C[(size_t)m * Nn + n] = o;
  }
}

// ---------------------------------------------------------------------------
// RoPE in-place on q and k (f32), layout (S,B,H,DH), rows n=s*B+b.
// ---------------------------------------------------------------------------
__global__ __launch_bounds__(256) void rope_k(float* __restrict__ q, float* __restrict__ k,
                                              const float* __restrict__ cosb,
                                              const float* __restrict__ sinb) {
  int idx = blockIdx.x * 256 + threadIdx.x;
  int tsel = idx >> 20;
  int r = idx & ((1 << 20) - 1);
  int n = r >> 8;
  int h = (r >> 5) & 7;
  int d0 = r & 31;
  int s = n >> 1;
  size_t base = (size_t)n * D_ + h * DH_ + d0;
  float c = cosb[s * DH_ + d0];
  float sn = sinb[s * DH_ + d0];
  float* buf = tsel ? k : q;
  float a = buf[base], b = buf[base + 32];
  buf[base]      = a * c - b * sn;
  buf[base + 32] = b * c + a * sn;
}

// ---------------------------------------------------------------------------
// MFMA flash attention. QT=64 (4 waves x 16 rows), KT=64.
// Q,K in split-bf16 (hi+lo, 3 MFMA products) for f32-grade scores;
// P,V single bf16. Fragment layouts as verified by moe_mfma (round 1):
//   A: row=lane&15, k=(lane>>4)*8+j ; C/D: col=lane&15, row=(lane>>4)*4+i.
// ---------------------------------------------------------------------------
__global__ __launch_bounds__(256) void attn_mfma(const float* __restrict__ q,
                                                 const float* __restrict__ k,
                                                 const float* __restrict__ v,
                                                 float* __restrict__ ctx) {
  __shared__ unsigned short Khi[64][72];   // [kv][dh], stride 144B (16B-aligned)
  __shared__ unsigned short Klo[64][72];
  __shared__ unsigned short Vt[64][72];    // [dh][kv]
  __shared__ unsigned short Pl[4][16][72]; // per-wave P tile [qrow][kv]
  int tid = threadIdx.x;
  int w = tid >> 6, l = tid & 63;
  int lg = l >> 4, lx = l & 15;
  int qt = blockIdx.x, bh = blockIdx.y;
  int b = bh >> 3, h = bh & 7;

  // Hoist Q A-frags (scaled by 1/8, split hi/lo)
  short8 qhi[2], qlo[2];
  {
    int qrow = qt * 64 + w * 16 + lx;
    const float* qp = &q[(size_t)(qrow * 2 + b) * D_ + h * DH_ + lg * 8];
#pragma unroll
    for (int kc = 0; kc < 2; ++kc) {
      float f[8];
      *(float4*)&f[0] = *(const float4*)&qp[kc * 32];
      *(float4*)&f[4] = *(const float4*)&qp[kc * 32 + 4];
#pragma unroll
      for (int j = 0; j < 8; ++j) {
        float s = f[j] * 0.125f;
        unsigned short hi = f2bf(s);
        qhi[kc][j] = (short)hi;
        qlo[kc][j] = (short)f2bf(s - bf2f(hi));
      }
    }
  }

  f32x4 o_acc[4];
#pragma unroll
  for (int dg = 0; dg < 4; ++dg) o_acc[dg] = (f32x4){0.f, 0.f, 0.f, 0.f};
  float m_run[4], l_run[4];
#pragma unroll
  for (int i = 0; i < 4; ++i) { m_run[i] = -1e30f; l_run[i] = 0.f; }

  int kvr = tid >> 2, ds4 = (tid & 3) * 16;   // K staging map
  int kvc = tid & 63, dsg = (tid >> 6) * 16;  // V staging map (transpose)

  for (int t0 = 0; t0 < S_; t0 += 64) {
    __syncthreads();
    // ---- stage K (split) and V^T (bf16) ----
    {
      const float* kp = &k[(size_t)((t0 + kvr) * 2 + b) * D_ + h * DH_ + ds4];
      float f[16];
#pragma unroll
      for (int c = 0; c < 16; c += 4) *(float4*)&f[c] = *(const float4*)&kp[c];
      short8 h0, h1, l0, l1;
#pragma unroll
      for (int j = 0; j < 8; ++j) {
        unsigned short a = f2bf(f[j]);
        h0[j] = (short)a; l0[j] = (short)f2bf(f[j] - bf2f(a));
        unsigned short bb = f2bf(f[j + 8]);
        h1[j] = (short)bb; l1[j] = (short)f2bf(f[j + 8] - bf2f(bb));
      }
      *(short8*)&Khi[kvr][ds4] = h0;
      *(short8*)&Khi[kvr][ds4 + 8] = h1;
      *(short8*)&Klo[kvr][ds4] = l0;
      *(short8*)&Klo[kvr][ds4 + 8] = l1;
      const float* vp = &v[(size_t)((t0 + kvc) * 2 + b) * D_ + h * DH_ + dsg];
      float g[16];
#pragma unroll
      for (int c = 0; c < 16; c += 4) *(float4*)&g[c] = *(const float4*)&vp[c];
#pragma unroll
      for (int c = 0; c < 16; ++c) Vt[dsg + c][kvc] = f2bf(g[c]);
    }
    __syncthreads();

    // ---- QK^T (split-bf16: hi*hi + hi*lo + lo*hi) ----
    f32x4 sc[4];
#pragma unroll
    for (int cg = 0; cg < 4; ++cg) {
      short8 kh0 = *(const short8*)&Khi[cg * 16 + lx][lg * 8];
      short8 kh1 = *(const short8*)&Khi[cg * 16 + lx][32 + lg * 8];
      short8 kl0 = *(const short8*)&Klo[cg * 16 + lx][lg * 8];
      short8 kl1 = *(const short8*)&Klo[cg * 16 + lx][32 + lg * 8];
      f32x4 a = (f32x4){0.f, 0.f, 0.f, 0.f};
      a = __builtin_amdgcn_mfma_f32_16x16x32_bf16(qhi[0], kh0, a, 0, 0, 0);
      a = __builtin_amdgcn_mfma_f32_16x16x32_bf16(qhi[1], kh1, a, 0, 0, 0);
      a = __builtin_amdgcn_mfma_f32_16x16x32_bf16(qlo[0], kh0, a, 0, 0, 0);
      a = __builtin_amdgcn_mfma_f32_16x16x32_bf16(qlo[1], kh1, a, 0, 0, 0);
      a = __builtin_amdgcn_mfma_f32_16x16x32_bf16(qhi[0], kl0, a, 0, 0, 0);
      a = __builtin_amdgcn_mfma_f32_16x16x32_bf16(qhi[1], kl1, a, 0, 0, 0);
      sc[cg] = a;
    }

    // ---- online softmax (rows lg*4+i, cols across 16-lane group) ----
#pragma unroll
    for (int i = 0; i < 4; ++i) {
      float s0 = sc[0][i], s1 = sc[1][i], s2 = sc[2][i], s3 = sc[3][i];
      float tm = fmaxf(fmaxf(s0, s1), fmaxf(s2, s3));
      tm = fmaxf(tm, __shfl_xor(tm, 1));
      tm = fmaxf(tm, __shfl_xor(tm, 2));
      tm = fmaxf(tm, __shfl_xor(tm, 4));
      tm = fmaxf(tm, __shfl_xor(tm, 8));
      float mn = fmaxf(m_run[i], tm);
      float corr = __expf(m_run[i] - mn);
      m_run[i] = mn;
      float p0 = __expf(s0 - mn), p1 = __expf(s1 - mn);
      float p2 = __expf(s2 - mn), p3 = __expf(s3 - mn);
      float ts = p0 + p1 + p2 + p3;
      ts += __shfl_xor(ts, 1); ts += __shfl_xor(ts, 2);
      ts += __shfl_xor(ts, 4); ts += __shfl_xor(ts, 8);
      l_run[i] = l_run[i] * corr + ts;
#pragma unroll
      for (int dg = 0; dg < 4; ++dg) o_acc[dg][i] *= corr;
      int row = lg * 4 + i;
      Pl[w][row][lx]      = f2bf(p0);
      Pl[w][row][16 + lx] = f2bf(p1);
      Pl[w][row][32 + lx] = f2bf(p2);
      Pl[w][row][48 + lx] = f2bf(p3);
    }

    // ---- PV ----
    short8 pa0 = *(const short8*)&Pl[w][lx][lg * 8];
    short8 pa1 = *(const short8*)&Pl[w][lx][32 + lg * 8];
#pragma unroll
    for (int dg = 0; dg < 4; ++dg) {
      short8 v0 = *(const short8*)&Vt[dg * 16 + lx][lg * 8];
      short8 v1 = *(const short8*)&Vt[dg * 16 + lx][32 + lg * 8];
      o_acc[dg] = __builtin_amdgcn_mfma_f32_16x16x32_bf16(pa0, v0, o_acc[dg], 0, 0, 0);
      o_acc[dg] = __builtin_amdgcn_mfma_f32_16x16x32_bf16(pa1, v1, o_acc[dg], 0, 0, 0);
    }
  }

  // ---- epilogue ----
#pragma unroll
  for (int i = 0; i < 4; ++i) {
    float inv = 1.f / l_run[i];
    int srow = qt * 64 + w * 16 + lg * 4 + i;
    float* cp = &ctx[(size_t)(srow * 2 + b) * D_ + h * DH_];
#pragma unroll
    for (int dg = 0; dg < 4; ++dg)
      cp[dg * 16 + lx] = o_acc[dg][i] * inv;
  }
}

// ---------------------------------------------------------------------------
// LayerNorm with residual: out = LN(a + b) (f32) + bf16 copy for MoE.
// ---------------------------------------------------------------------------
__global__ __launch_bounds__(256) void ln_res(const float* __restrict__ a,
                                              const float* __restrict__ b,
                                              const float* __restrict__ g,
                                              const float* __restrict__ beta,
                                              float* __restrict__ out,
                                              unsigned short* __restrict__ obf) {
  int n = blockIdx.x * 4 + (threadIdx.x >> 6);
  int lane = threadIdx.x & 63;
  float v[8];
  float s = 0.f;
#pragma unroll
  for (int i = 0; i < 8; ++i) {
    int d = lane + 64 * i;
    v[i] = a[(size_t)n * D_ + d] + b[(size_t)n * D_ + d];
    s += v[i];
  }
#pragma unroll
  for (int m = 32; m; m >>= 1) s += __shfl_xor(s, m);
  float mean = s * (1.f / D_);
  float s2 = 0.f;
#pragma unroll
  for (int i = 0; i < 8; ++i) { float t = v[i] - mean; s2 += t * t; }
#pragma unroll
  for (int m = 32; m; m >>= 1) s2 += __shfl_xor(s2, m);
  float r = rsqrtf(s2 * (1.f / D_) + 1e-5f);
#pragma unroll
  for (int i = 0; i < 8; ++i) {
    int d = lane + 64 * i;
    float val = (v[i] - mean) * r * g[d] + beta[d];
    out[(size_t)n * D_ + d] = val;
    obf[(size_t)n * D_ + d] = f2bf(val);
  }
}

// Final: out = LN(x + mp[2n] + mp[2n+1]), mp is bf16.
__global__ __launch_bounds__(256) void ln2_final(const float* __restrict__ x,
                                                 const unsigned short* __restrict__ mp,
                                                 const float* __restrict__ g,
                                                 const float* __restrict__ beta,
                                                 float* __restrict__ out) {
  int n = blockIdx.x * 4 + (threadIdx.x >> 6);
  int lane = threadIdx.x & 63;
  float v[8];
  float s = 0.f;
#pragma unroll
  for (int i = 0; i < 8; ++i) {
    int d = lane + 64 * i;
    v[i] = x[(size_t)n * D_ + d] + bf2f(mp[(size_t)(2 * n) * D_ + d]) +
           bf2f(mp[(size_t)(2 * n + 1) * D_ + d]);
    s += v[i];
  }
#pragma unroll
  for (int m = 32; m; m >>= 1) s += __shfl_xor(s, m);
  float mean = s * (1.f / D_);
  float s2 = 0.f;
#pragma unroll
  for (int i = 0; i < 8; ++i) { float t = v[i] - mean; s2 += t * t; }
#pragma unroll
  for (int m = 32; m; m >>= 1) s2 += __shfl_xor(s2, m);
  float r = rsqrtf(s2 * (1.f / D_) + 1e-5f);
#pragma unroll
  for (int i = 0; i < 8; ++i) {
    int d = lane + 64 * i;
    out[(size_t)n * D_ + d] = (v[i] - mean) * r * g[d] + beta[d];
  }
}

// ---------------------------------------------------------------------------
// Gate + top-2 routing (f32 — decision-critical).
// ---------------------------------------------------------------------------
__global__ __launch_bounds__(256) void gate_route(const float* __restrict__ x,
                                                  const float* __restrict__ Wg,
                                                  float* __restrict__ gp,
                                                  int* __restrict__ cnt,
                                                  int* __restrict__ lst) {
  int n = blockIdx.x * 4 + (threadIdx.x >> 6);
  int lane = threadIdx.x & 63;
  float p[E_] = {};
  for (int d = lane; d < D_; d += 64) {
    float xv = x[(size_t)n * D_ + d];
    const float* wr = &Wg[(size_t)d * E_];
#pragma unroll
    for (int e = 0; e < E_; ++e) p[e] += xv * wr[e];
  }
#pragma unroll
  for (int e = 0; e < E_; ++e)
#pragma unroll
    for (int m = 32; m; m >>= 1) p[e] += __shfl_xor(p[e], m);
  if (lane == 0) {
    float mx = p[0];
#pragma unroll
    for (int e = 1; e < E_; ++e) mx = fmaxf(mx, p[e]);
    float q[E_];
#pragma unroll
    for (int e = 0; e < E_; ++e) q[e] = expf(p[e] - mx);
    int e1 = 0;
#pragma unroll
    for (int e = 1; e < E_; ++e) if (q[e] > q[e1]) e1 = e;
    int e2 = (e1 == 0) ? 1 : 0;
#pragma unroll
    for (int e = 0; e < E_; ++e) if (e != e1 && q[e] > q[e2]) e2 = e;
    float denom = q[e1] + q[e2];
    float w1 = q[e1] / denom, w2 = q[e2] / denom;
    int s1 = atomicAdd(&cnt[e1], 1);
    lst[e1 * N_ + s1] = n * 2;
    int s2 = atomicAdd(&cnt[e2], 1);
    lst[e2 * N_ + s2] = n * 2 + 1;
    gp[n * 2] = w1;
    gp[n * 2 + 1] = w2;
  }
}

// ---------------------------------------------------------------------------
// Weight transpose + f32->bf16: Wt[n][k] = bf16(W[k][n]). grid z = expert.
// ---------------------------------------------------------------------------
__global__ __launch_bounds__(256) void wtrans(const float* __restrict__ W,
                                              unsigned short* __restrict__ Wt,
                                              int K, int Nn) {
  size_t eo = (size_t)blockIdx.z * K * Nn;
  __shared__ unsigned short T[64][72];
  int kb = blockIdx.y * 64, nb = blockIdx.x * 64;
  int r = threadIdx.x >> 2, c0 = (threadIdx.x & 3) * 16;
  const float* wp = &W[eo + (size_t)(kb + r) * Nn + nb + c0];
#pragma unroll
  for (int c = 0; c < 16; c += 4) {
    float4 t = *(const float4*)&wp[c];
    T[r][c0 + c + 0] = f2bf(t.x);
    T[r][c0 + c + 1] = f2bf(t.y);
    T[r][c0 + c + 2] = f2bf(t.z);
    T[r][c0 + c + 3] = f2bf(t.w);
  }
  __syncthreads();
  unsigned short o[16];
#pragma unroll
  for (int j = 0; j < 16; ++j) o[j] = T[c0 + j][r];
  short8 s0, s1;
#pragma unroll
  for (int j = 0; j < 8; ++j) { s0[j] = (short)o[j]; s1[j] = (short)o[j + 8]; }
  *(short8*)&Wt[eo + (size_t)(nb + r) * K + kb + c0] = s0;
  *(short8*)&Wt[eo + (size_t)(nb + r) * K + kb + c0 + 8] = s1;
}

// ---------------------------------------------------------------------------
// bf16 MFMA MoE GEMM, 128x128 tile, BK=32, 4 waves (2x2), 4x4 16x16 frags.
// ---------------------------------------------------------------------------
template <int MODE>
__global__ __launch_bounds__(256) void moe_mfma(const unsigned short* __restrict__ Abase,
                                                const unsigned short* __restrict__ Wt,
                                                const float* __restrict__ bias,
                                                const float* __restrict__ gp,
                                                unsigned short* __restrict__ outp,
                                                const int* __restrict__ cnt,
                                                const int* __restrict__ lst) {
  constexpr int K  = MODE ? 1024 : 512;
  constexpr int Nn = MODE ? 512 : 1024;
  int e = blockIdx.z;
  int c = cnt[e];
  int m0 = blockIdx.x * 128;
  if (m0 >= c) return;
  int off = 0;
#pragma unroll
  for (int i = 0; i < E_; ++i) if (i < e) off += cnt[i];
  int n0 = blockIdx.y * 128;
  __shared__ unsigned short As[128][40];
  __shared__ unsigned short Bs[128][40];
  int tid = threadIdx.x;
  int w = tid >> 6, l = tid & 63;
  int wr = w >> 1, wc = w & 1;
  int sr = tid >> 1, sh = (tid & 1) * 16;
  int ar = m0 + sr; if (ar > c - 1) ar = c - 1;
  const unsigned short* Ap;
  if (MODE == 0) Ap = Abase + (size_t)(lst[e * N_ + ar] >> 1) * 512;
  else           Ap = Abase + (size_t)(off + ar) * 1024;
  const unsigned short* Bp = Wt + (size_t)e * K * Nn + (size_t)(n0 + sr) * K;
  f32x4 acc[4][4];
#pragma unroll
  for (int m = 0; m < 4; ++m)
#pragma unroll
    for (int n = 0; n < 4; ++n) acc[m][n] = (f32x4){0.f, 0.f, 0.f, 0.f};
  for (int k0 = 0; k0 < K; k0 += 32) {
    short8 av0 = *(const short8*)&Ap[k0 + sh];
    short8 av1 = *(const short8*)&Ap[k0 + sh + 8];
    short8 bv0 = *(const short8*)&Bp[k0 + sh];
    short8 bv1 = *(const short8*)&Bp[k0 + sh + 8];
    __syncthreads();
    *(short8*)&As[sr][sh] = av0;
    *(short8*)&As[sr][sh + 8] = av1;
    *(short8*)&Bs[sr][sh] = bv0;
    *(short8*)&Bs[sr][sh + 8] = bv1;
    __syncthreads();
    short8 a[4], bfr[4];
#pragma unroll
    for (int m = 0; m < 4; ++m)
      a[m] = *(const short8*)&As[wr * 64 + m * 16 + (l & 15)][(l >> 4) * 8];
#pragma unroll
    for (int n = 0; n < 4; ++n)
      bfr[n] = *(const short8*)&Bs[wc * 64 + n * 16 + (l & 15)][(l >> 4) * 8];
#pragma unroll
    for (int m = 0; m < 4; ++m)
#pragma unroll
      for (int n = 0; n < 4; ++n)
        acc[m][n] = __builtin_amdgcn_mfma_f32_16x16x32_bf16(a[m], bfr[n], acc[m][n], 0, 0, 0);
  }
#pragma unroll
  for (int m = 0; m < 4; ++m)
#pragma unroll
    for (int n = 0; n < 4; ++n)
#pragma unroll
      for (int i = 0; i < 4; ++i) {
        int r = m0 + wr * 64 + m * 16 + (l >> 4) * 4 + i;
        if (r < c) {
          int col = n0 + wc * 64 + n * 16 + (l & 15);
          float val = acc[m][n][i] + bias[e * Nn + col];
          if (MODE == 0) {
            val = fmaxf(val, 0.f);
            outp[(size_t)(off + r) * 1024 + col] = f2bf(val);
          } else {
            int p = lst[e * N_ + r];
            outp[(size_t)p * 512 + col] = f2bf(gp[p] * val);
          }
        }
      }
}

// ---------------------------------------------------------------------------
extern "C" void kernel_launch(void* const* d_in, const int* in_sizes, int n_in,
                              void* d_out, int out_size, void* d_ws, size_t ws_size,
                              hipStream_t stream) {
  const float* src  = (const float*)d_in[0];
  const float* cosb = (const float*)d_in[1];
  const float* sinb = (const float*)d_in[2];
  const float* Wq   = (const float*)d_in[3];
  const float* bq   = (const float*)d_in[4];
  const float* Wk   = (const float*)d_in[5];
  const float* bk   = (const float*)d_in[6];
  const float* Wv   = (const float*)d_in[7];
  const float* bv   = (const float*)d_in[8];
  const float* Wo   = (const float*)d_in[9];
  const float* bo   = (const float*)d_in[10];
  const float* ln1g = (const float*)d_in[11];
  const float* ln1b = (const float*)d_in[12];
  const float* ln2g = (const float*)d_in[13];
  const float* ln2b = (const float*)d_in[14];
  const float* Wg   = (const float*)d_in[15];
  const float* W1   = (const float*)d_in[16];
  const float* B1   = (const float*)d_in[17];
  const float* W2   = (const float*)d_in[18];
  const float* B2   = (const float*)d_in[19];
  float* out = (float*)d_out;
  float* ws = (float*)d_ws;

  const size_t ND = (size_t)N_ * D_;  // 2,097,152 floats
  float* qb   = ws;                        // [0,2M)   q f32; later attn_out
  float* kb   = ws + ND;                   // [2M,4M)
  float* vb   = ws + 2 * ND;               // [4M,6M)
  float* ctxb = ws + 3 * ND;               // [6M,8M)  ctx f32; later mp (bf16)
  float* aob  = qb;
  unsigned short* mp = (unsigned short*)(ws + 3 * ND);
  float* xb   = ws + 4 * ND;               // [8M,10M) LN1 out f32
  unsigned short* xbf = (unsigned short*)(ws + 5 * ND);            // [10M,11M)
  unsigned short* W1t = (unsigned short*)(ws + 5 * ND + ND / 2);   // [11M,13M)
  unsigned short* W2t = (unsigned short*)(ws + 6 * ND + ND / 2);   // [13M,15M)
  float* gpb  = ws + 7 * ND + ND / 2 + 131072;
  int*   cnt  = (int*)(gpb + NPAIR_);
  int*   lst  = cnt + 16;
  unsigned short* hbf = (unsigned short*)(ws + ND);  // [2M,6M) alias kb/vb, after attn

  hipMemsetAsync(cnt, 0, 16 * sizeof(int), stream);

  dim3 blk(256);
  // QKV projections (f32 — precision-critical)
  gemm_bias<<<dim3(64, 8), blk, 0, stream>>>(src, Wq, bq, qb, N_, D_, D_);
  gemm_bias<<<dim3(64, 8), blk, 0, stream>>>(src, Wk, bk, kb, N_, D_, D_);
  gemm_bias<<<dim3(64, 8), blk, 0, stream>>>(src, Wv, bv, vb, N_, D_, D_);
  rope_k<<<dim3(8192), blk, 0, stream>>>(qb, kb, cosb, sinb);
  // Attention — split-bf16 MFMA flash
  attn_mfma<<<dim3(S_ / 64, 16), blk, 0, stream>>>(qb, kb, vb, ctxb);
  // Output projection (f32)
  gemm_bias<<<dim3(64, 8), blk, 0, stream>>>(ctxb, Wo, bo, aob, N_, D_, D_);
  // LN1 (+bf16 copy of x)
  ln_res<<<dim3(1024), blk, 0, stream>>>(src, aob, ln1g, ln1b, xb, xbf);
  // MoE weight transposes to bf16
  wtrans<<<dim3(16, 8, 8), blk, 0, stream>>>(W1, W1t, 512, 1024);
  wtrans<<<dim3(8, 16, 8), blk, 0, stream>>>(W2, W2t, 1024, 512);
  // Gate + route (f32)
  gate_route<<<dim3(1024), blk, 0, stream>>>(xb, Wg, gpb, cnt, lst);
  // Sparse MoE expert GEMMs — bf16 MFMA
  moe_mfma<0><<<dim3(32, 8, 8), blk, 0, stream>>>(xbf, W1t, B1, gpb, hbf, cnt, lst);
  moe_mfma<1><<<dim3(32, 4, 8), blk, 0, stream>>>(hbf, W2t, B2, gpb, mp, cnt, lst);
  // Final LN
  ln2_final<<<dim3(1024), blk, 0, stream>>>(xb, mp, ln2g, ln2b, out);
}

// Round 5
// 452.160 us; speedup vs baseline: 2.5903x; 1.2750x over previous
//
#include <hip/hip_runtime.h>
#include <math.h>

// Shapes (fixed)
#define S_  2048
#define B_  2
#define D_  512
#define H_  8
#define DH_ 64
#define E_  8
#define F_  1024
#define N_  4096   // S_*B_
#define NPAIR_ 8192

typedef __attribute__((ext_vector_type(4))) float f32x4;
typedef __attribute__((ext_vector_type(8))) short short8;
typedef unsigned short u16;

__device__ __forceinline__ u16 f2bf(float f) {
  unsigned u = __builtin_bit_cast(unsigned, f);
  u += 0x7fffu + ((u >> 16) & 1u);
  return (u16)(u >> 16);
}
__device__ __forceinline__ float bf2f(u16 h) {
  unsigned u = ((unsigned)h) << 16;
  return __builtin_bit_cast(float, u);
}

// ---------------------------------------------------------------------------
// src -> split bf16 (hi, lo). 2M elements, 8/thread.
// ---------------------------------------------------------------------------
__global__ __launch_bounds__(256) void src_split(const float* __restrict__ in,
                                                 u16* __restrict__ hi,
                                                 u16* __restrict__ lo) {
  size_t i = ((size_t)blockIdx.x * 256 + threadIdx.x) * 8;
  float f[8];
  *(float4*)&f[0] = *(const float4*)&in[i];
  *(float4*)&f[4] = *(const float4*)&in[i + 4];
  short8 h, l;
#pragma unroll
  for (int j = 0; j < 8; ++j) {
    u16 a = f2bf(f[j]);
    h[j] = (short)a;
    l[j] = (short)f2bf(f[j] - bf2f(a));
  }
  *(short8*)&hi[i] = h;
  *(short8*)&lo[i] = l;
}

// ---------------------------------------------------------------------------
// Weight transpose + split: Whi/Wlo[n][k] = split(W[k][n]). W is [K][Nn].
// grid (Nn/64, K/64).
// ---------------------------------------------------------------------------
__global__ __launch_bounds__(256) void wsplit_t(const float* __restrict__ W,
                                                u16* __restrict__ Whi,
                                                u16* __restrict__ Wlo,
                                                int Nn, int K) {
  __shared__ u16 Th[64][72];
  __shared__ u16 Tl[64][72];
  int kb = blockIdx.y * 64, nb = blockIdx.x * 64;
  int r = threadIdx.x >> 2, c0 = (threadIdx.x & 3) * 16;
  const float* wp = &W[(size_t)(kb + r) * Nn + nb + c0];
#pragma unroll
  for (int c = 0; c < 16; c += 4) {
    float4 t = *(const float4*)&wp[c];
    float f[4] = {t.x, t.y, t.z, t.w};
#pragma unroll
    for (int j = 0; j < 4; ++j) {
      u16 a = f2bf(f[j]);
      Th[r][c0 + c + j] = a;
      Tl[r][c0 + c + j] = f2bf(f[j] - bf2f(a));
    }
  }
  __syncthreads();
  short8 h0, h1, l0, l1;
#pragma unroll
  for (int j = 0; j < 8; ++j) {
    h0[j] = (short)Th[c0 + j][r];     h1[j] = (short)Th[c0 + 8 + j][r];
    l0[j] = (short)Tl[c0 + j][r];     l1[j] = (short)Tl[c0 + 8 + j][r];
  }
  size_t ob = (size_t)(nb + r) * K + kb + c0;
  *(short8*)&Whi[ob] = h0;  *(short8*)&Whi[ob + 8] = h1;
  *(short8*)&Wlo[ob] = l0;  *(short8*)&Wlo[ob + 8] = l1;
}

// ---------------------------------------------------------------------------
// Plain bf16 weight transpose for MoE (W1, W2).
// ---------------------------------------------------------------------------
__global__ __launch_bounds__(256) void wtrans(const float* __restrict__ W,
                                              u16* __restrict__ Wt,
                                              int K, int Nn) {
  size_t eo = (size_t)blockIdx.z * K * Nn;
  __shared__ u16 T[64][72];
  int kb = blockIdx.y * 64, nb = blockIdx.x * 64;
  int r = threadIdx.x >> 2, c0 = (threadIdx.x & 3) * 16;
  const float* wp = &W[eo + (size_t)(kb + r) * Nn + nb + c0];
#pragma unroll
  for (int c = 0; c < 16; c += 4) {
    float4 t = *(const float4*)&wp[c];
    T[r][c0 + c + 0] = f2bf(t.x);
    T[r][c0 + c + 1] = f2bf(t.y);
    T[r][c0 + c + 2] = f2bf(t.z);
    T[r][c0 + c + 3] = f2bf(t.w);
  }
  __syncthreads();
  short8 s0, s1;
#pragma unroll
  for (int j = 0; j < 8; ++j) {
    s0[j] = (short)T[c0 + j][r];
    s1[j] = (short)T[c0 + 8 + j][r];
  }
  *(short8*)&Wt[eo + (size_t)(nb + r) * K + kb + c0] = s0;
  *(short8*)&Wt[eo + (size_t)(nb + r) * K + kb + c0 + 8] = s1;
}

// ---------------------------------------------------------------------------
// Fused QKV split-bf16 MFMA GEMM + RoPE. M=4096, N=1536, K=512.
// 128x128 tile, BK=32, 4 waves 2x2, 3-product split precision.
// Outputs: qh/ql, kh/kl (RoPE'd, q scaled 1/8, split bf16), vb (bf16).
// ---------------------------------------------------------------------------
__global__ __launch_bounds__(256) void qkv_mfma(const u16* __restrict__ Ah_g,
                                                const u16* __restrict__ Al_g,
                                                const u16* __restrict__ Bh_g,
                                                const u16* __restrict__ Bl_g,
                                                const float* __restrict__ bq,
                                                const float* __restrict__ bk,
                                                const float* __restrict__ bv,
                                                const float* __restrict__ cosb,
                                                const float* __restrict__ sinb,
                                                u16* __restrict__ qh, u16* __restrict__ ql,
                                                u16* __restrict__ kh, u16* __restrict__ kl,
                                                u16* __restrict__ vb) {
  __shared__ u16 Ah[128][40], Al[128][40], Bh[128][40], Bl[128][40];
  int tid = threadIdx.x;
  int w = tid >> 6, l = tid & 63;
  int wr = w >> 1, wc = w & 1;
  int lg = l >> 4, lx = l & 15;
  int m0 = blockIdx.x * 128, n0 = blockIdx.y * 128;
  int sr = tid >> 1, s16 = (tid & 1) * 16;
  const u16* Aph = Ah_g + (size_t)(m0 + sr) * 512;
  const u16* Apl = Al_g + (size_t)(m0 + sr) * 512;
  const u16* Bph = Bh_g + (size_t)(n0 + sr) * 512;
  const u16* Bpl = Bl_g + (size_t)(n0 + sr) * 512;
  f32x4 acc[4][4];
#pragma unroll
  for (int m = 0; m < 4; ++m)
#pragma unroll
    for (int n = 0; n < 4; ++n) acc[m][n] = (f32x4){0.f, 0.f, 0.f, 0.f};
  for (int k0 = 0; k0 < 512; k0 += 32) {
    short8 ah0 = *(const short8*)&Aph[k0 + s16];
    short8 ah1 = *(const short8*)&Aph[k0 + s16 + 8];
    short8 al0 = *(const short8*)&Apl[k0 + s16];
    short8 al1 = *(const short8*)&Apl[k0 + s16 + 8];
    short8 bh0 = *(const short8*)&Bph[k0 + s16];
    short8 bh1 = *(const short8*)&Bph[k0 + s16 + 8];
    short8 bl0 = *(const short8*)&Bpl[k0 + s16];
    short8 bl1 = *(const short8*)&Bpl[k0 + s16 + 8];
    __syncthreads();
    *(short8*)&Ah[sr][s16] = ah0; *(short8*)&Ah[sr][s16 + 8] = ah1;
    *(short8*)&Al[sr][s16] = al0; *(short8*)&Al[sr][s16 + 8] = al1;
    *(short8*)&Bh[sr][s16] = bh0; *(short8*)&Bh[sr][s16 + 8] = bh1;
    *(short8*)&Bl[sr][s16] = bl0; *(short8*)&Bl[sr][s16 + 8] = bl1;
    __syncthreads();
    short8 fah[4], fal[4], fbh[4], fbl[4];
#pragma unroll
    for (int m = 0; m < 4; ++m) {
      fah[m] = *(const short8*)&Ah[wr * 64 + m * 16 + lx][lg * 8];
      fal[m] = *(const short8*)&Al[wr * 64 + m * 16 + lx][lg * 8];
    }
#pragma unroll
    for (int n = 0; n < 4; ++n) {
      fbh[n] = *(const short8*)&Bh[wc * 64 + n * 16 + lx][lg * 8];
      fbl[n] = *(const short8*)&Bl[wc * 64 + n * 16 + lx][lg * 8];
    }
#pragma unroll
    for (int m = 0; m < 4; ++m)
#pragma unroll
      for (int n = 0; n < 4; ++n) {
        acc[m][n] = __builtin_amdgcn_mfma_f32_16x16x32_bf16(fah[m], fbh[n], acc[m][n], 0, 0, 0);
        acc[m][n] = __builtin_amdgcn_mfma_f32_16x16x32_bf16(fal[m], fbh[n], acc[m][n], 0, 0, 0);
        acc[m][n] = __builtin_amdgcn_mfma_f32_16x16x32_bf16(fah[m], fbl[n], acc[m][n], 0, 0, 0);
      }
  }
  // ---- epilogue: bias + (RoPE + split for q/k) or bf16 store for v ----
  int tcolbase = n0 + wc * 64;          // multiple of 64
  int tsel = tcolbase >> 9;             // 0=q, 1=k, 2=v
  int hbase = tcolbase & 511;           // head-aligned col within tensor
  const float* bias = (tsel == 0) ? bq : (tsel == 1) ? bk : bv;
  if (tsel == 2) {
#pragma unroll
    for (int m = 0; m < 4; ++m)
#pragma unroll
      for (int i = 0; i < 4; ++i) {
        int row = m0 + wr * 64 + m * 16 + lg * 4 + i;
#pragma unroll
        for (int n = 0; n < 4; ++n) {
          int col = hbase + n * 16 + lx;
          vb[(size_t)row * 512 + col] = f2bf(acc[m][n][i] + bias[col]);
        }
      }
  } else {
    u16* oh = tsel ? kh : qh;
    u16* ol = tsel ? kl : ql;
    float qsc = tsel ? 1.f : 0.125f;
#pragma unroll
    for (int m = 0; m < 4; ++m)
#pragma unroll
      for (int i = 0; i < 4; ++i) {
        int row = m0 + wr * 64 + m * 16 + lg * 4 + i;
        int s = row >> 1;
#pragma unroll
        for (int n = 0; n < 2; ++n) {
          int dln = n * 16 + lx;        // 0..31
          float c  = cosb[s * 64 + dln];
          float sn = sinb[s * 64 + dln];
          float a  = acc[m][n][i]     + bias[hbase + dln];
          float b2 = acc[m][n + 2][i] + bias[hbase + dln + 32];
          float ra = (a * c - b2 * sn) * qsc;
          float rb = (b2 * c + a * sn) * qsc;
          size_t ix = (size_t)row * 512 + hbase + dln;
          u16 rah = f2bf(ra);
          oh[ix] = rah; ol[ix] = f2bf(ra - bf2f(rah));
          u16 rbh = f2bf(rb);
          oh[ix + 32] = rbh; ol[ix + 32] = f2bf(rb - bf2f(rbh));
        }
      }
  }
}

// ---------------------------------------------------------------------------
// MFMA flash attention, KV-split=2. Inputs pre-split bf16 q/k, bf16 v.
// QT=64 (4 waves x 16 rows), KT=64, 16 tiles per half.
// Writes split-bf16 unnormalized partial O + (m,l).
// ---------------------------------------------------------------------------
__global__ __launch_bounds__(256) void attn_mfma2(const u16* __restrict__ qh,
                                                  const u16* __restrict__ ql,
                                                  const u16* __restrict__ kh,
                                                  const u16* __restrict__ kl,
                                                  const u16* __restrict__ vbuf,
                                                  u16* __restrict__ poh,
                                                  u16* __restrict__ pol,
                                                  float* __restrict__ pml) {
  __shared__ u16 Khi[64][72];
  __shared__ u16 Klo[64][72];
  __shared__ u16 Vt[64][72];
  __shared__ u16 Pl[4][16][72];
  int tid = threadIdx.x;
  int w = tid >> 6, l = tid & 63;
  int lg = l >> 4, lx = l & 15;
  int qt = blockIdx.x, bh = blockIdx.y, kvh = blockIdx.z;
  int b = bh >> 3, h = bh & 7;

  short8 qfh[2], qfl[2];
  {
    int qrow = qt * 64 + w * 16 + lx;
    size_t qo = (size_t)(qrow * 2 + b) * 512 + h * 64 + lg * 8;
    qfh[0] = *(const short8*)&qh[qo];
    qfh[1] = *(const short8*)&qh[qo + 32];
    qfl[0] = *(const short8*)&ql[qo];
    qfl[1] = *(const short8*)&ql[qo + 32];
  }

  f32x4 o_acc[4];
#pragma unroll
  for (int dg = 0; dg < 4; ++dg) o_acc[dg] = (f32x4){0.f, 0.f, 0.f, 0.f};
  float m_run[4], l_run[4];
#pragma unroll
  for (int i = 0; i < 4; ++i) { m_run[i] = -1e30f; l_run[i] = 0.f; }

  int kvr = tid >> 2, ds4 = (tid & 3) * 16;
  int kvc = tid & 63, dsg = (tid >> 6) * 16;

  for (int tt = 0; tt < 1024; tt += 64) {
    int t0 = kvh * 1024 + tt;
    __syncthreads();
    {
      size_t ko = (size_t)((t0 + kvr) * 2 + b) * 512 + h * 64 + ds4;
      *(short8*)&Khi[kvr][ds4]     = *(const short8*)&kh[ko];
      *(short8*)&Khi[kvr][ds4 + 8] = *(const short8*)&kh[ko + 8];
      *(short8*)&Klo[kvr][ds4]     = *(const short8*)&kl[ko];
      *(short8*)&Klo[kvr][ds4 + 8] = *(const short8*)&kl[ko + 8];
      size_t vo = (size_t)((t0 + kvc) * 2 + b) * 512 + h * 64 + dsg;
      short8 v0 = *(const short8*)&vbuf[vo];
      short8 v1 = *(const short8*)&vbuf[vo + 8];
#pragma unroll
      for (int c = 0; c < 8; ++c) {
        Vt[dsg + c][kvc] = (u16)v0[c];
        Vt[dsg + 8 + c][kvc] = (u16)v1[c];
      }
    }
    __syncthreads();

    f32x4 sc[4];
#pragma unroll
    for (int cg = 0; cg < 4; ++cg) {
      short8 kh0 = *(const short8*)&Khi[cg * 16 + lx][lg * 8];
      short8 kh1 = *(const short8*)&Khi[cg * 16 + lx][32 + lg * 8];
      short8 kl0 = *(const short8*)&Klo[cg * 16 + lx][lg * 8];
      short8 kl1 = *(const short8*)&Klo[cg * 16 + lx][32 + lg * 8];
      f32x4 a = (f32x4){0.f, 0.f, 0.f, 0.f};
      a = __builtin_amdgcn_mfma_f32_16x16x32_bf16(qfh[0], kh0, a, 0, 0, 0);
      a = __builtin_amdgcn_mfma_f32_16x16x32_bf16(qfh[1], kh1, a, 0, 0, 0);
      a = __builtin_amdgcn_mfma_f32_16x16x32_bf16(qfl[0], kh0, a, 0, 0, 0);
      a = __builtin_amdgcn_mfma_f32_16x16x32_bf16(qfl[1], kh1, a, 0, 0, 0);
      a = __builtin_amdgcn_mfma_f32_16x16x32_bf16(qfh[0], kl0, a, 0, 0, 0);
      a = __builtin_amdgcn_mfma_f32_16x16x32_bf16(qfh[1], kl1, a, 0, 0, 0);
      sc[cg] = a;
    }

#pragma unroll
    for (int i = 0; i < 4; ++i) {
      float s0 = sc[0][i], s1 = sc[1][i], s2 = sc[2][i], s3 = sc[3][i];
      float tm = fmaxf(fmaxf(s0, s1), fmaxf(s2, s3));
      tm = fmaxf(tm, __shfl_xor(tm, 1));
      tm = fmaxf(tm, __shfl_xor(tm, 2));
      tm = fmaxf(tm, __shfl_xor(tm, 4));
      tm = fmaxf(tm, __shfl_xor(tm, 8));
      float mn = fmaxf(m_run[i], tm);
      float corr = __expf(m_run[i] - mn);
      m_run[i] = mn;
      float p0 = __expf(s0 - mn), p1 = __expf(s1 - mn);
      float p2 = __expf(s2 - mn), p3 = __expf(s3 - mn);
      float ts = p0 + p1 + p2 + p3;
      ts += __shfl_xor(ts, 1); ts += __shfl_xor(ts, 2);
      ts += __shfl_xor(ts, 4); ts += __shfl_xor(ts, 8);
      l_run[i] = l_run[i] * corr + ts;
#pragma unroll
      for (int dg = 0; dg < 4; ++dg) o_acc[dg][i] *= corr;
      int row = lg * 4 + i;
      Pl[w][row][lx]      = f2bf(p0);
      Pl[w][row][16 + lx] = f2bf(p1);
      Pl[w][row][32 + lx] = f2bf(p2);
      Pl[w][row][48 + lx] = f2bf(p3);
    }

    short8 pa0 = *(const short8*)&Pl[w][lx][lg * 8];
    short8 pa1 = *(const short8*)&Pl[w][lx][32 + lg * 8];
#pragma unroll
    for (int dg = 0; dg < 4; ++dg) {
      short8 v0 = *(const short8*)&Vt[dg * 16 + lx][lg * 8];
      short8 v1 = *(const short8*)&Vt[dg * 16 + lx][32 + lg * 8];
      o_acc[dg] = __builtin_amdgcn_mfma_f32_16x16x32_bf16(pa0, v0, o_acc[dg], 0, 0, 0);
      o_acc[dg] = __builtin_amdgcn_mfma_f32_16x16x32_bf16(pa1, v1, o_acc[dg], 0, 0, 0);
    }
  }

#pragma unroll
  for (int i = 0; i < 4; ++i) {
    int srow = qt * 64 + w * 16 + lg * 4 + i;
    int row2 = srow * 2 + b;
    size_t base = (size_t)kvh * ((size_t)N_ * D_) + (size_t)row2 * 512 + h * 64;
#pragma unroll
    for (int dg = 0; dg < 4; ++dg) {
      float val = o_acc[dg][i];
      u16 hi = f2bf(val);
      poh[base + dg * 16 + lx] = hi;
      pol[base + dg * 16 + lx] = f2bf(val - bf2f(hi));
    }
    if (lx == 0) {
      int u = row2 * 8 + h;
      pml[(size_t)kvh * 65536 + u * 2 + 0] = m_run[i];
      pml[(size_t)kvh * 65536 + u * 2 + 1] = l_run[i];
    }
  }
}

// Merge the two KV halves -> split-bf16 ctx.
__global__ __launch_bounds__(256) void merge_attn2(const u16* __restrict__ poh,
                                                   const u16* __restrict__ pol,
                                                   const float* __restrict__ pml,
                                                   u16* __restrict__ ch,
                                                   u16* __restrict__ cl) {
  int u = blockIdx.x * 4 + (threadIdx.x >> 6);
  int lane = threadIdx.x & 63;
  float m0 = pml[u * 2], l0 = pml[u * 2 + 1];
  float m1 = pml[65536 + u * 2], l1 = pml[65536 + u * 2 + 1];
  float m = fmaxf(m0, m1);
  float e0 = __expf(m0 - m), e1 = __expf(m1 - m);
  float inv = 1.f / (l0 * e0 + l1 * e1);
  int n = u >> 3, h = u & 7;
  size_t base = (size_t)n * 512 + h * 64 + lane;
  const size_t PO1 = (size_t)N_ * D_;
  float v0 = bf2f(poh[base]) + bf2f(pol[base]);
  float v1 = bf2f(poh[PO1 + base]) + bf2f(pol[PO1 + base]);
  float val = (v0 * e0 + v1 * e1) * inv;
  u16 hi = f2bf(val);
  ch[base] = hi;
  cl[base] = f2bf(val - bf2f(hi));
}

// ---------------------------------------------------------------------------
// Wo projection: split-bf16 MFMA GEMM, M=4096, N=512, K=512, f32 out.
// ---------------------------------------------------------------------------
__global__ __launch_bounds__(256) void wo_mfma(const u16* __restrict__ Ah_g,
                                               const u16* __restrict__ Al_g,
                                               const u16* __restrict__ Bh_g,
                                               const u16* __restrict__ Bl_g,
                                               const float* __restrict__ bias,
                                               float* __restrict__ C) {
  __shared__ u16 Ah[128][40], Al[128][40], Bh[128][40], Bl[128][40];
  int tid = threadIdx.x;
  int w = tid >> 6, l = tid & 63;
  int wr = w >> 1, wc = w & 1;
  int lg = l >> 4, lx = l & 15;
  int m0 = blockIdx.x * 128, n0 = blockIdx.y * 128;
  int sr = tid >> 1, s16 = (tid & 1) * 16;
  const u16* Aph = Ah_g + (size_t)(m0 + sr) * 512;
  const u16* Apl = Al_g + (size_t)(m0 + sr) * 512;
  const u16* Bph = Bh_g + (size_t)(n0 + sr) * 512;
  const u16* Bpl = Bl_g + (size_t)(n0 + sr) * 512;
  f32x4 acc[4][4];
#pragma unroll
  for (int m = 0; m < 4; ++m)
#pragma unroll
    for (int n = 0; n < 4; ++n) acc[m][n] = (f32x4){0.f, 0.f, 0.f, 0.f};
  for (int k0 = 0; k0 < 512; k0 += 32) {
    short8 ah0 = *(const short8*)&Aph[k0 + s16];
    short8 ah1 = *(const short8*)&Aph[k0 + s16 + 8];
    short8 al0 = *(const short8*)&Apl[k0 + s16];
    short8 al1 = *(const short8*)&Apl[k0 + s16 + 8];
    short8 bh0 = *(const short8*)&Bph[k0 + s16];
    short8 bh1 = *(const short8*)&Bph[k0 + s16 + 8];
    short8 bl0 = *(const short8*)&Bpl[k0 + s16];
    short8 bl1 = *(const short8*)&Bpl[k0 + s16 + 8];
    __syncthreads();
    *(short8*)&Ah[sr][s16] = ah0; *(short8*)&Ah[sr][s16 + 8] = ah1;
    *(short8*)&Al[sr][s16] = al0; *(short8*)&Al[sr][s16 + 8] = al1;
    *(short8*)&Bh[sr][s16] = bh0; *(short8*)&Bh[sr][s16 + 8] = bh1;
    *(short8*)&Bl[sr][s16] = bl0; *(short8*)&Bl[sr][s16 + 8] = bl1;
    __syncthreads();
    short8 fah[4], fal[4], fbh[4], fbl[4];
#pragma unroll
    for (int m = 0; m < 4; ++m) {
      fah[m] = *(const short8*)&Ah[wr * 64 + m * 16 + lx][lg * 8];
      fal[m] = *(const short8*)&Al[wr * 64 + m * 16 + lx][lg * 8];
    }
#pragma unroll
    for (int n = 0; n < 4; ++n) {
      fbh[n] = *(const short8*)&Bh[wc * 64 + n * 16 + lx][lg * 8];
      fbl[n] = *(const short8*)&Bl[wc * 64 + n * 16 + lx][lg * 8];
    }
#pragma unroll
    for (int m = 0; m < 4; ++m)
#pragma unroll
      for (int n = 0; n < 4; ++n) {
        acc[m][n] = __builtin_amdgcn_mfma_f32_16x16x32_bf16(fah[m], fbh[n], acc[m][n], 0, 0, 0);
        acc[m][n] = __builtin_amdgcn_mfma_f32_16x16x32_bf16(fal[m], fbh[n], acc[m][n], 0, 0, 0);
        acc[m][n] = __builtin_amdgcn_mfma_f32_16x16x32_bf16(fah[m], fbl[n], acc[m][n], 0, 0, 0);
      }
  }
#pragma unroll
  for (int m = 0; m < 4; ++m)
#pragma unroll
    for (int i = 0; i < 4; ++i) {
      int row = m0 + wr * 64 + m * 16 + lg * 4 + i;
#pragma unroll
      for (int n = 0; n < 4; ++n) {
        int col = n0 + wc * 64 + n * 16 + lx;
        C[(size_t)row * 512 + col] = acc[m][n][i] + bias[col];
      }
    }
}

// ---------------------------------------------------------------------------
// LayerNorm with residual + bf16 copy.
// ---------------------------------------------------------------------------
__global__ __launch_bounds__(256) void ln_res(const float* __restrict__ a,
                                              const float* __restrict__ b,
                                              const float* __restrict__ g,
                                              const float* __restrict__ beta,
                                              float* __restrict__ out,
                                              u16* __restrict__ obf) {
  int n = blockIdx.x * 4 + (threadIdx.x >> 6);
  int lane = threadIdx.x & 63;
  float v[8];
  float s = 0.f;
#pragma unroll
  for (int i = 0; i < 8; ++i) {
    int d = lane + 64 * i;
    v[i] = a[(size_t)n * D_ + d] + b[(size_t)n * D_ + d];
    s += v[i];
  }
#pragma unroll
  for (int m = 32; m; m >>= 1) s += __shfl_xor(s, m);
  float mean = s * (1.f / D_);
  float s2 = 0.f;
#pragma unroll
  for (int i = 0; i < 8; ++i) { float t = v[i] - mean; s2 += t * t; }
#pragma unroll
  for (int m = 32; m; m >>= 1) s2 += __shfl_xor(s2, m);
  float r = rsqrtf(s2 * (1.f / D_) + 1e-5f);
#pragma unroll
  for (int i = 0; i < 8; ++i) {
    int d = lane + 64 * i;
    float val = (v[i] - mean) * r * g[d] + beta[d];
    out[(size_t)n * D_ + d] = val;
    obf[(size_t)n * D_ + d] = f2bf(val);
  }
}

__global__ __launch_bounds__(256) void ln2_final(const float* __restrict__ x,
                                                 const u16* __restrict__ mp,
                                                 const float* __restrict__ g,
                                                 const float* __restrict__ beta,
                                                 float* __restrict__ out) {
  int n = blockIdx.x * 4 + (threadIdx.x >> 6);
  int lane = threadIdx.x & 63;
  float v[8];
  float s = 0.f;
#pragma unroll
  for (int i = 0; i < 8; ++i) {
    int d = lane + 64 * i;
    v[i] = x[(size_t)n * D_ + d] + bf2f(mp[(size_t)(2 * n) * D_ + d]) +
           bf2f(mp[(size_t)(2 * n + 1) * D_ + d]);
    s += v[i];
  }
#pragma unroll
  for (int m = 32; m; m >>= 1) s += __shfl_xor(s, m);
  float mean = s * (1.f / D_);
  float s2 = 0.f;
#pragma unroll
  for (int i = 0; i < 8; ++i) { float t = v[i] - mean; s2 += t * t; }
#pragma unroll
  for (int m = 32; m; m >>= 1) s2 += __shfl_xor(s2, m);
  float r = rsqrtf(s2 * (1.f / D_) + 1e-5f);
#pragma unroll
  for (int i = 0; i < 8; ++i) {
    int d = lane + 64 * i;
    out[(size_t)n * D_ + d] = (v[i] - mean) * r * g[d] + beta[d];
  }
}

// ---------------------------------------------------------------------------
// Gate + top-2 routing (f32 — decision-critical).
// ---------------------------------------------------------------------------
__global__ __launch_bounds__(256) void gate_route(const float* __restrict__ x,
                                                  const float* __restrict__ Wg,
                                                  float* __restrict__ gp,
                                                  int* __restrict__ cnt,
                                                  int* __restrict__ lst) {
  int n = blockIdx.x * 4 + (threadIdx.x >> 6);
  int lane = threadIdx.x & 63;
  float p[E_] = {};
  for (int d = lane; d < D_; d += 64) {
    float xv = x[(size_t)n * D_ + d];
    const float* wr = &Wg[(size_t)d * E_];
#pragma unroll
    for (int e = 0; e < E_; ++e) p[e] += xv * wr[e];
  }
#pragma unroll
  for (int e = 0; e < E_; ++e)
#pragma unroll
    for (int m = 32; m; m >>= 1) p[e] += __shfl_xor(p[e], m);
  if (lane == 0) {
    float mx = p[0];
#pragma unroll
    for (int e = 1; e < E_; ++e) mx = fmaxf(mx, p[e]);
    float q[E_];
#pragma unroll
    for (int e = 0; e < E_; ++e) q[e] = expf(p[e] - mx);
    int e1 = 0;
#pragma unroll
    for (int e = 1; e < E_; ++e) if (q[e] > q[e1]) e1 = e;
    int e2 = (e1 == 0) ? 1 : 0;
#pragma unroll
    for (int e = 0; e < E_; ++e) if (e != e1 && q[e] > q[e2]) e2 = e;
    float denom = q[e1] + q[e2];
    float w1 = q[e1] / denom, w2 = q[e2] / denom;
    int s1 = atomicAdd(&cnt[e1], 1);
    lst[e1 * N_ + s1] = n * 2;
    int s2 = atomicAdd(&cnt[e2], 1);
    lst[e2 * N_ + s2] = n * 2 + 1;
    gp[n * 2] = w1;
    gp[n * 2 + 1] = w2;
  }
}

// ---------------------------------------------------------------------------
// bf16 MFMA MoE GEMM, 128x128 tile, BK=32, 4 waves (2x2).
// ---------------------------------------------------------------------------
template <int MODE>
__global__ __launch_bounds__(256) void moe_mfma(const u16* __restrict__ Abase,
                                                const u16* __restrict__ Wt,
                                                const float* __restrict__ bias,
                                                const float* __restrict__ gp,
                                                u16* __restrict__ outp,
                                                const int* __restrict__ cnt,
                                                const int* __restrict__ lst) {
  constexpr int K  = MODE ? 1024 : 512;
  constexpr int Nn = MODE ? 512 : 1024;
  int e = blockIdx.z;
  int c = cnt[e];
  int m0 = blockIdx.x * 128;
  if (m0 >= c) return;
  int off = 0;
#pragma unroll
  for (int i = 0; i < E_; ++i) if (i < e) off += cnt[i];
  int n0 = blockIdx.y * 128;
  __shared__ u16 As[128][40];
  __shared__ u16 Bs[128][40];
  int tid = threadIdx.x;
  int w = tid >> 6, l = tid & 63;
  int wr = w >> 1, wc = w & 1;
  int lg = l >> 4, lx = l & 15;
  int sr = tid >> 1, s16 = (tid & 1) * 16;
  int ar = m0 + sr; if (ar > c - 1) ar = c - 1;
  const u16* Ap;
  if (MODE == 0) Ap = Abase + (size_t)(lst[e * N_ + ar] >> 1) * 512;
  else           Ap = Abase + (size_t)(off + ar) * 1024;
  const u16* Bp = Wt + (size_t)e * K * Nn + (size_t)(n0 + sr) * K;
  f32x4 acc[4][4];
#pragma unroll
  for (int m = 0; m < 4; ++m)
#pragma unroll
    for (int n = 0; n < 4; ++n) acc[m][n] = (f32x4){0.f, 0.f, 0.f, 0.f};
  for (int k0 = 0; k0 < K; k0 += 32) {
    short8 av0 = *(const short8*)&Ap[k0 + s16];
    short8 av1 = *(const short8*)&Ap[k0 + s16 + 8];
    short8 bv0 = *(const short8*)&Bp[k0 + s16];
    short8 bv1 = *(const short8*)&Bp[k0 + s16 + 8];
    __syncthreads();
    *(short8*)&As[sr][s16] = av0;
    *(short8*)&As[sr][s16 + 8] = av1;
    *(short8*)&Bs[sr][s16] = bv0;
    *(short8*)&Bs[sr][s16 + 8] = bv1;
    __syncthreads();
    short8 a[4], bfr[4];
#pragma unroll
    for (int m = 0; m < 4; ++m)
      a[m] = *(const short8*)&As[wr * 64 + m * 16 + lx][lg * 8];
#pragma unroll
    for (int n = 0; n < 4; ++n)
      bfr[n] = *(const short8*)&Bs[wc * 64 + n * 16 + lx][lg * 8];
#pragma unroll
    for (int m = 0; m < 4; ++m)
#pragma unroll
      for (int n = 0; n < 4; ++n)
        acc[m][n] = __builtin_amdgcn_mfma_f32_16x16x32_bf16(a[m], bfr[n], acc[m][n], 0, 0, 0);
  }
#pragma unroll
  for (int m = 0; m < 4; ++m)
#pragma unroll
    for (int n = 0; n < 4; ++n)
#pragma unroll
      for (int i = 0; i < 4; ++i) {
        int r = m0 + wr * 64 + m * 16 + lg * 4 + i;
        if (r < c) {
          int col = n0 + wc * 64 + n * 16 + lx;
          float val = acc[m][n][i] + bias[e * Nn + col];
          if (MODE == 0) {
            val = fmaxf(val, 0.f);
            outp[(size_t)(off + r) * 1024 + col] = f2bf(val);
          } else {
            int p = lst[e * N_ + r];
            outp[(size_t)p * 512 + col] = f2bf(gp[p] * val);
          }
        }
      }
}

// ---------------------------------------------------------------------------
extern "C" void kernel_launch(void* const* d_in, const int* in_sizes, int n_in,
                              void* d_out, int out_size, void* d_ws, size_t ws_size,
                              hipStream_t stream) {
  const float* src  = (const float*)d_in[0];
  const float* cosb = (const float*)d_in[1];
  const float* sinb = (const float*)d_in[2];
  const float* Wq   = (const float*)d_in[3];
  const float* bq   = (const float*)d_in[4];
  const float* Wk   = (const float*)d_in[5];
  const float* bk   = (const float*)d_in[6];
  const float* Wv   = (const float*)d_in[7];
  const float* bv   = (const float*)d_in[8];
  const float* Wo   = (const float*)d_in[9];
  const float* bo   = (const float*)d_in[10];
  const float* ln1g = (const float*)d_in[11];
  const float* ln1b = (const float*)d_in[12];
  const float* ln2g = (const float*)d_in[13];
  const float* ln2b = (const float*)d_in[14];
  const float* Wg   = (const float*)d_in[15];
  const float* W1   = (const float*)d_in[16];
  const float* B1   = (const float*)d_in[17];
  const float* W2   = (const float*)d_in[18];
  const float* B2   = (const float*)d_in[19];
  float* out = (float*)d_out;
  char* wsb = (char*)d_ws;

  const size_t MB1 = 1u << 20;
  // Byte layout (~60.2 MB high-water):
  u16* sh   = (u16*)(wsb + 0 * MB1);      // src hi  [0,4M)   ; later ch
  u16* sl   = (u16*)(wsb + 4 * MB1);      // src lo  [4,8M)   ; later cl
  u16* qhb  = (u16*)(wsb + 8 * MB1);      // [8,12M)          ; later hbf part
  u16* qlb  = (u16*)(wsb + 12 * MB1);
  u16* khb  = (u16*)(wsb + 16 * MB1);
  u16* klb  = (u16*)(wsb + 20 * MB1);
  u16* vbuf = (u16*)(wsb + 24 * MB1);     // [24,28M)
  u16* poh  = (u16*)(wsb + 28 * MB1);     // [28,36M) attn partial hi ; later aob f32
  u16* pol  = (u16*)(wsb + 36 * MB1);     // [36,44M) attn partial lo ; later xb f32
  float* pml = (float*)(wsb + 44 * MB1);  // [44,44.5M)       ; later xbf
  float* aob = (float*)(wsb + 28 * MB1);  // [28,36M)
  float* xb  = (float*)(wsb + 36 * MB1);  // [36,44M)
  u16* xbf   = (u16*)(wsb + 44 * MB1);    // [44,48M)
  u16* Wqkv_hi = (u16*)(wsb + 48 * MB1);              // 1.5MB
  u16* Wqkv_lo = (u16*)(wsb + 48 * MB1 + 1572864);    // 1.5MB
  u16* Wo_hi   = (u16*)(wsb + 48 * MB1 + 3145728);    // 0.5MB
  u16* Wo_lo   = (u16*)(wsb + 48 * MB1 + 3670016);    // 0.5MB
  u16* W1t     = (u16*)(wsb + 52 * MB1);  // [52,60M) ; W2t aliases after moe1
  u16* W2t     = W1t;
  float* gpb   = (float*)(wsb + 60 * MB1);
  int* cnt     = (int*)(wsb + 60 * MB1 + 32768);
  int* lst     = (int*)(wsb + 60 * MB1 + 32768 + 64);
  u16* ch  = sh;                          // ctx hi aliases src-split (dead)
  u16* cl  = sl;
  u16* hbf = (u16*)(wsb + 8 * MB1);       // [8,24M) aliases q/k (dead after attn)
  u16* mp  = (u16*)(wsb + 0 * MB1);       // [0,8M)  aliases ch/cl (dead after wo)

  hipMemsetAsync(cnt, 0, 16 * sizeof(int), stream);

  dim3 blk(256);
  src_split<<<dim3(1024), blk, 0, stream>>>(src, sh, sl);
  wsplit_t<<<dim3(8, 8), blk, 0, stream>>>(Wq, Wqkv_hi, Wqkv_lo, 512, 512);
  wsplit_t<<<dim3(8, 8), blk, 0, stream>>>(Wk, Wqkv_hi + 512 * 512, Wqkv_lo + 512 * 512, 512, 512);
  wsplit_t<<<dim3(8, 8), blk, 0, stream>>>(Wv, Wqkv_hi + 1024 * 512, Wqkv_lo + 1024 * 512, 512, 512);
  wsplit_t<<<dim3(8, 8), blk, 0, stream>>>(Wo, Wo_hi, Wo_lo, 512, 512);
  // QKV + RoPE fused (split-bf16, f32-grade)
  qkv_mfma<<<dim3(32, 12), blk, 0, stream>>>(sh, sl, Wqkv_hi, Wqkv_lo, bq, bk, bv,
                                             cosb, sinb, qhb, qlb, khb, klb, vbuf);
  // Attention, KV-split=2 + merge
  attn_mfma2<<<dim3(32, 16, 2), blk, 0, stream>>>(qhb, qlb, khb, klb, vbuf, poh, pol, pml);
  merge_attn2<<<dim3(8192), blk, 0, stream>>>(poh, pol, pml, ch, cl);
  // Wo projection (split-bf16)
  wo_mfma<<<dim3(32, 4), blk, 0, stream>>>(ch, cl, Wo_hi, Wo_lo, bo, aob);
  // LN1 (+bf16 copy)
  ln_res<<<dim3(1024), blk, 0, stream>>>(src, aob, ln1g, ln1b, xb, xbf);
  // MoE
  wtrans<<<dim3(16, 8, 8), blk, 0, stream>>>(W1, W1t, 512, 1024);
  gate_route<<<dim3(1024), blk, 0, stream>>>(xb, Wg, gpb, cnt, lst);
  moe_mfma<0><<<dim3(32, 8, 8), blk, 0, stream>>>(xbf, W1t, B1, gpb, hbf, cnt, lst);
  wtrans<<<dim3(8, 16, 8), blk, 0, stream>>>(W2, W2t, 1024, 512);
  moe_mfma<1><<<dim3(32, 4, 8), blk, 0, stream>>>(hbf, W2t, B2, gpb, mp, cnt, lst);
  ln2_final<<<dim3(1024), blk, 0, stream>>>(xb, mp, ln2g, ln2b, out);
}

// Round 6
// 365.551 us; speedup vs baseline: 3.2040x; 1.2369x over previous
//
#include <hip/hip_runtime.h>
#include <math.h>

// Shapes (fixed)
#define S_  2048
#define B_  2
#define D_  512
#define H_  8
#define DH_ 64
#define E_  8
#define F_  1024
#define N_  4096   // S_*B_
#define NPAIR_ 8192

typedef __attribute__((ext_vector_type(4))) float f32x4;
typedef __attribute__((ext_vector_type(8))) short short8;
typedef unsigned short u16;

__device__ __forceinline__ u16 f2bf(float f) {
  unsigned u = __builtin_bit_cast(unsigned, f);
  u += 0x7fffu + ((u >> 16) & 1u);
  return (u16)(u >> 16);
}
__device__ __forceinline__ float bf2f(u16 h) {
  unsigned u = ((unsigned)h) << 16;
  return __builtin_bit_cast(float, u);
}

// ---------------------------------------------------------------------------
// src -> split bf16 (hi, lo). 2M elements, 8/thread.
// ---------------------------------------------------------------------------
__global__ __launch_bounds__(256) void src_split(const float* __restrict__ in,
                                                 u16* __restrict__ hi,
                                                 u16* __restrict__ lo) {
  size_t i = ((size_t)blockIdx.x * 256 + threadIdx.x) * 8;
  float f[8];
  *(float4*)&f[0] = *(const float4*)&in[i];
  *(float4*)&f[4] = *(const float4*)&in[i + 4];
  short8 h, l;
#pragma unroll
  for (int j = 0; j < 8; ++j) {
    u16 a = f2bf(f[j]);
    h[j] = (short)a;
    l[j] = (short)f2bf(f[j] - bf2f(a));
  }
  *(short8*)&hi[i] = h;
  *(short8*)&lo[i] = l;
}

// ---------------------------------------------------------------------------
// Weight transpose + split: Whi/Wlo[n][k] = split(W[k][n]). W is [K][Nn].
// ---------------------------------------------------------------------------
__global__ __launch_bounds__(256) void wsplit_t(const float* __restrict__ W,
                                                u16* __restrict__ Whi,
                                                u16* __restrict__ Wlo,
                                                int Nn, int K) {
  __shared__ u16 Th[64][72];
  __shared__ u16 Tl[64][72];
  int kb = blockIdx.y * 64, nb = blockIdx.x * 64;
  int r = threadIdx.x >> 2, c0 = (threadIdx.x & 3) * 16;
  const float* wp = &W[(size_t)(kb + r) * Nn + nb + c0];
#pragma unroll
  for (int c = 0; c < 16; c += 4) {
    float4 t = *(const float4*)&wp[c];
    float f[4] = {t.x, t.y, t.z, t.w};
#pragma unroll
    for (int j = 0; j < 4; ++j) {
      u16 a = f2bf(f[j]);
      Th[r][c0 + c + j] = a;
      Tl[r][c0 + c + j] = f2bf(f[j] - bf2f(a));
    }
  }
  __syncthreads();
  short8 h0, h1, l0, l1;
#pragma unroll
  for (int j = 0; j < 8; ++j) {
    h0[j] = (short)Th[c0 + j][r];     h1[j] = (short)Th[c0 + 8 + j][r];
    l0[j] = (short)Tl[c0 + j][r];     l1[j] = (short)Tl[c0 + 8 + j][r];
  }
  size_t ob = (size_t)(nb + r) * K + kb + c0;
  *(short8*)&Whi[ob] = h0;  *(short8*)&Whi[ob + 8] = h1;
  *(short8*)&Wlo[ob] = l0;  *(short8*)&Wlo[ob + 8] = l1;
}

// ---------------------------------------------------------------------------
// Plain bf16 weight transpose for MoE (W1, W2).
// ---------------------------------------------------------------------------
__global__ __launch_bounds__(256) void wtrans(const float* __restrict__ W,
                                              u16* __restrict__ Wt,
                                              int K, int Nn) {
  size_t eo = (size_t)blockIdx.z * K * Nn;
  __shared__ u16 T[64][72];
  int kb = blockIdx.y * 64, nb = blockIdx.x * 64;
  int r = threadIdx.x >> 2, c0 = (threadIdx.x & 3) * 16;
  const float* wp = &W[eo + (size_t)(kb + r) * Nn + nb + c0];
#pragma unroll
  for (int c = 0; c < 16; c += 4) {
    float4 t = *(const float4*)&wp[c];
    T[r][c0 + c + 0] = f2bf(t.x);
    T[r][c0 + c + 1] = f2bf(t.y);
    T[r][c0 + c + 2] = f2bf(t.z);
    T[r][c0 + c + 3] = f2bf(t.w);
  }
  __syncthreads();
  short8 s0, s1;
#pragma unroll
  for (int j = 0; j < 8; ++j) {
    s0[j] = (short)T[c0 + j][r];
    s1[j] = (short)T[c0 + 8 + j][r];
  }
  *(short8*)&Wt[eo + (size_t)(nb + r) * K + kb + c0] = s0;
  *(short8*)&Wt[eo + (size_t)(nb + r) * K + kb + c0 + 8] = s1;
}

// ---------------------------------------------------------------------------
// Fused QKV split-bf16 MFMA GEMM + RoPE. M=4096, N=1536, K=512.
// ---------------------------------------------------------------------------
__global__ __launch_bounds__(256) void qkv_mfma(const u16* __restrict__ Ah_g,
                                                const u16* __restrict__ Al_g,
                                                const u16* __restrict__ Bh_g,
                                                const u16* __restrict__ Bl_g,
                                                const float* __restrict__ bq,
                                                const float* __restrict__ bk,
                                                const float* __restrict__ bv,
                                                const float* __restrict__ cosb,
                                                const float* __restrict__ sinb,
                                                u16* __restrict__ qh, u16* __restrict__ ql,
                                                u16* __restrict__ kh, u16* __restrict__ kl,
                                                u16* __restrict__ vb) {
  __shared__ u16 Ah[128][40], Al[128][40], Bh[128][40], Bl[128][40];
  int tid = threadIdx.x;
  int w = tid >> 6, l = tid & 63;
  int wr = w >> 1, wc = w & 1;
  int lg = l >> 4, lx = l & 15;
  int m0 = blockIdx.x * 128, n0 = blockIdx.y * 128;
  int sr = tid >> 1, s16 = (tid & 1) * 16;
  const u16* Aph = Ah_g + (size_t)(m0 + sr) * 512;
  const u16* Apl = Al_g + (size_t)(m0 + sr) * 512;
  const u16* Bph = Bh_g + (size_t)(n0 + sr) * 512;
  const u16* Bpl = Bl_g + (size_t)(n0 + sr) * 512;
  f32x4 acc[4][4];
#pragma unroll
  for (int m = 0; m < 4; ++m)
#pragma unroll
    for (int n = 0; n < 4; ++n) acc[m][n] = (f32x4){0.f, 0.f, 0.f, 0.f};
  for (int k0 = 0; k0 < 512; k0 += 32) {
    short8 ah0 = *(const short8*)&Aph[k0 + s16];
    short8 ah1 = *(const short8*)&Aph[k0 + s16 + 8];
    short8 al0 = *(const short8*)&Apl[k0 + s16];
    short8 al1 = *(const short8*)&Apl[k0 + s16 + 8];
    short8 bh0 = *(const short8*)&Bph[k0 + s16];
    short8 bh1 = *(const short8*)&Bph[k0 + s16 + 8];
    short8 bl0 = *(const short8*)&Bpl[k0 + s16];
    short8 bl1 = *(const short8*)&Bpl[k0 + s16 + 8];
    __syncthreads();
    *(short8*)&Ah[sr][s16] = ah0; *(short8*)&Ah[sr][s16 + 8] = ah1;
    *(short8*)&Al[sr][s16] = al0; *(short8*)&Al[sr][s16 + 8] = al1;
    *(short8*)&Bh[sr][s16] = bh0; *(short8*)&Bh[sr][s16 + 8] = bh1;
    *(short8*)&Bl[sr][s16] = bl0; *(short8*)&Bl[sr][s16 + 8] = bl1;
    __syncthreads();
    short8 fah[4], fal[4], fbh[4], fbl[4];
#pragma unroll
    for (int m = 0; m < 4; ++m) {
      fah[m] = *(const short8*)&Ah[wr * 64 + m * 16 + lx][lg * 8];
      fal[m] = *(const short8*)&Al[wr * 64 + m * 16 + lx][lg * 8];
    }
#pragma unroll
    for (int n = 0; n < 4; ++n) {
      fbh[n] = *(const short8*)&Bh[wc * 64 + n * 16 + lx][lg * 8];
      fbl[n] = *(const short8*)&Bl[wc * 64 + n * 16 + lx][lg * 8];
    }
#pragma unroll
    for (int m = 0; m < 4; ++m)
#pragma unroll
      for (int n = 0; n < 4; ++n) {
        acc[m][n] = __builtin_amdgcn_mfma_f32_16x16x32_bf16(fah[m], fbh[n], acc[m][n], 0, 0, 0);
        acc[m][n] = __builtin_amdgcn_mfma_f32_16x16x32_bf16(fal[m], fbh[n], acc[m][n], 0, 0, 0);
        acc[m][n] = __builtin_amdgcn_mfma_f32_16x16x32_bf16(fah[m], fbl[n], acc[m][n], 0, 0, 0);
      }
  }
  // ---- epilogue ----
  int tcolbase = n0 + wc * 64;
  int tsel = tcolbase >> 9;             // 0=q, 1=k, 2=v
  int hbase = tcolbase & 511;
  const float* bias = (tsel == 0) ? bq : (tsel == 1) ? bk : bv;
  if (tsel == 2) {
#pragma unroll
    for (int m = 0; m < 4; ++m)
#pragma unroll
      for (int i = 0; i < 4; ++i) {
        int row = m0 + wr * 64 + m * 16 + lg * 4 + i;
#pragma unroll
        for (int n = 0; n < 4; ++n) {
          int col = hbase + n * 16 + lx;
          vb[(size_t)row * 512 + col] = f2bf(acc[m][n][i] + bias[col]);
        }
      }
  } else {
    u16* oh = tsel ? kh : qh;
    u16* ol = tsel ? kl : ql;
    float qsc = tsel ? 1.f : 0.125f;
#pragma unroll
    for (int m = 0; m < 4; ++m)
#pragma unroll
      for (int i = 0; i < 4; ++i) {
        int row = m0 + wr * 64 + m * 16 + lg * 4 + i;
        int s = row >> 1;
#pragma unroll
        for (int n = 0; n < 2; ++n) {
          int dln = n * 16 + lx;
          float c  = cosb[s * 64 + dln];
          float sn = sinb[s * 64 + dln];
          float a  = acc[m][n][i]     + bias[hbase + dln];
          float b2 = acc[m][n + 2][i] + bias[hbase + dln + 32];
          float ra = (a * c - b2 * sn) * qsc;
          float rb = (b2 * c + a * sn) * qsc;
          size_t ix = (size_t)row * 512 + hbase + dln;
          u16 rah = f2bf(ra);
          oh[ix] = rah; ol[ix] = f2bf(ra - bf2f(rah));
          u16 rbh = f2bf(rb);
          oh[ix + 32] = rbh; ol[ix + 32] = f2bf(rb - bf2f(rbh));
        }
      }
  }
}

// ---------------------------------------------------------------------------
// MFMA flash attention, KV-split=2. Inputs pre-split bf16 q/k, bf16 v.
// ---------------------------------------------------------------------------
__global__ __launch_bounds__(256) void attn_mfma2(const u16* __restrict__ qh,
                                                  const u16* __restrict__ ql,
                                                  const u16* __restrict__ kh,
                                                  const u16* __restrict__ kl,
                                                  const u16* __restrict__ vbuf,
                                                  u16* __restrict__ poh,
                                                  u16* __restrict__ pol,
                                                  float* __restrict__ pml) {
  __shared__ u16 Khi[64][72];
  __shared__ u16 Klo[64][72];
  __shared__ u16 Vt[64][72];
  __shared__ u16 Pl[4][16][72];
  int tid = threadIdx.x;
  int w = tid >> 6, l = tid & 63;
  int lg = l >> 4, lx = l & 15;
  int qt = blockIdx.x, bh = blockIdx.y, kvh = blockIdx.z;
  int b = bh >> 3, h = bh & 7;

  short8 qfh[2], qfl[2];
  {
    int qrow = qt * 64 + w * 16 + lx;
    size_t qo = (size_t)(qrow * 2 + b) * 512 + h * 64 + lg * 8;
    qfh[0] = *(const short8*)&qh[qo];
    qfh[1] = *(const short8*)&qh[qo + 32];
    qfl[0] = *(const short8*)&ql[qo];
    qfl[1] = *(const short8*)&ql[qo + 32];
  }

  f32x4 o_acc[4];
#pragma unroll
  for (int dg = 0; dg < 4; ++dg) o_acc[dg] = (f32x4){0.f, 0.f, 0.f, 0.f};
  float m_run[4], l_run[4];
#pragma unroll
  for (int i = 0; i < 4; ++i) { m_run[i] = -1e30f; l_run[i] = 0.f; }

  int kvr = tid >> 2, ds4 = (tid & 3) * 16;
  int kvc = tid & 63, dsg = (tid >> 6) * 16;

  for (int tt = 0; tt < 1024; tt += 64) {
    int t0 = kvh * 1024 + tt;
    __syncthreads();
    {
      size_t ko = (size_t)((t0 + kvr) * 2 + b) * 512 + h * 64 + ds4;
      *(short8*)&Khi[kvr][ds4]     = *(const short8*)&kh[ko];
      *(short8*)&Khi[kvr][ds4 + 8] = *(const short8*)&kh[ko + 8];
      *(short8*)&Klo[kvr][ds4]     = *(const short8*)&kl[ko];
      *(short8*)&Klo[kvr][ds4 + 8] = *(const short8*)&kl[ko + 8];
      size_t vo = (size_t)((t0 + kvc) * 2 + b) * 512 + h * 64 + dsg;
      short8 v0 = *(const short8*)&vbuf[vo];
      short8 v1 = *(const short8*)&vbuf[vo + 8];
#pragma unroll
      for (int c = 0; c < 8; ++c) {
        Vt[dsg + c][kvc] = (u16)v0[c];
        Vt[dsg + 8 + c][kvc] = (u16)v1[c];
      }
    }
    __syncthreads();

    f32x4 sc[4];
#pragma unroll
    for (int cg = 0; cg < 4; ++cg) {
      short8 kh0 = *(const short8*)&Khi[cg * 16 + lx][lg * 8];
      short8 kh1 = *(const short8*)&Khi[cg * 16 + lx][32 + lg * 8];
      short8 kl0 = *(const short8*)&Klo[cg * 16 + lx][lg * 8];
      short8 kl1 = *(const short8*)&Klo[cg * 16 + lx][32 + lg * 8];
      f32x4 a = (f32x4){0.f, 0.f, 0.f, 0.f};
      a = __builtin_amdgcn_mfma_f32_16x16x32_bf16(qfh[0], kh0, a, 0, 0, 0);
      a = __builtin_amdgcn_mfma_f32_16x16x32_bf16(qfh[1], kh1, a, 0, 0, 0);
      a = __builtin_amdgcn_mfma_f32_16x16x32_bf16(qfl[0], kh0, a, 0, 0, 0);
      a = __builtin_amdgcn_mfma_f32_16x16x32_bf16(qfl[1], kh1, a, 0, 0, 0);
      a = __builtin_amdgcn_mfma_f32_16x16x32_bf16(qfh[0], kl0, a, 0, 0, 0);
      a = __builtin_amdgcn_mfma_f32_16x16x32_bf16(qfh[1], kl1, a, 0, 0, 0);
      sc[cg] = a;
    }

#pragma unroll
    for (int i = 0; i < 4; ++i) {
      float s0 = sc[0][i], s1 = sc[1][i], s2 = sc[2][i], s3 = sc[3][i];
      float tm = fmaxf(fmaxf(s0, s1), fmaxf(s2, s3));
      tm = fmaxf(tm, __shfl_xor(tm, 1));
      tm = fmaxf(tm, __shfl_xor(tm, 2));
      tm = fmaxf(tm, __shfl_xor(tm, 4));
      tm = fmaxf(tm, __shfl_xor(tm, 8));
      float mn = fmaxf(m_run[i], tm);
      float corr = __expf(m_run[i] - mn);
      m_run[i] = mn;
      float p0 = __expf(s0 - mn), p1 = __expf(s1 - mn);
      float p2 = __expf(s2 - mn), p3 = __expf(s3 - mn);
      float ts = p0 + p1 + p2 + p3;
      ts += __shfl_xor(ts, 1); ts += __shfl_xor(ts, 2);
      ts += __shfl_xor(ts, 4); ts += __shfl_xor(ts, 8);
      l_run[i] = l_run[i] * corr + ts;
#pragma unroll
      for (int dg = 0; dg < 4; ++dg) o_acc[dg][i] *= corr;
      int row = lg * 4 + i;
      Pl[w][row][lx]      = f2bf(p0);
      Pl[w][row][16 + lx] = f2bf(p1);
      Pl[w][row][32 + lx] = f2bf(p2);
      Pl[w][row][48 + lx] = f2bf(p3);
    }

    short8 pa0 = *(const short8*)&Pl[w][lx][lg * 8];
    short8 pa1 = *(const short8*)&Pl[w][lx][32 + lg * 8];
#pragma unroll
    for (int dg = 0; dg < 4; ++dg) {
      short8 v0 = *(const short8*)&Vt[dg * 16 + lx][lg * 8];
      short8 v1 = *(const short8*)&Vt[dg * 16 + lx][32 + lg * 8];
      o_acc[dg] = __builtin_amdgcn_mfma_f32_16x16x32_bf16(pa0, v0, o_acc[dg], 0, 0, 0);
      o_acc[dg] = __builtin_amdgcn_mfma_f32_16x16x32_bf16(pa1, v1, o_acc[dg], 0, 0, 0);
    }
  }

#pragma unroll
  for (int i = 0; i < 4; ++i) {
    int srow = qt * 64 + w * 16 + lg * 4 + i;
    int row2 = srow * 2 + b;
    size_t base = (size_t)kvh * ((size_t)N_ * D_) + (size_t)row2 * 512 + h * 64;
#pragma unroll
    for (int dg = 0; dg < 4; ++dg) {
      float val = o_acc[dg][i];
      u16 hi = f2bf(val);
      poh[base + dg * 16 + lx] = hi;
      pol[base + dg * 16 + lx] = f2bf(val - bf2f(hi));
    }
    if (lx == 0) {
      int u = row2 * 8 + h;
      pml[(size_t)kvh * 65536 + u * 2 + 0] = m_run[i];
      pml[(size_t)kvh * 65536 + u * 2 + 1] = l_run[i];
    }
  }
}

// Merge the two KV halves -> split-bf16 ctx.
__global__ __launch_bounds__(256) void merge_attn2(const u16* __restrict__ poh,
                                                   const u16* __restrict__ pol,
                                                   const float* __restrict__ pml,
                                                   u16* __restrict__ ch,
                                                   u16* __restrict__ cl) {
  int u = blockIdx.x * 4 + (threadIdx.x >> 6);
  int lane = threadIdx.x & 63;
  float m0 = pml[u * 2], l0 = pml[u * 2 + 1];
  float m1 = pml[65536 + u * 2], l1 = pml[65536 + u * 2 + 1];
  float m = fmaxf(m0, m1);
  float e0 = __expf(m0 - m), e1 = __expf(m1 - m);
  float inv = 1.f / (l0 * e0 + l1 * e1);
  int n = u >> 3, h = u & 7;
  size_t base = (size_t)n * 512 + h * 64 + lane;
  const size_t PO1 = (size_t)N_ * D_;
  float v0 = bf2f(poh[base]) + bf2f(pol[base]);
  float v1 = bf2f(poh[PO1 + base]) + bf2f(pol[PO1 + base]);
  float val = (v0 * e0 + v1 * e1) * inv;
  u16 hi = f2bf(val);
  ch[base] = hi;
  cl[base] = f2bf(val - bf2f(hi));
}

// ---------------------------------------------------------------------------
// Wo projection: split-bf16 MFMA GEMM, M=4096, N=512, K=512, f32 out.
// ---------------------------------------------------------------------------
__global__ __launch_bounds__(256) void wo_mfma(const u16* __restrict__ Ah_g,
                                               const u16* __restrict__ Al_g,
                                               const u16* __restrict__ Bh_g,
                                               const u16* __restrict__ Bl_g,
                                               const float* __restrict__ bias,
                                               float* __restrict__ C) {
  __shared__ u16 Ah[128][40], Al[128][40], Bh[128][40], Bl[128][40];
  int tid = threadIdx.x;
  int w = tid >> 6, l = tid & 63;
  int wr = w >> 1, wc = w & 1;
  int lg = l >> 4, lx = l & 15;
  int m0 = blockIdx.x * 128, n0 = blockIdx.y * 128;
  int sr = tid >> 1, s16 = (tid & 1) * 16;
  const u16* Aph = Ah_g + (size_t)(m0 + sr) * 512;
  const u16* Apl = Al_g + (size_t)(m0 + sr) * 512;
  const u16* Bph = Bh_g + (size_t)(n0 + sr) * 512;
  const u16* Bpl = Bl_g + (size_t)(n0 + sr) * 512;
  f32x4 acc[4][4];
#pragma unroll
  for (int m = 0; m < 4; ++m)
#pragma unroll
    for (int n = 0; n < 4; ++n) acc[m][n] = (f32x4){0.f, 0.f, 0.f, 0.f};
  for (int k0 = 0; k0 < 512; k0 += 32) {
    short8 ah0 = *(const short8*)&Aph[k0 + s16];
    short8 ah1 = *(const short8*)&Aph[k0 + s16 + 8];
    short8 al0 = *(const short8*)&Apl[k0 + s16];
    short8 al1 = *(const short8*)&Apl[k0 + s16 + 8];
    short8 bh0 = *(const short8*)&Bph[k0 + s16];
    short8 bh1 = *(const short8*)&Bph[k0 + s16 + 8];
    short8 bl0 = *(const short8*)&Bpl[k0 + s16];
    short8 bl1 = *(const short8*)&Bpl[k0 + s16 + 8];
    __syncthreads();
    *(short8*)&Ah[sr][s16] = ah0; *(short8*)&Ah[sr][s16 + 8] = ah1;
    *(short8*)&Al[sr][s16] = al0; *(short8*)&Al[sr][s16 + 8] = al1;
    *(short8*)&Bh[sr][s16] = bh0; *(short8*)&Bh[sr][s16 + 8] = bh1;
    *(short8*)&Bl[sr][s16] = bl0; *(short8*)&Bl[sr][s16 + 8] = bl1;
    __syncthreads();
    short8 fah[4], fal[4], fbh[4], fbl[4];
#pragma unroll
    for (int m = 0; m < 4; ++m) {
      fah[m] = *(const short8*)&Ah[wr * 64 + m * 16 + lx][lg * 8];
      fal[m] = *(const short8*)&Al[wr * 64 + m * 16 + lx][lg * 8];
    }
#pragma unroll
    for (int n = 0; n < 4; ++n) {
      fbh[n] = *(const short8*)&Bh[wc * 64 + n * 16 + lx][lg * 8];
      fbl[n] = *(const short8*)&Bl[wc * 64 + n * 16 + lx][lg * 8];
    }
#pragma unroll
    for (int m = 0; m < 4; ++m)
#pragma unroll
      for (int n = 0; n < 4; ++n) {
        acc[m][n] = __builtin_amdgcn_mfma_f32_16x16x32_bf16(fah[m], fbh[n], acc[m][n], 0, 0, 0);
        acc[m][n] = __builtin_amdgcn_mfma_f32_16x16x32_bf16(fal[m], fbh[n], acc[m][n], 0, 0, 0);
        acc[m][n] = __builtin_amdgcn_mfma_f32_16x16x32_bf16(fah[m], fbl[n], acc[m][n], 0, 0, 0);
      }
  }
#pragma unroll
  for (int m = 0; m < 4; ++m)
#pragma unroll
    for (int i = 0; i < 4; ++i) {
      int row = m0 + wr * 64 + m * 16 + lg * 4 + i;
#pragma unroll
      for (int n = 0; n < 4; ++n) {
        int col = n0 + wc * 64 + n * 16 + lx;
        C[(size_t)row * 512 + col] = acc[m][n][i] + bias[col];
      }
    }
}

// ---------------------------------------------------------------------------
// LayerNorm with residual + bf16 copy.
// ---------------------------------------------------------------------------
__global__ __launch_bounds__(256) void ln_res(const float* __restrict__ a,
                                              const float* __restrict__ b,
                                              const float* __restrict__ g,
                                              const float* __restrict__ beta,
                                              float* __restrict__ out,
                                              u16* __restrict__ obf) {
  int n = blockIdx.x * 4 + (threadIdx.x >> 6);
  int lane = threadIdx.x & 63;
  float v[8];
  float s = 0.f;
#pragma unroll
  for (int i = 0; i < 8; ++i) {
    int d = lane + 64 * i;
    v[i] = a[(size_t)n * D_ + d] + b[(size_t)n * D_ + d];
    s += v[i];
  }
#pragma unroll
  for (int m = 32; m; m >>= 1) s += __shfl_xor(s, m);
  float mean = s * (1.f / D_);
  float s2 = 0.f;
#pragma unroll
  for (int i = 0; i < 8; ++i) { float t = v[i] - mean; s2 += t * t; }
#pragma unroll
  for (int m = 32; m; m >>= 1) s2 += __shfl_xor(s2, m);
  float r = rsqrtf(s2 * (1.f / D_) + 1e-5f);
#pragma unroll
  for (int i = 0; i < 8; ++i) {
    int d = lane + 64 * i;
    float val = (v[i] - mean) * r * g[d] + beta[d];
    out[(size_t)n * D_ + d] = val;
    obf[(size_t)n * D_ + d] = f2bf(val);
  }
}

__global__ __launch_bounds__(256) void ln2_final(const float* __restrict__ x,
                                                 const u16* __restrict__ mp,
                                                 const float* __restrict__ g,
                                                 const float* __restrict__ beta,
                                                 float* __restrict__ out) {
  int n = blockIdx.x * 4 + (threadIdx.x >> 6);
  int lane = threadIdx.x & 63;
  float v[8];
  float s = 0.f;
#pragma unroll
  for (int i = 0; i < 8; ++i) {
    int d = lane + 64 * i;
    v[i] = x[(size_t)n * D_ + d] + bf2f(mp[(size_t)(2 * n) * D_ + d]) +
           bf2f(mp[(size_t)(2 * n + 1) * D_ + d]);
    s += v[i];
  }
#pragma unroll
  for (int m = 32; m; m >>= 1) s += __shfl_xor(s, m);
  float mean = s * (1.f / D_);
  float s2 = 0.f;
#pragma unroll
  for (int i = 0; i < 8; ++i) { float t = v[i] - mean; s2 += t * t; }
#pragma unroll
  for (int m = 32; m; m >>= 1) s2 += __shfl_xor(s2, m);
  float r = rsqrtf(s2 * (1.f / D_) + 1e-5f);
#pragma unroll
  for (int i = 0; i < 8; ++i) {
    int d = lane + 64 * i;
    out[(size_t)n * D_ + d] = (v[i] - mean) * r * g[d] + beta[d];
  }
}

// ---------------------------------------------------------------------------
// Gate phase A: per-token top-2 computation. NO atomics.
// Writes tope[n] = e1 | (e2<<8), gp[2n]=w1, gp[2n+1]=w2.
// ---------------------------------------------------------------------------
__global__ __launch_bounds__(256) void gate_compute(const float* __restrict__ x,
                                                    const float* __restrict__ Wg,
                                                    float* __restrict__ gp,
                                                    int* __restrict__ tope) {
  int n = blockIdx.x * 4 + (threadIdx.x >> 6);
  int lane = threadIdx.x & 63;
  float p[E_] = {};
  for (int d = lane; d < D_; d += 64) {
    float xv = x[(size_t)n * D_ + d];
    const float* wr = &Wg[(size_t)d * E_];
#pragma unroll
    for (int e = 0; e < E_; ++e) p[e] += xv * wr[e];
  }
#pragma unroll
  for (int e = 0; e < E_; ++e)
#pragma unroll
    for (int m = 32; m; m >>= 1) p[e] += __shfl_xor(p[e], m);
  if (lane == 0) {
    float mx = p[0];
#pragma unroll
    for (int e = 1; e < E_; ++e) mx = fmaxf(mx, p[e]);
    float q[E_];
#pragma unroll
    for (int e = 0; e < E_; ++e) q[e] = expf(p[e] - mx);
    int e1 = 0;
#pragma unroll
    for (int e = 1; e < E_; ++e) if (q[e] > q[e1]) e1 = e;
    int e2 = (e1 == 0) ? 1 : 0;
#pragma unroll
    for (int e = 0; e < E_; ++e) if (e != e1 && q[e] > q[e2]) e2 = e;
    float denom = q[e1] + q[e2];
    gp[n * 2] = q[e1] / denom;
    gp[n * 2 + 1] = q[e2] / denom;
    tope[n] = e1 | (e2 << 8);
  }
}

// ---------------------------------------------------------------------------
// Gate phase B: per-expert ordered compaction. One block per expert.
// Deterministic (token-order) lists; writes cnt[e] at the end.
// ---------------------------------------------------------------------------
__global__ __launch_bounds__(256) void route_build(const int* __restrict__ tope,
                                                   int* __restrict__ cnt,
                                                   int* __restrict__ lst) {
  int e = blockIdx.x;
  __shared__ int wsum[4];
  __shared__ int basem;
  int tid = threadIdx.x;
  int w = tid >> 6, lane = tid & 63;
  if (tid == 0) basem = 0;
  __syncthreads();
  for (int c0 = 0; c0 < N_; c0 += 256) {
    int n = c0 + tid;
    int te = tope[n];
    int e1 = te & 0xff, e2 = (te >> 8) & 0xff;
    bool m2 = (e2 == e);
    bool flag = (e1 == e) || m2;
    unsigned long long mask = __ballot(flag);
    int wpre = __popcll(mask & ((1ull << lane) - 1ull));
    if (lane == 0) wsum[w] = __popcll(mask);
    __syncthreads();
    int woff = 0;
    for (int i = 0; i < w; ++i) woff += wsum[i];
    int total = wsum[0] + wsum[1] + wsum[2] + wsum[3];
    if (flag) lst[e * N_ + basem + woff + wpre] = n * 2 + (m2 ? 1 : 0);
    __syncthreads();
    if (tid == 0) basem += total;
    __syncthreads();
  }
  if (tid == 0) cnt[e] = basem;
}

// ---------------------------------------------------------------------------
// bf16 MFMA MoE GEMM, 128x128 tile, BK=32, 4 waves (2x2).
// ---------------------------------------------------------------------------
template <int MODE>
__global__ __launch_bounds__(256) void moe_mfma(const u16* __restrict__ Abase,
                                                const u16* __restrict__ Wt,
                                                const float* __restrict__ bias,
                                                const float* __restrict__ gp,
                                                u16* __restrict__ outp,
                                                const int* __restrict__ cnt,
                                                const int* __restrict__ lst) {
  constexpr int K  = MODE ? 1024 : 512;
  constexpr int Nn = MODE ? 512 : 1024;
  int e = blockIdx.z;
  int c = cnt[e];
  int m0 = blockIdx.x * 128;
  if (m0 >= c) return;
  int off = 0;
#pragma unroll
  for (int i = 0; i < E_; ++i) if (i < e) off += cnt[i];
  int n0 = blockIdx.y * 128;
  __shared__ u16 As[128][40];
  __shared__ u16 Bs[128][40];
  int tid = threadIdx.x;
  int w = tid >> 6, l = tid & 63;
  int wr = w >> 1, wc = w & 1;
  int lg = l >> 4, lx = l & 15;
  int sr = tid >> 1, s16 = (tid & 1) * 16;
  int ar = m0 + sr; if (ar > c - 1) ar = c - 1;
  const u16* Ap;
  if (MODE == 0) Ap = Abase + (size_t)(lst[e * N_ + ar] >> 1) * 512;
  else           Ap = Abase + (size_t)(off + ar) * 1024;
  const u16* Bp = Wt + (size_t)e * K * Nn + (size_t)(n0 + sr) * K;
  f32x4 acc[4][4];
#pragma unroll
  for (int m = 0; m < 4; ++m)
#pragma unroll
    for (int n = 0; n < 4; ++n) acc[m][n] = (f32x4){0.f, 0.f, 0.f, 0.f};
  for (int k0 = 0; k0 < K; k0 += 32) {
    short8 av0 = *(const short8*)&Ap[k0 + s16];
    short8 av1 = *(const short8*)&Ap[k0 + s16 + 8];
    short8 bv0 = *(const short8*)&Bp[k0 + s16];
    short8 bv1 = *(const short8*)&Bp[k0 + s16 + 8];
    __syncthreads();
    *(short8*)&As[sr][s16] = av0;
    *(short8*)&As[sr][s16 + 8] = av1;
    *(short8*)&Bs[sr][s16] = bv0;
    *(short8*)&Bs[sr][s16 + 8] = bv1;
    __syncthreads();
    short8 a[4], bfr[4];
#pragma unroll
    for (int m = 0; m < 4; ++m)
      a[m] = *(const short8*)&As[wr * 64 + m * 16 + lx][lg * 8];
#pragma unroll
    for (int n = 0; n < 4; ++n)
      bfr[n] = *(const short8*)&Bs[wc * 64 + n * 16 + lx][lg * 8];
#pragma unroll
    for (int m = 0; m < 4; ++m)
#pragma unroll
      for (int n = 0; n < 4; ++n)
        acc[m][n] = __builtin_amdgcn_mfma_f32_16x16x32_bf16(a[m], bfr[n], acc[m][n], 0, 0, 0);
  }
#pragma unroll
  for (int m = 0; m < 4; ++m)
#pragma unroll
    for (int n = 0; n < 4; ++n)
#pragma unroll
      for (int i = 0; i < 4; ++i) {
        int r = m0 + wr * 64 + m * 16 + lg * 4 + i;
        if (r < c) {
          int col = n0 + wc * 64 + n * 16 + lx;
          float val = acc[m][n][i] + bias[e * Nn + col];
          if (MODE == 0) {
            val = fmaxf(val, 0.f);
            outp[(size_t)(off + r) * 1024 + col] = f2bf(val);
          } else {
            int p = lst[e * N_ + r];
            outp[(size_t)p * 512 + col] = f2bf(gp[p] * val);
          }
        }
      }
}

// ---------------------------------------------------------------------------
extern "C" void kernel_launch(void* const* d_in, const int* in_sizes, int n_in,
                              void* d_out, int out_size, void* d_ws, size_t ws_size,
                              hipStream_t stream) {
  const float* src  = (const float*)d_in[0];
  const float* cosb = (const float*)d_in[1];
  const float* sinb = (const float*)d_in[2];
  const float* Wq   = (const float*)d_in[3];
  const float* bq   = (const float*)d_in[4];
  const float* Wk   = (const float*)d_in[5];
  const float* bk   = (const float*)d_in[6];
  const float* Wv   = (const float*)d_in[7];
  const float* bv   = (const float*)d_in[8];
  const float* Wo   = (const float*)d_in[9];
  const float* bo   = (const float*)d_in[10];
  const float* ln1g = (const float*)d_in[11];
  const float* ln1b = (const float*)d_in[12];
  const float* ln2g = (const float*)d_in[13];
  const float* ln2b = (const float*)d_in[14];
  const float* Wg   = (const float*)d_in[15];
  const float* W1   = (const float*)d_in[16];
  const float* B1   = (const float*)d_in[17];
  const float* W2   = (const float*)d_in[18];
  const float* B2   = (const float*)d_in[19];
  float* out = (float*)d_out;
  char* wsb = (char*)d_ws;

  const size_t MB1 = 1u << 20;
  // Byte layout (~60.4 MB high-water):
  u16* sh   = (u16*)(wsb + 0 * MB1);      // src hi  [0,4M)   ; later ch
  u16* sl   = (u16*)(wsb + 4 * MB1);      // src lo  [4,8M)   ; later cl
  u16* qhb  = (u16*)(wsb + 8 * MB1);      // [8,12M)          ; later hbf part
  u16* qlb  = (u16*)(wsb + 12 * MB1);
  u16* khb  = (u16*)(wsb + 16 * MB1);
  u16* klb  = (u16*)(wsb + 20 * MB1);
  u16* vbuf = (u16*)(wsb + 24 * MB1);     // [24,28M)
  u16* poh  = (u16*)(wsb + 28 * MB1);     // [28,36M) attn partial hi ; later aob f32
  u16* pol  = (u16*)(wsb + 36 * MB1);     // [36,44M) attn partial lo ; later xb f32
  float* pml = (float*)(wsb + 44 * MB1);  // [44,44.5M)       ; later xbf
  float* aob = (float*)(wsb + 28 * MB1);  // [28,36M)
  float* xb  = (float*)(wsb + 36 * MB1);  // [36,44M)
  u16* xbf   = (u16*)(wsb + 44 * MB1);    // [44,48M)
  u16* Wqkv_hi = (u16*)(wsb + 48 * MB1);              // 1.5MB
  u16* Wqkv_lo = (u16*)(wsb + 48 * MB1 + 1572864);    // 1.5MB
  u16* Wo_hi   = (u16*)(wsb + 48 * MB1 + 3145728);    // 0.5MB
  u16* Wo_lo   = (u16*)(wsb + 48 * MB1 + 3670016);    // 0.5MB
  u16* W1t     = (u16*)(wsb + 52 * MB1);  // [52,60M) ; W2t aliases after moe1
  u16* W2t     = W1t;
  float* gpb   = (float*)(wsb + 60 * MB1);                 // 32 KB
  int* cnt     = (int*)(wsb + 60 * MB1 + 32768);           // 64 B
  int* lst     = (int*)(wsb + 60 * MB1 + 32768 + 64);      // 128 KB
  int* tope    = (int*)(wsb + 60 * MB1 + 32768 + 64 + 131072);  // 16 KB
  u16* ch  = sh;                          // ctx hi aliases src-split (dead)
  u16* cl  = sl;
  u16* hbf = (u16*)(wsb + 8 * MB1);       // [8,24M) aliases q/k (dead after attn)
  u16* mp  = (u16*)(wsb + 0 * MB1);       // [0,8M)  aliases ch/cl (dead after wo)

  dim3 blk(256);
  src_split<<<dim3(1024), blk, 0, stream>>>(src, sh, sl);
  wsplit_t<<<dim3(8, 8), blk, 0, stream>>>(Wq, Wqkv_hi, Wqkv_lo, 512, 512);
  wsplit_t<<<dim3(8, 8), blk, 0, stream>>>(Wk, Wqkv_hi + 512 * 512, Wqkv_lo + 512 * 512, 512, 512);
  wsplit_t<<<dim3(8, 8), blk, 0, stream>>>(Wv, Wqkv_hi + 1024 * 512, Wqkv_lo + 1024 * 512, 512, 512);
  wsplit_t<<<dim3(8, 8), blk, 0, stream>>>(Wo, Wo_hi, Wo_lo, 512, 512);
  // QKV + RoPE fused (split-bf16, f32-grade)
  qkv_mfma<<<dim3(32, 12), blk, 0, stream>>>(sh, sl, Wqkv_hi, Wqkv_lo, bq, bk, bv,
                                             cosb, sinb, qhb, qlb, khb, klb, vbuf);
  // Attention, KV-split=2 + merge
  attn_mfma2<<<dim3(32, 16, 2), blk, 0, stream>>>(qhb, qlb, khb, klb, vbuf, poh, pol, pml);
  merge_attn2<<<dim3(8192), blk, 0, stream>>>(poh, pol, pml, ch, cl);
  // Wo projection (split-bf16)
  wo_mfma<<<dim3(32, 4), blk, 0, stream>>>(ch, cl, Wo_hi, Wo_lo, bo, aob);
  // LN1 (+bf16 copy)
  ln_res<<<dim3(1024), blk, 0, stream>>>(src, aob, ln1g, ln1b, xb, xbf);
  // MoE: gate (atomic-free) + ordered routing
  wtrans<<<dim3(16, 8, 8), blk, 0, stream>>>(W1, W1t, 512, 1024);
  gate_compute<<<dim3(1024), blk, 0, stream>>>(xb, Wg, gpb, tope);
  route_build<<<dim3(8), blk, 0, stream>>>(tope, cnt, lst);
  moe_mfma<0><<<dim3(32, 8, 8), blk, 0, stream>>>(xbf, W1t, B1, gpb, hbf, cnt, lst);
  wtrans<<<dim3(8, 16, 8), blk, 0, stream>>>(W2, W2t, 1024, 512);
  moe_mfma<1><<<dim3(32, 4, 8), blk, 0, stream>>>(hbf, W2t, B2, gpb, mp, cnt, lst);
  ln2_final<<<dim3(1024), blk, 0, stream>>>(xb, mp, ln2g, ln2b, out);
}

// Round 7
// 253.507 us; speedup vs baseline: 4.6201x; 1.4420x over previous
//
#include <hip/hip_runtime.h>
#include <math.h>

// Shapes (fixed)
#define S_  2048
#define B_  2
#define D_  512
#define H_  8
#define DH_ 64
#define E_  8
#define F_  1024
#define N_  4096   // S_*B_
#define NPAIR_ 8192

typedef __attribute__((ext_vector_type(4))) float f32x4;
typedef __attribute__((ext_vector_type(8))) short short8;
typedef unsigned short u16;

__device__ __forceinline__ u16 f2bf(float f) {
  unsigned u = __builtin_bit_cast(unsigned, f);
  u += 0x7fffu + ((u >> 16) & 1u);
  return (u16)(u >> 16);
}
__device__ __forceinline__ float bf2f(u16 h) {
  unsigned u = ((unsigned)h) << 16;
  return __builtin_bit_cast(float, u);
}

// ---------------------------------------------------------------------------
// src -> split bf16 (hi, lo). 2M elements, 8/thread.
// ---------------------------------------------------------------------------
__global__ __launch_bounds__(256) void src_split(const float* __restrict__ in,
                                                 u16* __restrict__ hi,
                                                 u16* __restrict__ lo) {
  size_t i = ((size_t)blockIdx.x * 256 + threadIdx.x) * 8;
  float f[8];
  *(float4*)&f[0] = *(const float4*)&in[i];
  *(float4*)&f[4] = *(const float4*)&in[i + 4];
  short8 h, l;
#pragma unroll
  for (int j = 0; j < 8; ++j) {
    u16 a = f2bf(f[j]);
    h[j] = (short)a;
    l[j] = (short)f2bf(f[j] - bf2f(a));
  }
  *(short8*)&hi[i] = h;
  *(short8*)&lo[i] = l;
}

// ---------------------------------------------------------------------------
// Weight transpose + split: Whi/Wlo[n][k] = split(W[k][n]). W is [K][Nn].
// ---------------------------------------------------------------------------
__global__ __launch_bounds__(256) void wsplit_t(const float* __restrict__ W,
                                                u16* __restrict__ Whi,
                                                u16* __restrict__ Wlo,
                                                int Nn, int K) {
  __shared__ u16 Th[64][72];
  __shared__ u16 Tl[64][72];
  int kb = blockIdx.y * 64, nb = blockIdx.x * 64;
  int r = threadIdx.x >> 2, c0 = (threadIdx.x & 3) * 16;
  const float* wp = &W[(size_t)(kb + r) * Nn + nb + c0];
#pragma unroll
  for (int c = 0; c < 16; c += 4) {
    float4 t = *(const float4*)&wp[c];
    float f[4] = {t.x, t.y, t.z, t.w};
#pragma unroll
    for (int j = 0; j < 4; ++j) {
      u16 a = f2bf(f[j]);
      Th[r][c0 + c + j] = a;
      Tl[r][c0 + c + j] = f2bf(f[j] - bf2f(a));
    }
  }
  __syncthreads();
  short8 h0, h1, l0, l1;
#pragma unroll
  for (int j = 0; j < 8; ++j) {
    h0[j] = (short)Th[c0 + j][r];     h1[j] = (short)Th[c0 + 8 + j][r];
    l0[j] = (short)Tl[c0 + j][r];     l1[j] = (short)Tl[c0 + 8 + j][r];
  }
  size_t ob = (size_t)(nb + r) * K + kb + c0;
  *(short8*)&Whi[ob] = h0;  *(short8*)&Whi[ob + 8] = h1;
  *(short8*)&Wlo[ob] = l0;  *(short8*)&Wlo[ob + 8] = l1;
}

// ---------------------------------------------------------------------------
// Plain bf16 weight transpose for MoE (W1, W2).
// ---------------------------------------------------------------------------
__global__ __launch_bounds__(256) void wtrans(const float* __restrict__ W,
                                              u16* __restrict__ Wt,
                                              int K, int Nn) {
  size_t eo = (size_t)blockIdx.z * K * Nn;
  __shared__ u16 T[64][72];
  int kb = blockIdx.y * 64, nb = blockIdx.x * 64;
  int r = threadIdx.x >> 2, c0 = (threadIdx.x & 3) * 16;
  const float* wp = &W[eo + (size_t)(kb + r) * Nn + nb + c0];
#pragma unroll
  for (int c = 0; c < 16; c += 4) {
    float4 t = *(const float4*)&wp[c];
    T[r][c0 + c + 0] = f2bf(t.x);
    T[r][c0 + c + 1] = f2bf(t.y);
    T[r][c0 + c + 2] = f2bf(t.z);
    T[r][c0 + c + 3] = f2bf(t.w);
  }
  __syncthreads();
  short8 s0, s1;
#pragma unroll
  for (int j = 0; j < 8; ++j) {
    s0[j] = (short)T[c0 + j][r];
    s1[j] = (short)T[c0 + 8 + j][r];
  }
  *(short8*)&Wt[eo + (size_t)(nb + r) * K + kb + c0] = s0;
  *(short8*)&Wt[eo + (size_t)(nb + r) * K + kb + c0 + 8] = s1;
}

// ---------------------------------------------------------------------------
// Fused QKV split-bf16 MFMA GEMM + RoPE. M=4096, N=1536, K=512.
// ---------------------------------------------------------------------------
__global__ __launch_bounds__(256) void qkv_mfma(const u16* __restrict__ Ah_g,
                                                const u16* __restrict__ Al_g,
                                                const u16* __restrict__ Bh_g,
                                                const u16* __restrict__ Bl_g,
                                                const float* __restrict__ bq,
                                                const float* __restrict__ bk,
                                                const float* __restrict__ bv,
                                                const float* __restrict__ cosb,
                                                const float* __restrict__ sinb,
                                                u16* __restrict__ qh, u16* __restrict__ ql,
                                                u16* __restrict__ kh, u16* __restrict__ kl,
                                                u16* __restrict__ vb) {
  __shared__ u16 Ah[128][40], Al[128][40], Bh[128][40], Bl[128][40];
  int tid = threadIdx.x;
  int w = tid >> 6, l = tid & 63;
  int wr = w >> 1, wc = w & 1;
  int lg = l >> 4, lx = l & 15;
  int m0 = blockIdx.x * 128, n0 = blockIdx.y * 128;
  int sr = tid >> 1, s16 = (tid & 1) * 16;
  const u16* Aph = Ah_g + (size_t)(m0 + sr) * 512;
  const u16* Apl = Al_g + (size_t)(m0 + sr) * 512;
  const u16* Bph = Bh_g + (size_t)(n0 + sr) * 512;
  const u16* Bpl = Bl_g + (size_t)(n0 + sr) * 512;
  f32x4 acc[4][4];
#pragma unroll
  for (int m = 0; m < 4; ++m)
#pragma unroll
    for (int n = 0; n < 4; ++n) acc[m][n] = (f32x4){0.f, 0.f, 0.f, 0.f};
  for (int k0 = 0; k0 < 512; k0 += 32) {
    short8 ah0 = *(const short8*)&Aph[k0 + s16];
    short8 ah1 = *(const short8*)&Aph[k0 + s16 + 8];
    short8 al0 = *(const short8*)&Apl[k0 + s16];
    short8 al1 = *(const short8*)&Apl[k0 + s16 + 8];
    short8 bh0 = *(const short8*)&Bph[k0 + s16];
    short8 bh1 = *(const short8*)&Bph[k0 + s16 + 8];
    short8 bl0 = *(const short8*)&Bpl[k0 + s16];
    short8 bl1 = *(const short8*)&Bpl[k0 + s16 + 8];
    __syncthreads();
    *(short8*)&Ah[sr][s16] = ah0; *(short8*)&Ah[sr][s16 + 8] = ah1;
    *(short8*)&Al[sr][s16] = al0; *(short8*)&Al[sr][s16 + 8] = al1;
    *(short8*)&Bh[sr][s16] = bh0; *(short8*)&Bh[sr][s16 + 8] = bh1;
    *(short8*)&Bl[sr][s16] = bl0; *(short8*)&Bl[sr][s16 + 8] = bl1;
    __syncthreads();
    short8 fah[4], fal[4], fbh[4], fbl[4];
#pragma unroll
    for (int m = 0; m < 4; ++m) {
      fah[m] = *(const short8*)&Ah[wr * 64 + m * 16 + lx][lg * 8];
      fal[m] = *(const short8*)&Al[wr * 64 + m * 16 + lx][lg * 8];
    }
#pragma unroll
    for (int n = 0; n < 4; ++n) {
      fbh[n] = *(const short8*)&Bh[wc * 64 + n * 16 + lx][lg * 8];
      fbl[n] = *(const short8*)&Bl[wc * 64 + n * 16 + lx][lg * 8];
    }
#pragma unroll
    for (int m = 0; m < 4; ++m)
#pragma unroll
      for (int n = 0; n < 4; ++n) {
        acc[m][n] = __builtin_amdgcn_mfma_f32_16x16x32_bf16(fah[m], fbh[n], acc[m][n], 0, 0, 0);
        acc[m][n] = __builtin_amdgcn_mfma_f32_16x16x32_bf16(fal[m], fbh[n], acc[m][n], 0, 0, 0);
        acc[m][n] = __builtin_amdgcn_mfma_f32_16x16x32_bf16(fah[m], fbl[n], acc[m][n], 0, 0, 0);
      }
  }
  // ---- epilogue ----
  int tcolbase = n0 + wc * 64;
  int tsel = tcolbase >> 9;             // 0=q, 1=k, 2=v
  int hbase = tcolbase & 511;
  const float* bias = (tsel == 0) ? bq : (tsel == 1) ? bk : bv;
  if (tsel == 2) {
#pragma unroll
    for (int m = 0; m < 4; ++m)
#pragma unroll
      for (int i = 0; i < 4; ++i) {
        int row = m0 + wr * 64 + m * 16 + lg * 4 + i;
#pragma unroll
        for (int n = 0; n < 4; ++n) {
          int col = hbase + n * 16 + lx;
          vb[(size_t)row * 512 + col] = f2bf(acc[m][n][i] + bias[col]);
        }
      }
  } else {
    u16* oh = tsel ? kh : qh;
    u16* ol = tsel ? kl : ql;
    float qsc = tsel ? 1.f : 0.125f;
#pragma unroll
    for (int m = 0; m < 4; ++m)
#pragma unroll
      for (int i = 0; i < 4; ++i) {
        int row = m0 + wr * 64 + m * 16 + lg * 4 + i;
        int s = row >> 1;
#pragma unroll
        for (int n = 0; n < 2; ++n) {
          int dln = n * 16 + lx;
          float c  = cosb[s * 64 + dln];
          float sn = sinb[s * 64 + dln];
          float a  = acc[m][n][i]     + bias[hbase + dln];
          float b2 = acc[m][n + 2][i] + bias[hbase + dln + 32];
          float ra = (a * c - b2 * sn) * qsc;
          float rb = (b2 * c + a * sn) * qsc;
          size_t ix = (size_t)row * 512 + hbase + dln;
          u16 rah = f2bf(ra);
          oh[ix] = rah; ol[ix] = f2bf(ra - bf2f(rah));
          u16 rbh = f2bf(rb);
          oh[ix + 32] = rbh; ol[ix + 32] = f2bf(rb - bf2f(rbh));
        }
      }
  }
}

// ---------------------------------------------------------------------------
// MFMA flash attention, KV-split=2, XCD-pinned (b,h,kvh) slabs.
// Flat grid 1024: x=f&7 (XCD), slab = x + 8*((f>>3)&3), qt = f>>5.
// ---------------------------------------------------------------------------
__global__ __launch_bounds__(256) void attn_mfma2(const u16* __restrict__ qh,
                                                  const u16* __restrict__ ql,
                                                  const u16* __restrict__ kh,
                                                  const u16* __restrict__ kl,
                                                  const u16* __restrict__ vbuf,
                                                  u16* __restrict__ poh,
                                                  u16* __restrict__ pol,
                                                  float* __restrict__ pml) {
  __shared__ u16 Khi[64][72];
  __shared__ u16 Klo[64][72];
  __shared__ u16 Vt[64][72];
  __shared__ u16 Pl[4][16][72];
  int tid = threadIdx.x;
  int w = tid >> 6, l = tid & 63;
  int lg = l >> 4, lx = l & 15;
  int f = blockIdx.x;
  int xcd = f & 7, j = f >> 3;
  int slab = xcd + 8 * (j & 3);   // 0..31 : all qt of a slab share an XCD
  int qt = j >> 2;                // 0..31
  int bh = slab >> 1, kvh = slab & 1;
  int b = bh >> 3, h = bh & 7;

  short8 qfh[2], qfl[2];
  {
    int qrow = qt * 64 + w * 16 + lx;
    size_t qo = (size_t)(qrow * 2 + b) * 512 + h * 64 + lg * 8;
    qfh[0] = *(const short8*)&qh[qo];
    qfh[1] = *(const short8*)&qh[qo + 32];
    qfl[0] = *(const short8*)&ql[qo];
    qfl[1] = *(const short8*)&ql[qo + 32];
  }

  f32x4 o_acc[4];
#pragma unroll
  for (int dg = 0; dg < 4; ++dg) o_acc[dg] = (f32x4){0.f, 0.f, 0.f, 0.f};
  float m_run[4], l_run[4];
#pragma unroll
  for (int i = 0; i < 4; ++i) { m_run[i] = -1e30f; l_run[i] = 0.f; }

  int kvr = tid >> 2, ds4 = (tid & 3) * 16;
  int kvc = tid & 63, dsg = (tid >> 6) * 16;

  for (int tt = 0; tt < 1024; tt += 64) {
    int t0 = kvh * 1024 + tt;
    __syncthreads();
    {
      size_t ko = (size_t)((t0 + kvr) * 2 + b) * 512 + h * 64 + ds4;
      *(short8*)&Khi[kvr][ds4]     = *(const short8*)&kh[ko];
      *(short8*)&Khi[kvr][ds4 + 8] = *(const short8*)&kh[ko + 8];
      *(short8*)&Klo[kvr][ds4]     = *(const short8*)&kl[ko];
      *(short8*)&Klo[kvr][ds4 + 8] = *(const short8*)&kl[ko + 8];
      size_t vo = (size_t)((t0 + kvc) * 2 + b) * 512 + h * 64 + dsg;
      short8 v0 = *(const short8*)&vbuf[vo];
      short8 v1 = *(const short8*)&vbuf[vo + 8];
#pragma unroll
      for (int c = 0; c < 8; ++c) {
        Vt[dsg + c][kvc] = (u16)v0[c];
        Vt[dsg + 8 + c][kvc] = (u16)v1[c];
      }
    }
    __syncthreads();

    f32x4 sc[4];
#pragma unroll
    for (int cg = 0; cg < 4; ++cg) {
      short8 kh0 = *(const short8*)&Khi[cg * 16 + lx][lg * 8];
      short8 kh1 = *(const short8*)&Khi[cg * 16 + lx][32 + lg * 8];
      short8 kl0 = *(const short8*)&Klo[cg * 16 + lx][lg * 8];
      short8 kl1 = *(const short8*)&Klo[cg * 16 + lx][32 + lg * 8];
      f32x4 a = (f32x4){0.f, 0.f, 0.f, 0.f};
      a = __builtin_amdgcn_mfma_f32_16x16x32_bf16(qfh[0], kh0, a, 0, 0, 0);
      a = __builtin_amdgcn_mfma_f32_16x16x32_bf16(qfh[1], kh1, a, 0, 0, 0);
      a = __builtin_amdgcn_mfma_f32_16x16x32_bf16(qfl[0], kh0, a, 0, 0, 0);
      a = __builtin_amdgcn_mfma_f32_16x16x32_bf16(qfl[1], kh1, a, 0, 0, 0);
      a = __builtin_amdgcn_mfma_f32_16x16x32_bf16(qfh[0], kl0, a, 0, 0, 0);
      a = __builtin_amdgcn_mfma_f32_16x16x32_bf16(qfh[1], kl1, a, 0, 0, 0);
      sc[cg] = a;
    }

#pragma unroll
    for (int i = 0; i < 4; ++i) {
      float s0 = sc[0][i], s1 = sc[1][i], s2 = sc[2][i], s3 = sc[3][i];
      float tm = fmaxf(fmaxf(s0, s1), fmaxf(s2, s3));
      tm = fmaxf(tm, __shfl_xor(tm, 1));
      tm = fmaxf(tm, __shfl_xor(tm, 2));
      tm = fmaxf(tm, __shfl_xor(tm, 4));
      tm = fmaxf(tm, __shfl_xor(tm, 8));
      float mn = fmaxf(m_run[i], tm);
      float corr = __expf(m_run[i] - mn);
      m_run[i] = mn;
      float p0 = __expf(s0 - mn), p1 = __expf(s1 - mn);
      float p2 = __expf(s2 - mn), p3 = __expf(s3 - mn);
      float ts = p0 + p1 + p2 + p3;
      ts += __shfl_xor(ts, 1); ts += __shfl_xor(ts, 2);
      ts += __shfl_xor(ts, 4); ts += __shfl_xor(ts, 8);
      l_run[i] = l_run[i] * corr + ts;
#pragma unroll
      for (int dg = 0; dg < 4; ++dg) o_acc[dg][i] *= corr;
      int row = lg * 4 + i;
      Pl[w][row][lx]      = f2bf(p0);
      Pl[w][row][16 + lx] = f2bf(p1);
      Pl[w][row][32 + lx] = f2bf(p2);
      Pl[w][row][48 + lx] = f2bf(p3);
    }

    short8 pa0 = *(const short8*)&Pl[w][lx][lg * 8];
    short8 pa1 = *(const short8*)&Pl[w][lx][32 + lg * 8];
#pragma unroll
    for (int dg = 0; dg < 4; ++dg) {
      short8 v0 = *(const short8*)&Vt[dg * 16 + lx][lg * 8];
      short8 v1 = *(const short8*)&Vt[dg * 16 + lx][32 + lg * 8];
      o_acc[dg] = __builtin_amdgcn_mfma_f32_16x16x32_bf16(pa0, v0, o_acc[dg], 0, 0, 0);
      o_acc[dg] = __builtin_amdgcn_mfma_f32_16x16x32_bf16(pa1, v1, o_acc[dg], 0, 0, 0);
    }
  }

#pragma unroll
  for (int i = 0; i < 4; ++i) {
    int srow = qt * 64 + w * 16 + lg * 4 + i;
    int row2 = srow * 2 + b;
    size_t base = (size_t)kvh * ((size_t)N_ * D_) + (size_t)row2 * 512 + h * 64;
#pragma unroll
    for (int dg = 0; dg < 4; ++dg) {
      float val = o_acc[dg][i];
      u16 hi = f2bf(val);
      poh[base + dg * 16 + lx] = hi;
      pol[base + dg * 16 + lx] = f2bf(val - bf2f(hi));
    }
    if (lx == 0) {
      int u = row2 * 8 + h;
      pml[(size_t)kvh * 65536 + u * 2 + 0] = m_run[i];
      pml[(size_t)kvh * 65536 + u * 2 + 1] = l_run[i];
    }
  }
}

// Merge the two KV halves -> split-bf16 ctx.
__global__ __launch_bounds__(256) void merge_attn2(const u16* __restrict__ poh,
                                                   const u16* __restrict__ pol,
                                                   const float* __restrict__ pml,
                                                   u16* __restrict__ ch,
                                                   u16* __restrict__ cl) {
  int u = blockIdx.x * 4 + (threadIdx.x >> 6);
  int lane = threadIdx.x & 63;
  float m0 = pml[u * 2], l0 = pml[u * 2 + 1];
  float m1 = pml[65536 + u * 2], l1 = pml[65536 + u * 2 + 1];
  float m = fmaxf(m0, m1);
  float e0 = __expf(m0 - m), e1 = __expf(m1 - m);
  float inv = 1.f / (l0 * e0 + l1 * e1);
  int n = u >> 3, h = u & 7;
  size_t base = (size_t)n * 512 + h * 64 + lane;
  const size_t PO1 = (size_t)N_ * D_;
  float v0 = bf2f(poh[base]) + bf2f(pol[base]);
  float v1 = bf2f(poh[PO1 + base]) + bf2f(pol[PO1 + base]);
  float val = (v0 * e0 + v1 * e1) * inv;
  u16 hi = f2bf(val);
  ch[base] = hi;
  cl[base] = f2bf(val - bf2f(hi));
}

// ---------------------------------------------------------------------------
// Wo projection: split-bf16 MFMA GEMM, M=4096, N=512, K=512, f32 out.
// ---------------------------------------------------------------------------
__global__ __launch_bounds__(256) void wo_mfma(const u16* __restrict__ Ah_g,
                                               const u16* __restrict__ Al_g,
                                               const u16* __restrict__ Bh_g,
                                               const u16* __restrict__ Bl_g,
                                               const float* __restrict__ bias,
                                               float* __restrict__ C) {
  __shared__ u16 Ah[128][40], Al[128][40], Bh[128][40], Bl[128][40];
  int tid = threadIdx.x;
  int w = tid >> 6, l = tid & 63;
  int wr = w >> 1, wc = w & 1;
  int lg = l >> 4, lx = l & 15;
  int m0 = blockIdx.x * 128, n0 = blockIdx.y * 128;
  int sr = tid >> 1, s16 = (tid & 1) * 16;
  const u16* Aph = Ah_g + (size_t)(m0 + sr) * 512;
  const u16* Apl = Al_g + (size_t)(m0 + sr) * 512;
  const u16* Bph = Bh_g + (size_t)(n0 + sr) * 512;
  const u16* Bpl = Bl_g + (size_t)(n0 + sr) * 512;
  f32x4 acc[4][4];
#pragma unroll
  for (int m = 0; m < 4; ++m)
#pragma unroll
    for (int n = 0; n < 4; ++n) acc[m][n] = (f32x4){0.f, 0.f, 0.f, 0.f};
  for (int k0 = 0; k0 < 512; k0 += 32) {
    short8 ah0 = *(const short8*)&Aph[k0 + s16];
    short8 ah1 = *(const short8*)&Aph[k0 + s16 + 8];
    short8 al0 = *(const short8*)&Apl[k0 + s16];
    short8 al1 = *(const short8*)&Apl[k0 + s16 + 8];
    short8 bh0 = *(const short8*)&Bph[k0 + s16];
    short8 bh1 = *(const short8*)&Bph[k0 + s16 + 8];
    short8 bl0 = *(const short8*)&Bpl[k0 + s16];
    short8 bl1 = *(const short8*)&Bpl[k0 + s16 + 8];
    __syncthreads();
    *(short8*)&Ah[sr][s16] = ah0; *(short8*)&Ah[sr][s16 + 8] = ah1;
    *(short8*)&Al[sr][s16] = al0; *(short8*)&Al[sr][s16 + 8] = al1;
    *(short8*)&Bh[sr][s16] = bh0; *(short8*)&Bh[sr][s16 + 8] = bh1;
    *(short8*)&Bl[sr][s16] = bl0; *(short8*)&Bl[sr][s16 + 8] = bl1;
    __syncthreads();
    short8 fah[4], fal[4], fbh[4], fbl[4];
#pragma unroll
    for (int m = 0; m < 4; ++m) {
      fah[m] = *(const short8*)&Ah[wr * 64 + m * 16 + lx][lg * 8];
      fal[m] = *(const short8*)&Al[wr * 64 + m * 16 + lx][lg * 8];
    }
#pragma unroll
    for (int n = 0; n < 4; ++n) {
      fbh[n] = *(const short8*)&Bh[wc * 64 + n * 16 + lx][lg * 8];
      fbl[n] = *(const short8*)&Bl[wc * 64 + n * 16 + lx][lg * 8];
    }
#pragma unroll
    for (int m = 0; m < 4; ++m)
#pragma unroll
      for (int n = 0; n < 4; ++n) {
        acc[m][n] = __builtin_amdgcn_mfma_f32_16x16x32_bf16(fah[m], fbh[n], acc[m][n], 0, 0, 0);
        acc[m][n] = __builtin_amdgcn_mfma_f32_16x16x32_bf16(fal[m], fbh[n], acc[m][n], 0, 0, 0);
        acc[m][n] = __builtin_amdgcn_mfma_f32_16x16x32_bf16(fah[m], fbl[n], acc[m][n], 0, 0, 0);
      }
  }
#pragma unroll
  for (int m = 0; m < 4; ++m)
#pragma unroll
    for (int i = 0; i < 4; ++i) {
      int row = m0 + wr * 64 + m * 16 + lg * 4 + i;
#pragma unroll
      for (int n = 0; n < 4; ++n) {
        int col = n0 + wc * 64 + n * 16 + lx;
        C[(size_t)row * 512 + col] = acc[m][n][i] + bias[col];
      }
    }
}

// ---------------------------------------------------------------------------
// LayerNorm with residual + bf16 copy.
// ---------------------------------------------------------------------------
__global__ __launch_bounds__(256) void ln_res(const float* __restrict__ a,
                                              const float* __restrict__ b,
                                              const float* __restrict__ g,
                                              const float* __restrict__ beta,
                                              float* __restrict__ out,
                                              u16* __restrict__ obf) {
  int n = blockIdx.x * 4 + (threadIdx.x >> 6);
  int lane = threadIdx.x & 63;
  float v[8];
  float s = 0.f;
#pragma unroll
  for (int i = 0; i < 8; ++i) {
    int d = lane + 64 * i;
    v[i] = a[(size_t)n * D_ + d] + b[(size_t)n * D_ + d];
    s += v[i];
  }
#pragma unroll
  for (int m = 32; m; m >>= 1) s += __shfl_xor(s, m);
  float mean = s * (1.f / D_);
  float s2 = 0.f;
#pragma unroll
  for (int i = 0; i < 8; ++i) { float t = v[i] - mean; s2 += t * t; }
#pragma unroll
  for (int m = 32; m; m >>= 1) s2 += __shfl_xor(s2, m);
  float r = rsqrtf(s2 * (1.f / D_) + 1e-5f);
#pragma unroll
  for (int i = 0; i < 8; ++i) {
    int d = lane + 64 * i;
    float val = (v[i] - mean) * r * g[d] + beta[d];
    out[(size_t)n * D_ + d] = val;
    obf[(size_t)n * D_ + d] = f2bf(val);
  }
}

__global__ __launch_bounds__(256) void ln2_final(const float* __restrict__ x,
                                                 const u16* __restrict__ mp,
                                                 const float* __restrict__ g,
                                                 const float* __restrict__ beta,
                                                 float* __restrict__ out) {
  int n = blockIdx.x * 4 + (threadIdx.x >> 6);
  int lane = threadIdx.x & 63;
  float v[8];
  float s = 0.f;
#pragma unroll
  for (int i = 0; i < 8; ++i) {
    int d = lane + 64 * i;
    v[i] = x[(size_t)n * D_ + d] + bf2f(mp[(size_t)(2 * n) * D_ + d]) +
           bf2f(mp[(size_t)(2 * n + 1) * D_ + d]);
    s += v[i];
  }
#pragma unroll
  for (int m = 32; m; m >>= 1) s += __shfl_xor(s, m);
  float mean = s * (1.f / D_);
  float s2 = 0.f;
#pragma unroll
  for (int i = 0; i < 8; ++i) { float t = v[i] - mean; s2 += t * t; }
#pragma unroll
  for (int m = 32; m; m >>= 1) s2 += __shfl_xor(s2, m);
  float r = rsqrtf(s2 * (1.f / D_) + 1e-5f);
#pragma unroll
  for (int i = 0; i < 8; ++i) {
    int d = lane + 64 * i;
    out[(size_t)n * D_ + d] = (v[i] - mean) * r * g[d] + beta[d];
  }
}

// ---------------------------------------------------------------------------
// Gate phase A: per-token top-2 computation. NO atomics.
// ---------------------------------------------------------------------------
__global__ __launch_bounds__(256) void gate_compute(const float* __restrict__ x,
                                                    const float* __restrict__ Wg,
                                                    float* __restrict__ gp,
                                                    int* __restrict__ tope) {
  int n = blockIdx.x * 4 + (threadIdx.x >> 6);
  int lane = threadIdx.x & 63;
  float p[E_] = {};
  for (int d = lane; d < D_; d += 64) {
    float xv = x[(size_t)n * D_ + d];
    const float* wr = &Wg[(size_t)d * E_];
#pragma unroll
    for (int e = 0; e < E_; ++e) p[e] += xv * wr[e];
  }
#pragma unroll
  for (int e = 0; e < E_; ++e)
#pragma unroll
    for (int m = 32; m; m >>= 1) p[e] += __shfl_xor(p[e], m);
  if (lane == 0) {
    float mx = p[0];
#pragma unroll
    for (int e = 1; e < E_; ++e) mx = fmaxf(mx, p[e]);
    float q[E_];
#pragma unroll
    for (int e = 0; e < E_; ++e) q[e] = expf(p[e] - mx);
    int e1 = 0;
#pragma unroll
    for (int e = 1; e < E_; ++e) if (q[e] > q[e1]) e1 = e;
    int e2 = (e1 == 0) ? 1 : 0;
#pragma unroll
    for (int e = 0; e < E_; ++e) if (e != e1 && q[e] > q[e2]) e2 = e;
    float denom = q[e1] + q[e2];
    gp[n * 2] = q[e1] / denom;
    gp[n * 2 + 1] = q[e2] / denom;
    tope[n] = e1 | (e2 << 8);
  }
}

// ---------------------------------------------------------------------------
// Gate phase B: per-expert ordered compaction. One block per expert.
// ---------------------------------------------------------------------------
__global__ __launch_bounds__(256) void route_build(const int* __restrict__ tope,
                                                   int* __restrict__ cnt,
                                                   int* __restrict__ lst) {
  int e = blockIdx.x;
  __shared__ int wsum[4];
  __shared__ int basem;
  int tid = threadIdx.x;
  int w = tid >> 6, lane = tid & 63;
  if (tid == 0) basem = 0;
  __syncthreads();
  for (int c0 = 0; c0 < N_; c0 += 256) {
    int n = c0 + tid;
    int te = tope[n];
    int e1 = te & 0xff, e2 = (te >> 8) & 0xff;
    bool m2 = (e2 == e);
    bool flag = (e1 == e) || m2;
    unsigned long long mask = __ballot(flag);
    int wpre = __popcll(mask & ((1ull << lane) - 1ull));
    if (lane == 0) wsum[w] = __popcll(mask);
    __syncthreads();
    int woff = 0;
    for (int i = 0; i < w; ++i) woff += wsum[i];
    int total = wsum[0] + wsum[1] + wsum[2] + wsum[3];
    if (flag) lst[e * N_ + basem + woff + wpre] = n * 2 + (m2 ? 1 : 0);
    __syncthreads();
    if (tid == 0) basem += total;
    __syncthreads();
  }
  if (tid == 0) cnt[e] = basem;
}

// ---------------------------------------------------------------------------
// bf16 MFMA MoE GEMM, 64x128 tile, BK=32, 4 waves (each 64x32 out).
// Flat grid, expert = blockIdx & 7 -> expert pinned to one XCD (L2 locality).
// Register prefetch of next K-step hides L2 latency under LDS-read+MFMA.
// ---------------------------------------------------------------------------
template <int MODE>
__global__ __launch_bounds__(256) void moe_mfma(const u16* __restrict__ Abase,
                                                const u16* __restrict__ Wt,
                                                const float* __restrict__ bias,
                                                const float* __restrict__ gp,
                                                u16* __restrict__ outp,
                                                const int* __restrict__ cnt,
                                                const int* __restrict__ lst) {
  constexpr int K  = MODE ? 1024 : 512;
  constexpr int Nn = MODE ? 512 : 1024;
  constexpr int NT = Nn / 128;          // n-tiles: 8 (moe1) / 4 (moe2)
  constexpr int NI = K / 32;            // K-steps: 16 / 32
  int fidx = blockIdx.x;
  int e = fidx & 7;                     // expert == XCD (id % 8 round-robin)
  int r = fidx >> 3;
  int nt = r % NT;
  int mt = r / NT;                      // [0, 64)
  int c = cnt[e];
  int m0 = mt * 64;
  if (m0 >= c) return;
  int off = 0;
#pragma unroll
  for (int i = 0; i < E_; ++i) if (i < e) off += cnt[i];
  int n0 = nt * 128;
  __shared__ u16 As[64][40];
  __shared__ u16 Bs[128][40];
  int tid = threadIdx.x;
  int w = tid >> 6, l = tid & 63;
  int lg = l >> 4, lx = l & 15;
  // staging maps
  int arow = tid >> 2, aseg = (tid & 3) * 8;    // A: 64 rows x 32k, 8 el/thread
  int brow = tid >> 1, bseg = (tid & 1) * 16;   // B: 128 rows x 32k, 16 el/thread
  int ar = m0 + arow; if (ar >= c) ar = c - 1;
  const u16* Ap;
  if (MODE == 0) Ap = Abase + (size_t)(lst[e * N_ + ar] >> 1) * 512 + aseg;
  else           Ap = Abase + (size_t)(off + ar) * 1024 + aseg;
  const u16* Bp = Wt + (size_t)e * K * Nn + (size_t)(n0 + brow) * K + bseg;

  f32x4 acc[4][2];
#pragma unroll
  for (int m = 0; m < 4; ++m)
#pragma unroll
    for (int n = 0; n < 2; ++n) acc[m][n] = (f32x4){0.f, 0.f, 0.f, 0.f};

  short8 pa  = *(const short8*)&Ap[0];
  short8 pb0 = *(const short8*)&Bp[0];
  short8 pb1 = *(const short8*)&Bp[8];
  for (int kk = 0; kk < NI; ++kk) {
    __syncthreads();
    *(short8*)&As[arow][aseg] = pa;
    *(short8*)&Bs[brow][bseg] = pb0;
    *(short8*)&Bs[brow][bseg + 8] = pb1;
    __syncthreads();
    if (kk + 1 < NI) {                     // prefetch next K-step (in flight
      int ko = (kk + 1) * 32;              //  during LDS reads + MFMA below)
      pa  = *(const short8*)&Ap[ko];
      pb0 = *(const short8*)&Bp[ko];
      pb1 = *(const short8*)&Bp[ko + 8];
    }
    short8 af[4], bf[2];
#pragma unroll
    for (int m = 0; m < 4; ++m)
      af[m] = *(const short8*)&As[m * 16 + lx][lg * 8];
#pragma unroll
    for (int n = 0; n < 2; ++n)
      bf[n] = *(const short8*)&Bs[w * 32 + n * 16 + lx][lg * 8];
#pragma unroll
    for (int m = 0; m < 4; ++m)
#pragma unroll
      for (int n = 0; n < 2; ++n)
        acc[m][n] = __builtin_amdgcn_mfma_f32_16x16x32_bf16(af[m], bf[n], acc[m][n], 0, 0, 0);
  }
#pragma unroll
  for (int m = 0; m < 4; ++m)
#pragma unroll
    for (int i = 0; i < 4; ++i) {
      int rr = m0 + m * 16 + lg * 4 + i;
      if (rr < c) {
#pragma unroll
        for (int n = 0; n < 2; ++n) {
          int col = n0 + w * 32 + n * 16 + lx;
          float val = acc[m][n][i] + bias[e * Nn + col];
          if (MODE == 0) {
            outp[(size_t)(off + rr) * 1024 + col] = f2bf(fmaxf(val, 0.f));
          } else {
            int p = lst[e * N_ + rr];
            outp[(size_t)p * 512 + col] = f2bf(gp[p] * val);
          }
        }
      }
    }
}

// ---------------------------------------------------------------------------
extern "C" void kernel_launch(void* const* d_in, const int* in_sizes, int n_in,
                              void* d_out, int out_size, void* d_ws, size_t ws_size,
                              hipStream_t stream) {
  const float* src  = (const float*)d_in[0];
  const float* cosb = (const float*)d_in[1];
  const float* sinb = (const float*)d_in[2];
  const float* Wq   = (const float*)d_in[3];
  const float* bq   = (const float*)d_in[4];
  const float* Wk   = (const float*)d_in[5];
  const float* bk   = (const float*)d_in[6];
  const float* Wv   = (const float*)d_in[7];
  const float* bv   = (const float*)d_in[8];
  const float* Wo   = (const float*)d_in[9];
  const float* bo   = (const float*)d_in[10];
  const float* ln1g = (const float*)d_in[11];
  const float* ln1b = (const float*)d_in[12];
  const float* ln2g = (const float*)d_in[13];
  const float* ln2b = (const float*)d_in[14];
  const float* Wg   = (const float*)d_in[15];
  const float* W1   = (const float*)d_in[16];
  const float* B1   = (const float*)d_in[17];
  const float* W2   = (const float*)d_in[18];
  const float* B2   = (const float*)d_in[19];
  float* out = (float*)d_out;
  char* wsb = (char*)d_ws;

  const size_t MB1 = 1u << 20;
  // Byte layout (~60.4 MB high-water):
  u16* sh   = (u16*)(wsb + 0 * MB1);      // src hi  [0,4M)   ; later ch, then mp
  u16* sl   = (u16*)(wsb + 4 * MB1);      // src lo  [4,8M)   ; later cl
  u16* qhb  = (u16*)(wsb + 8 * MB1);      // [8,12M)          ; later hbf part
  u16* qlb  = (u16*)(wsb + 12 * MB1);
  u16* khb  = (u16*)(wsb + 16 * MB1);
  u16* klb  = (u16*)(wsb + 20 * MB1);
  u16* vbuf = (u16*)(wsb + 24 * MB1);     // [24,28M)
  u16* poh  = (u16*)(wsb + 28 * MB1);     // [28,36M) attn partial hi ; later aob f32, then W2t
  u16* pol  = (u16*)(wsb + 36 * MB1);     // [36,44M) attn partial lo ; later xb f32
  float* pml = (float*)(wsb + 44 * MB1);  // [44,44.5M)       ; later xbf
  float* aob = (float*)(wsb + 28 * MB1);  // [28,36M)
  float* xb  = (float*)(wsb + 36 * MB1);  // [36,44M)
  u16* xbf   = (u16*)(wsb + 44 * MB1);    // [44,48M)
  u16* Wqkv_hi = (u16*)(wsb + 48 * MB1);              // 1.5MB
  u16* Wqkv_lo = (u16*)(wsb + 48 * MB1 + 1572864);    // 1.5MB
  u16* Wo_hi   = (u16*)(wsb + 48 * MB1 + 3145728);    // 0.5MB
  u16* Wo_lo   = (u16*)(wsb + 48 * MB1 + 3670016);    // 0.5MB
  u16* W1t     = (u16*)(wsb + 52 * MB1);  // [52,60M)
  u16* W2t     = (u16*)(wsb + 28 * MB1);  // [28,36M) — written after ln_res (aob dead)
  float* gpb   = (float*)(wsb + 60 * MB1);                 // 32 KB
  int* cnt     = (int*)(wsb + 60 * MB1 + 32768);           // 64 B
  int* lst     = (int*)(wsb + 60 * MB1 + 32768 + 64);      // 128 KB
  int* tope    = (int*)(wsb + 60 * MB1 + 32768 + 64 + 131072);  // 16 KB
  u16* ch  = sh;                          // ctx hi aliases src-split (dead)
  u16* cl  = sl;
  u16* hbf = (u16*)(wsb + 8 * MB1);       // [8,24M) aliases q/k (dead after attn)
  u16* mp  = (u16*)(wsb + 0 * MB1);       // [0,8M)  aliases ch/cl (dead after wo)

  dim3 blk(256);
  src_split<<<dim3(1024), blk, 0, stream>>>(src, sh, sl);
  wsplit_t<<<dim3(8, 8), blk, 0, stream>>>(Wq, Wqkv_hi, Wqkv_lo, 512, 512);
  wsplit_t<<<dim3(8, 8), blk, 0, stream>>>(Wk, Wqkv_hi + 512 * 512, Wqkv_lo + 512 * 512, 512, 512);
  wsplit_t<<<dim3(8, 8), blk, 0, stream>>>(Wv, Wqkv_hi + 1024 * 512, Wqkv_lo + 1024 * 512, 512, 512);
  wsplit_t<<<dim3(8, 8), blk, 0, stream>>>(Wo, Wo_hi, Wo_lo, 512, 512);
  // QKV + RoPE fused (split-bf16, f32-grade)
  qkv_mfma<<<dim3(32, 12), blk, 0, stream>>>(sh, sl, Wqkv_hi, Wqkv_lo, bq, bk, bv,
                                             cosb, sinb, qhb, qlb, khb, klb, vbuf);
  // Attention, KV-split=2, XCD-pinned slabs + merge
  attn_mfma2<<<dim3(1024), blk, 0, stream>>>(qhb, qlb, khb, klb, vbuf, poh, pol, pml);
  merge_attn2<<<dim3(8192), blk, 0, stream>>>(poh, pol, pml, ch, cl);
  // Wo projection (split-bf16)
  wo_mfma<<<dim3(32, 4), blk, 0, stream>>>(ch, cl, Wo_hi, Wo_lo, bo, aob);
  // LN1 (+bf16 copy)
  ln_res<<<dim3(1024), blk, 0, stream>>>(src, aob, ln1g, ln1b, xb, xbf);
  // MoE weight transposes BEFORE the expert GEMMs (no L2 pollution between them)
  wtrans<<<dim3(8, 16, 8), blk, 0, stream>>>(W2, W2t, 1024, 512);
  wtrans<<<dim3(16, 8, 8), blk, 0, stream>>>(W1, W1t, 512, 1024);
  // Gate (atomic-free) + ordered routing
  gate_compute<<<dim3(1024), blk, 0, stream>>>(xb, Wg, gpb, tope);
  route_build<<<dim3(8), blk, 0, stream>>>(tope, cnt, lst);
  // Sparse MoE expert GEMMs — expert pinned to XCD via flat-grid id&7
  moe_mfma<0><<<dim3(8 * 8 * 64), blk, 0, stream>>>(xbf, W1t, B1, gpb, hbf, cnt, lst);
  moe_mfma<1><<<dim3(8 * 4 * 64), blk, 0, stream>>>(hbf, W2t, B2, gpb, mp, cnt, lst);
  ln2_final<<<dim3(1024), blk, 0, stream>>>(xb, mp, ln2g, ln2b, out);
}

// Round 8
// 251.094 us; speedup vs baseline: 4.6645x; 1.0096x over previous
//
#include <hip/hip_runtime.h>
#include <math.h>

// Shapes (fixed)
#define S_  2048
#define B_  2
#define D_  512
#define H_  8
#define DH_ 64
#define E_  8
#define F_  1024
#define N_  4096   // S_*B_
#define NPAIR_ 8192

typedef __attribute__((ext_vector_type(4))) float f32x4;
typedef __attribute__((ext_vector_type(8))) short short8;
typedef unsigned short u16;

__device__ __forceinline__ u16 f2bf(float f) {
  unsigned u = __builtin_bit_cast(unsigned, f);
  u += 0x7fffu + ((u >> 16) & 1u);
  return (u16)(u >> 16);
}
__device__ __forceinline__ float bf2f(u16 h) {
  unsigned u = ((unsigned)h) << 16;
  return __builtin_bit_cast(float, u);
}

// ---------------------------------------------------------------------------
// src -> split bf16 (hi, lo). 2M elements, 8/thread.
// ---------------------------------------------------------------------------
__global__ __launch_bounds__(256) void src_split(const float* __restrict__ in,
                                                 u16* __restrict__ hi,
                                                 u16* __restrict__ lo) {
  size_t i = ((size_t)blockIdx.x * 256 + threadIdx.x) * 8;
  float f[8];
  *(float4*)&f[0] = *(const float4*)&in[i];
  *(float4*)&f[4] = *(const float4*)&in[i + 4];
  short8 h, l;
#pragma unroll
  for (int j = 0; j < 8; ++j) {
    u16 a = f2bf(f[j]);
    h[j] = (short)a;
    l[j] = (short)f2bf(f[j] - bf2f(a));
  }
  *(short8*)&hi[i] = h;
  *(short8*)&lo[i] = l;
}

// ---------------------------------------------------------------------------
// Weight transpose + split: Whi/Wlo[n][k] = split(W[k][n]). W is [K][Nn].
// ---------------------------------------------------------------------------
__global__ __launch_bounds__(256) void wsplit_t(const float* __restrict__ W,
                                                u16* __restrict__ Whi,
                                                u16* __restrict__ Wlo,
                                                int Nn, int K) {
  __shared__ u16 Th[64][72];
  __shared__ u16 Tl[64][72];
  int kb = blockIdx.y * 64, nb = blockIdx.x * 64;
  int r = threadIdx.x >> 2, c0 = (threadIdx.x & 3) * 16;
  const float* wp = &W[(size_t)(kb + r) * Nn + nb + c0];
#pragma unroll
  for (int c = 0; c < 16; c += 4) {
    float4 t = *(const float4*)&wp[c];
    float f[4] = {t.x, t.y, t.z, t.w};
#pragma unroll
    for (int j = 0; j < 4; ++j) {
      u16 a = f2bf(f[j]);
      Th[r][c0 + c + j] = a;
      Tl[r][c0 + c + j] = f2bf(f[j] - bf2f(a));
    }
  }
  __syncthreads();
  short8 h0, h1, l0, l1;
#pragma unroll
  for (int j = 0; j < 8; ++j) {
    h0[j] = (short)Th[c0 + j][r];     h1[j] = (short)Th[c0 + 8 + j][r];
    l0[j] = (short)Tl[c0 + j][r];     l1[j] = (short)Tl[c0 + 8 + j][r];
  }
  size_t ob = (size_t)(nb + r) * K + kb + c0;
  *(short8*)&Whi[ob] = h0;  *(short8*)&Whi[ob + 8] = h1;
  *(short8*)&Wlo[ob] = l0;  *(short8*)&Wlo[ob + 8] = l1;
}

// ---------------------------------------------------------------------------
// Plain bf16 weight transpose for MoE (W1, W2).
// ---------------------------------------------------------------------------
__global__ __launch_bounds__(256) void wtrans(const float* __restrict__ W,
                                              u16* __restrict__ Wt,
                                              int K, int Nn) {
  size_t eo = (size_t)blockIdx.z * K * Nn;
  __shared__ u16 T[64][72];
  int kb = blockIdx.y * 64, nb = blockIdx.x * 64;
  int r = threadIdx.x >> 2, c0 = (threadIdx.x & 3) * 16;
  const float* wp = &W[eo + (size_t)(kb + r) * Nn + nb + c0];
#pragma unroll
  for (int c = 0; c < 16; c += 4) {
    float4 t = *(const float4*)&wp[c];
    T[r][c0 + c + 0] = f2bf(t.x);
    T[r][c0 + c + 1] = f2bf(t.y);
    T[r][c0 + c + 2] = f2bf(t.z);
    T[r][c0 + c + 3] = f2bf(t.w);
  }
  __syncthreads();
  short8 s0, s1;
#pragma unroll
  for (int j = 0; j < 8; ++j) {
    s0[j] = (short)T[c0 + j][r];
    s1[j] = (short)T[c0 + 8 + j][r];
  }
  *(short8*)&Wt[eo + (size_t)(nb + r) * K + kb + c0] = s0;
  *(short8*)&Wt[eo + (size_t)(nb + r) * K + kb + c0 + 8] = s1;
}

// ---------------------------------------------------------------------------
// Fused QKV split-bf16 MFMA GEMM + RoPE. M=4096, N=1536, K=512.
// Register prefetch of next K-step (async-stage split).
// ---------------------------------------------------------------------------
__global__ __launch_bounds__(256) void qkv_mfma(const u16* __restrict__ Ah_g,
                                                const u16* __restrict__ Al_g,
                                                const u16* __restrict__ Bh_g,
                                                const u16* __restrict__ Bl_g,
                                                const float* __restrict__ bq,
                                                const float* __restrict__ bk,
                                                const float* __restrict__ bv,
                                                const float* __restrict__ cosb,
                                                const float* __restrict__ sinb,
                                                u16* __restrict__ qh, u16* __restrict__ ql,
                                                u16* __restrict__ kh, u16* __restrict__ kl,
                                                u16* __restrict__ vb) {
  __shared__ u16 Ah[128][40], Al[128][40], Bh[128][40], Bl[128][40];
  int tid = threadIdx.x;
  int w = tid >> 6, l = tid & 63;
  int wr = w >> 1, wc = w & 1;
  int lg = l >> 4, lx = l & 15;
  int m0 = blockIdx.x * 128, n0 = blockIdx.y * 128;
  int sr = tid >> 1, s16 = (tid & 1) * 16;
  const u16* Aph = Ah_g + (size_t)(m0 + sr) * 512;
  const u16* Apl = Al_g + (size_t)(m0 + sr) * 512;
  const u16* Bph = Bh_g + (size_t)(n0 + sr) * 512;
  const u16* Bpl = Bl_g + (size_t)(n0 + sr) * 512;
  f32x4 acc[4][4];
#pragma unroll
  for (int m = 0; m < 4; ++m)
#pragma unroll
    for (int n = 0; n < 4; ++n) acc[m][n] = (f32x4){0.f, 0.f, 0.f, 0.f};
  short8 ah0 = *(const short8*)&Aph[s16];
  short8 ah1 = *(const short8*)&Aph[s16 + 8];
  short8 al0 = *(const short8*)&Apl[s16];
  short8 al1 = *(const short8*)&Apl[s16 + 8];
  short8 bh0 = *(const short8*)&Bph[s16];
  short8 bh1 = *(const short8*)&Bph[s16 + 8];
  short8 bl0 = *(const short8*)&Bpl[s16];
  short8 bl1 = *(const short8*)&Bpl[s16 + 8];
  for (int k0 = 0; k0 < 512; k0 += 32) {
    __syncthreads();
    *(short8*)&Ah[sr][s16] = ah0; *(short8*)&Ah[sr][s16 + 8] = ah1;
    *(short8*)&Al[sr][s16] = al0; *(short8*)&Al[sr][s16 + 8] = al1;
    *(short8*)&Bh[sr][s16] = bh0; *(short8*)&Bh[sr][s16 + 8] = bh1;
    *(short8*)&Bl[sr][s16] = bl0; *(short8*)&Bl[sr][s16 + 8] = bl1;
    __syncthreads();
    if (k0 + 32 < 512) {                // prefetch next K-step under compute
      int ko = k0 + 32 + s16;
      ah0 = *(const short8*)&Aph[ko]; ah1 = *(const short8*)&Aph[ko + 8];
      al0 = *(const short8*)&Apl[ko]; al1 = *(const short8*)&Apl[ko + 8];
      bh0 = *(const short8*)&Bph[ko]; bh1 = *(const short8*)&Bph[ko + 8];
      bl0 = *(const short8*)&Bpl[ko]; bl1 = *(const short8*)&Bpl[ko + 8];
    }
    short8 fah[4], fal[4], fbh[4], fbl[4];
#pragma unroll
    for (int m = 0; m < 4; ++m) {
      fah[m] = *(const short8*)&Ah[wr * 64 + m * 16 + lx][lg * 8];
      fal[m] = *(const short8*)&Al[wr * 64 + m * 16 + lx][lg * 8];
    }
#pragma unroll
    for (int n = 0; n < 4; ++n) {
      fbh[n] = *(const short8*)&Bh[wc * 64 + n * 16 + lx][lg * 8];
      fbl[n] = *(const short8*)&Bl[wc * 64 + n * 16 + lx][lg * 8];
    }
#pragma unroll
    for (int m = 0; m < 4; ++m)
#pragma unroll
      for (int n = 0; n < 4; ++n) {
        acc[m][n] = __builtin_amdgcn_mfma_f32_16x16x32_bf16(fah[m], fbh[n], acc[m][n], 0, 0, 0);
        acc[m][n] = __builtin_amdgcn_mfma_f32_16x16x32_bf16(fal[m], fbh[n], acc[m][n], 0, 0, 0);
        acc[m][n] = __builtin_amdgcn_mfma_f32_16x16x32_bf16(fah[m], fbl[n], acc[m][n], 0, 0, 0);
      }
  }
  // ---- epilogue ----
  int tcolbase = n0 + wc * 64;
  int tsel = tcolbase >> 9;             // 0=q, 1=k, 2=v
  int hbase = tcolbase & 511;
  const float* bias = (tsel == 0) ? bq : (tsel == 1) ? bk : bv;
  if (tsel == 2) {
#pragma unroll
    for (int m = 0; m < 4; ++m)
#pragma unroll
      for (int i = 0; i < 4; ++i) {
        int row = m0 + wr * 64 + m * 16 + lg * 4 + i;
#pragma unroll
        for (int n = 0; n < 4; ++n) {
          int col = hbase + n * 16 + lx;
          vb[(size_t)row * 512 + col] = f2bf(acc[m][n][i] + bias[col]);
        }
      }
  } else {
    u16* oh = tsel ? kh : qh;
    u16* ol = tsel ? kl : ql;
    float qsc = tsel ? 1.f : 0.125f;
#pragma unroll
    for (int m = 0; m < 4; ++m)
#pragma unroll
      for (int i = 0; i < 4; ++i) {
        int row = m0 + wr * 64 + m * 16 + lg * 4 + i;
        int s = row >> 1;
#pragma unroll
        for (int n = 0; n < 2; ++n) {
          int dln = n * 16 + lx;
          float c  = cosb[s * 64 + dln];
          float sn = sinb[s * 64 + dln];
          float a  = acc[m][n][i]     + bias[hbase + dln];
          float b2 = acc[m][n + 2][i] + bias[hbase + dln + 32];
          float ra = (a * c - b2 * sn) * qsc;
          float rb = (b2 * c + a * sn) * qsc;
          size_t ix = (size_t)row * 512 + hbase + dln;
          u16 rah = f2bf(ra);
          oh[ix] = rah; ol[ix] = f2bf(ra - bf2f(rah));
          u16 rbh = f2bf(rb);
          oh[ix + 32] = rbh; ol[ix + 32] = f2bf(rb - bf2f(rbh));
        }
      }
  }
}

// ---------------------------------------------------------------------------
// MFMA flash attention, KV-split=2, XCD-pinned (b,h,kvh) slabs.
// Register prefetch of next KV tile; P-store XOR-swizzled (bank-conflict-free).
// ---------------------------------------------------------------------------
__global__ __launch_bounds__(256) void attn_mfma2(const u16* __restrict__ qh,
                                                  const u16* __restrict__ ql,
                                                  const u16* __restrict__ kh,
                                                  const u16* __restrict__ kl,
                                                  const u16* __restrict__ vbuf,
                                                  u16* __restrict__ poh,
                                                  u16* __restrict__ pol,
                                                  float* __restrict__ pml) {
  __shared__ u16 Khi[64][72];
  __shared__ u16 Klo[64][72];
  __shared__ u16 Vt[64][72];
  __shared__ u16 Pl[4][16][72];
  int tid = threadIdx.x;
  int w = tid >> 6, l = tid & 63;
  int lg = l >> 4, lx = l & 15;
  int f = blockIdx.x;
  int xcd = f & 7, j = f >> 3;
  int slab = xcd + 8 * (j & 3);   // 0..31 : all qt of a slab share an XCD
  int qt = j >> 2;                // 0..31
  int bh = slab >> 1, kvh = slab & 1;
  int b = bh >> 3, h = bh & 7;

  short8 qfh[2], qfl[2];
  {
    int qrow = qt * 64 + w * 16 + lx;
    size_t qo = (size_t)(qrow * 2 + b) * 512 + h * 64 + lg * 8;
    qfh[0] = *(const short8*)&qh[qo];
    qfh[1] = *(const short8*)&qh[qo + 32];
    qfl[0] = *(const short8*)&ql[qo];
    qfl[1] = *(const short8*)&ql[qo + 32];
  }

  f32x4 o_acc[4];
#pragma unroll
  for (int dg = 0; dg < 4; ++dg) o_acc[dg] = (f32x4){0.f, 0.f, 0.f, 0.f};
  float m_run[4], l_run[4];
#pragma unroll
  for (int i = 0; i < 4; ++i) { m_run[i] = -1e30f; l_run[i] = 0.f; }

  int kvr = tid >> 2, ds4 = (tid & 3) * 16;
  int kvc = tid & 63, dsg = (tid >> 6) * 16;
  int psw = ((lx >> 2) & 3) << 3;       // read-side P swizzle (row = lx)

  // preload tile 0 into regs
  short8 rkh0, rkh1, rkl0, rkl1, rv0, rv1;
  {
    int t0 = kvh * 1024;
    size_t ko = (size_t)((t0 + kvr) * 2 + b) * 512 + h * 64 + ds4;
    rkh0 = *(const short8*)&kh[ko]; rkh1 = *(const short8*)&kh[ko + 8];
    rkl0 = *(const short8*)&kl[ko]; rkl1 = *(const short8*)&kl[ko + 8];
    size_t vo = (size_t)((t0 + kvc) * 2 + b) * 512 + h * 64 + dsg;
    rv0 = *(const short8*)&vbuf[vo]; rv1 = *(const short8*)&vbuf[vo + 8];
  }

  for (int tt = 0; tt < 1024; tt += 64) {
    __syncthreads();
    // ---- write staged tile from regs ----
    *(short8*)&Khi[kvr][ds4]     = rkh0;
    *(short8*)&Khi[kvr][ds4 + 8] = rkh1;
    *(short8*)&Klo[kvr][ds4]     = rkl0;
    *(short8*)&Klo[kvr][ds4 + 8] = rkl1;
#pragma unroll
    for (int c = 0; c < 8; ++c) {
      Vt[dsg + c][kvc] = (u16)rv0[c];
      Vt[dsg + 8 + c][kvc] = (u16)rv1[c];
    }
    __syncthreads();
    // ---- prefetch next tile (in flight during compute) ----
    if (tt + 64 < 1024) {
      int t0 = kvh * 1024 + tt + 64;
      size_t ko = (size_t)((t0 + kvr) * 2 + b) * 512 + h * 64 + ds4;
      rkh0 = *(const short8*)&kh[ko]; rkh1 = *(const short8*)&kh[ko + 8];
      rkl0 = *(const short8*)&kl[ko]; rkl1 = *(const short8*)&kl[ko + 8];
      size_t vo = (size_t)((t0 + kvc) * 2 + b) * 512 + h * 64 + dsg;
      rv0 = *(const short8*)&vbuf[vo]; rv1 = *(const short8*)&vbuf[vo + 8];
    }

    // ---- QK^T (split-bf16: 3 products) ----
    f32x4 sc[4];
#pragma unroll
    for (int cg = 0; cg < 4; ++cg) {
      short8 kf0 = *(const short8*)&Khi[cg * 16 + lx][lg * 8];
      short8 kf1 = *(const short8*)&Khi[cg * 16 + lx][32 + lg * 8];
      short8 kg0 = *(const short8*)&Klo[cg * 16 + lx][lg * 8];
      short8 kg1 = *(const short8*)&Klo[cg * 16 + lx][32 + lg * 8];
      f32x4 a = (f32x4){0.f, 0.f, 0.f, 0.f};
      a = __builtin_amdgcn_mfma_f32_16x16x32_bf16(qfh[0], kf0, a, 0, 0, 0);
      a = __builtin_amdgcn_mfma_f32_16x16x32_bf16(qfh[1], kf1, a, 0, 0, 0);
      a = __builtin_amdgcn_mfma_f32_16x16x32_bf16(qfl[0], kf0, a, 0, 0, 0);
      a = __builtin_amdgcn_mfma_f32_16x16x32_bf16(qfl[1], kf1, a, 0, 0, 0);
      a = __builtin_amdgcn_mfma_f32_16x16x32_bf16(qfh[0], kg0, a, 0, 0, 0);
      a = __builtin_amdgcn_mfma_f32_16x16x32_bf16(qfh[1], kg1, a, 0, 0, 0);
      sc[cg] = a;
    }

    // ---- online softmax (P stored with XOR swizzle) ----
#pragma unroll
    for (int i = 0; i < 4; ++i) {
      float s0 = sc[0][i], s1 = sc[1][i], s2 = sc[2][i], s3 = sc[3][i];
      float tm = fmaxf(fmaxf(s0, s1), fmaxf(s2, s3));
      tm = fmaxf(tm, __shfl_xor(tm, 1));
      tm = fmaxf(tm, __shfl_xor(tm, 2));
      tm = fmaxf(tm, __shfl_xor(tm, 4));
      tm = fmaxf(tm, __shfl_xor(tm, 8));
      float mn = fmaxf(m_run[i], tm);
      float corr = __expf(m_run[i] - mn);
      m_run[i] = mn;
      float p0 = __expf(s0 - mn), p1 = __expf(s1 - mn);
      float p2 = __expf(s2 - mn), p3 = __expf(s3 - mn);
      float ts = p0 + p1 + p2 + p3;
      ts += __shfl_xor(ts, 1); ts += __shfl_xor(ts, 2);
      ts += __shfl_xor(ts, 4); ts += __shfl_xor(ts, 8);
      l_run[i] = l_run[i] * corr + ts;
#pragma unroll
      for (int dg = 0; dg < 4; ++dg) o_acc[dg][i] *= corr;
      int row = lg * 4 + i;
      int sw = ((row >> 2) & 3) << 3;   // = lg*8 & 24
      Pl[w][row][lx ^ sw]        = f2bf(p0);
      Pl[w][row][(16 + lx) ^ sw] = f2bf(p1);
      Pl[w][row][(32 + lx) ^ sw] = f2bf(p2);
      Pl[w][row][(48 + lx) ^ sw] = f2bf(p3);
    }

    // ---- PV ----
    short8 pa0 = *(const short8*)&Pl[w][lx][(lg * 8) ^ psw];
    short8 pa1 = *(const short8*)&Pl[w][lx][(32 + lg * 8) ^ psw];
#pragma unroll
    for (int dg = 0; dg < 4; ++dg) {
      short8 v0 = *(const short8*)&Vt[dg * 16 + lx][lg * 8];
      short8 v1 = *(const short8*)&Vt[dg * 16 + lx][32 + lg * 8];
      o_acc[dg] = __builtin_amdgcn_mfma_f32_16x16x32_bf16(pa0, v0, o_acc[dg], 0, 0, 0);
      o_acc[dg] = __builtin_amdgcn_mfma_f32_16x16x32_bf16(pa1, v1, o_acc[dg], 0, 0, 0);
    }
  }

#pragma unroll
  for (int i = 0; i < 4; ++i) {
    int srow = qt * 64 + w * 16 + lg * 4 + i;
    int row2 = srow * 2 + b;
    size_t base = (size_t)kvh * ((size_t)N_ * D_) + (size_t)row2 * 512 + h * 64;
#pragma unroll
    for (int dg = 0; dg < 4; ++dg) {
      float val = o_acc[dg][i];
      u16 hi = f2bf(val);
      poh[base + dg * 16 + lx] = hi;
      pol[base + dg * 16 + lx] = f2bf(val - bf2f(hi));
    }
    if (lx == 0) {
      int u = row2 * 8 + h;
      pml[(size_t)kvh * 65536 + u * 2 + 0] = m_run[i];
      pml[(size_t)kvh * 65536 + u * 2 + 1] = l_run[i];
    }
  }
}

// Merge the two KV halves -> split-bf16 ctx.
__global__ __launch_bounds__(256) void merge_attn2(const u16* __restrict__ poh,
                                                   const u16* __restrict__ pol,
                                                   const float* __restrict__ pml,
                                                   u16* __restrict__ ch,
                                                   u16* __restrict__ cl) {
  int u = blockIdx.x * 4 + (threadIdx.x >> 6);
  int lane = threadIdx.x & 63;
  float m0 = pml[u * 2], l0 = pml[u * 2 + 1];
  float m1 = pml[65536 + u * 2], l1 = pml[65536 + u * 2 + 1];
  float m = fmaxf(m0, m1);
  float e0 = __expf(m0 - m), e1 = __expf(m1 - m);
  float inv = 1.f / (l0 * e0 + l1 * e1);
  int n = u >> 3, h = u & 7;
  size_t base = (size_t)n * 512 + h * 64 + lane;
  const size_t PO1 = (size_t)N_ * D_;
  float v0 = bf2f(poh[base]) + bf2f(pol[base]);
  float v1 = bf2f(poh[PO1 + base]) + bf2f(pol[PO1 + base]);
  float val = (v0 * e0 + v1 * e1) * inv;
  u16 hi = f2bf(val);
  ch[base] = hi;
  cl[base] = f2bf(val - bf2f(hi));
}

// ---------------------------------------------------------------------------
// Wo projection: split-bf16 MFMA GEMM, M=4096, N=512, K=512, f32 out.
// Register prefetch of next K-step.
// ---------------------------------------------------------------------------
__global__ __launch_bounds__(256) void wo_mfma(const u16* __restrict__ Ah_g,
                                               const u16* __restrict__ Al_g,
                                               const u16* __restrict__ Bh_g,
                                               const u16* __restrict__ Bl_g,
                                               const float* __restrict__ bias,
                                               float* __restrict__ C) {
  __shared__ u16 Ah[128][40], Al[128][40], Bh[128][40], Bl[128][40];
  int tid = threadIdx.x;
  int w = tid >> 6, l = tid & 63;
  int wr = w >> 1, wc = w & 1;
  int lg = l >> 4, lx = l & 15;
  int m0 = blockIdx.x * 128, n0 = blockIdx.y * 128;
  int sr = tid >> 1, s16 = (tid & 1) * 16;
  const u16* Aph = Ah_g + (size_t)(m0 + sr) * 512;
  const u16* Apl = Al_g + (size_t)(m0 + sr) * 512;
  const u16* Bph = Bh_g + (size_t)(n0 + sr) * 512;
  const u16* Bpl = Bl_g + (size_t)(n0 + sr) * 512;
  f32x4 acc[4][4];
#pragma unroll
  for (int m = 0; m < 4; ++m)
#pragma unroll
    for (int n = 0; n < 4; ++n) acc[m][n] = (f32x4){0.f, 0.f, 0.f, 0.f};
  short8 ah0 = *(const short8*)&Aph[s16];
  short8 ah1 = *(const short8*)&Aph[s16 + 8];
  short8 al0 = *(const short8*)&Apl[s16];
  short8 al1 = *(const short8*)&Apl[s16 + 8];
  short8 bh0 = *(const short8*)&Bph[s16];
  short8 bh1 = *(const short8*)&Bph[s16 + 8];
  short8 bl0 = *(const short8*)&Bpl[s16];
  short8 bl1 = *(const short8*)&Bpl[s16 + 8];
  for (int k0 = 0; k0 < 512; k0 += 32) {
    __syncthreads();
    *(short8*)&Ah[sr][s16] = ah0; *(short8*)&Ah[sr][s16 + 8] = ah1;
    *(short8*)&Al[sr][s16] = al0; *(short8*)&Al[sr][s16 + 8] = al1;
    *(short8*)&Bh[sr][s16] = bh0; *(short8*)&Bh[sr][s16 + 8] = bh1;
    *(short8*)&Bl[sr][s16] = bl0; *(short8*)&Bl[sr][s16 + 8] = bl1;
    __syncthreads();
    if (k0 + 32 < 512) {
      int ko = k0 + 32 + s16;
      ah0 = *(const short8*)&Aph[ko]; ah1 = *(const short8*)&Aph[ko + 8];
      al0 = *(const short8*)&Apl[ko]; al1 = *(const short8*)&Apl[ko + 8];
      bh0 = *(const short8*)&Bph[ko]; bh1 = *(const short8*)&Bph[ko + 8];
      bl0 = *(const short8*)&Bpl[ko]; bl1 = *(const short8*)&Bpl[ko + 8];
    }
    short8 fah[4], fal[4], fbh[4], fbl[4];
#pragma unroll
    for (int m = 0; m < 4; ++m) {
      fah[m] = *(const short8*)&Ah[wr * 64 + m * 16 + lx][lg * 8];
      fal[m] = *(const short8*)&Al[wr * 64 + m * 16 + lx][lg * 8];
    }
#pragma unroll
    for (int n = 0; n < 4; ++n) {
      fbh[n] = *(const short8*)&Bh[wc * 64 + n * 16 + lx][lg * 8];
      fbl[n] = *(const short8*)&Bl[wc * 64 + n * 16 + lx][lg * 8];
    }
#pragma unroll
    for (int m = 0; m < 4; ++m)
#pragma unroll
      for (int n = 0; n < 4; ++n) {
        acc[m][n] = __builtin_amdgcn_mfma_f32_16x16x32_bf16(fah[m], fbh[n], acc[m][n], 0, 0, 0);
        acc[m][n] = __builtin_amdgcn_mfma_f32_16x16x32_bf16(fal[m], fbh[n], acc[m][n], 0, 0, 0);
        acc[m][n] = __builtin_amdgcn_mfma_f32_16x16x32_bf16(fah[m], fbl[n], acc[m][n], 0, 0, 0);
      }
  }
#pragma unroll
  for (int m = 0; m < 4; ++m)
#pragma unroll
    for (int i = 0; i < 4; ++i) {
      int row = m0 + wr * 64 + m * 16 + lg * 4 + i;
#pragma unroll
      for (int n = 0; n < 4; ++n) {
        int col = n0 + wc * 64 + n * 16 + lx;
        C[(size_t)row * 512 + col] = acc[m][n][i] + bias[col];
      }
    }
}

// ---------------------------------------------------------------------------
// LayerNorm with residual + bf16 copy.
// ---------------------------------------------------------------------------
__global__ __launch_bounds__(256) void ln_res(const float* __restrict__ a,
                                              const float* __restrict__ b,
                                              const float* __restrict__ g,
                                              const float* __restrict__ beta,
                                              float* __restrict__ out,
                                              u16* __restrict__ obf) {
  int n = blockIdx.x * 4 + (threadIdx.x >> 6);
  int lane = threadIdx.x & 63;
  float v[8];
  float s = 0.f;
#pragma unroll
  for (int i = 0; i < 8; ++i) {
    int d = lane + 64 * i;
    v[i] = a[(size_t)n * D_ + d] + b[(size_t)n * D_ + d];
    s += v[i];
  }
#pragma unroll
  for (int m = 32; m; m >>= 1) s += __shfl_xor(s, m);
  float mean = s * (1.f / D_);
  float s2 = 0.f;
#pragma unroll
  for (int i = 0; i < 8; ++i) { float t = v[i] - mean; s2 += t * t; }
#pragma unroll
  for (int m = 32; m; m >>= 1) s2 += __shfl_xor(s2, m);
  float r = rsqrtf(s2 * (1.f / D_) + 1e-5f);
#pragma unroll
  for (int i = 0; i < 8; ++i) {
    int d = lane + 64 * i;
    float val = (v[i] - mean) * r * g[d] + beta[d];
    out[(size_t)n * D_ + d] = val;
    obf[(size_t)n * D_ + d] = f2bf(val);
  }
}

__global__ __launch_bounds__(256) void ln2_final(const float* __restrict__ x,
                                                 const u16* __restrict__ mp,
                                                 const float* __restrict__ g,
                                                 const float* __restrict__ beta,
                                                 float* __restrict__ out) {
  int n = blockIdx.x * 4 + (threadIdx.x >> 6);
  int lane = threadIdx.x & 63;
  float v[8];
  float s = 0.f;
#pragma unroll
  for (int i = 0; i < 8; ++i) {
    int d = lane + 64 * i;
    v[i] = x[(size_t)n * D_ + d] + bf2f(mp[(size_t)(2 * n) * D_ + d]) +
           bf2f(mp[(size_t)(2 * n + 1) * D_ + d]);
    s += v[i];
  }
#pragma unroll
  for (int m = 32; m; m >>= 1) s += __shfl_xor(s, m);
  float mean = s * (1.f / D_);
  float s2 = 0.f;
#pragma unroll
  for (int i = 0; i < 8; ++i) { float t = v[i] - mean; s2 += t * t; }
#pragma unroll
  for (int m = 32; m; m >>= 1) s2 += __shfl_xor(s2, m);
  float r = rsqrtf(s2 * (1.f / D_) + 1e-5f);
#pragma unroll
  for (int i = 0; i < 8; ++i) {
    int d = lane + 64 * i;
    out[(size_t)n * D_ + d] = (v[i] - mean) * r * g[d] + beta[d];
  }
}

// ---------------------------------------------------------------------------
// Gate phase A: per-token top-2 computation. NO atomics.
// ---------------------------------------------------------------------------
__global__ __launch_bounds__(256) void gate_compute(const float* __restrict__ x,
                                                    const float* __restrict__ Wg,
                                                    float* __restrict__ gp,
                                                    int* __restrict__ tope) {
  int n = blockIdx.x * 4 + (threadIdx.x >> 6);
  int lane = threadIdx.x & 63;
  float p[E_] = {};
  for (int d = lane; d < D_; d += 64) {
    float xv = x[(size_t)n * D_ + d];
    const float* wr = &Wg[(size_t)d * E_];
#pragma unroll
    for (int e = 0; e < E_; ++e) p[e] += xv * wr[e];
  }
#pragma unroll
  for (int e = 0; e < E_; ++e)
#pragma unroll
    for (int m = 32; m; m >>= 1) p[e] += __shfl_xor(p[e], m);
  if (lane == 0) {
    float mx = p[0];
#pragma unroll
    for (int e = 1; e < E_; ++e) mx = fmaxf(mx, p[e]);
    float q[E_];
#pragma unroll
    for (int e = 0; e < E_; ++e) q[e] = expf(p[e] - mx);
    int e1 = 0;
#pragma unroll
    for (int e = 1; e < E_; ++e) if (q[e] > q[e1]) e1 = e;
    int e2 = (e1 == 0) ? 1 : 0;
#pragma unroll
    for (int e = 0; e < E_; ++e) if (e != e1 && q[e] > q[e2]) e2 = e;
    float denom = q[e1] + q[e2];
    gp[n * 2] = q[e1] / denom;
    gp[n * 2 + 1] = q[e2] / denom;
    tope[n] = e1 | (e2 << 8);
  }
}

// ---------------------------------------------------------------------------
// Gate phase B: per-expert ordered compaction. One block per expert.
// ---------------------------------------------------------------------------
__global__ __launch_bounds__(256) void route_build(const int* __restrict__ tope,
                                                   int* __restrict__ cnt,
                                                   int* __restrict__ lst) {
  int e = blockIdx.x;
  __shared__ int wsum[4];
  __shared__ int basem;
  int tid = threadIdx.x;
  int w = tid >> 6, lane = tid & 63;
  if (tid == 0) basem = 0;
  __syncthreads();
  for (int c0 = 0; c0 < N_; c0 += 256) {
    int n = c0 + tid;
    int te = tope[n];
    int e1 = te & 0xff, e2 = (te >> 8) & 0xff;
    bool m2 = (e2 == e);
    bool flag = (e1 == e) || m2;
    unsigned long long mask = __ballot(flag);
    int wpre = __popcll(mask & ((1ull << lane) - 1ull));
    if (lane == 0) wsum[w] = __popcll(mask);
    __syncthreads();
    int woff = 0;
    for (int i = 0; i < w; ++i) woff += wsum[i];
    int total = wsum[0] + wsum[1] + wsum[2] + wsum[3];
    if (flag) lst[e * N_ + basem + woff + wpre] = n * 2 + (m2 ? 1 : 0);
    __syncthreads();
    if (tid == 0) basem += total;
    __syncthreads();
  }
  if (tid == 0) cnt[e] = basem;
}

// ---------------------------------------------------------------------------
// bf16 MFMA MoE GEMM, 64x128 tile, BK=32, 4 waves (each 64x32 out).
// Flat grid, expert = blockIdx & 7 -> expert pinned to one XCD (L2 locality).
// Register prefetch of next K-step hides L2 latency under LDS-read+MFMA.
// ---------------------------------------------------------------------------
template <int MODE>
__global__ __launch_bounds__(256) void moe_mfma(const u16* __restrict__ Abase,
                                                const u16* __restrict__ Wt,
                                                const float* __restrict__ bias,
                                                const float* __restrict__ gp,
                                                u16* __restrict__ outp,
                                                const int* __restrict__ cnt,
                                                const int* __restrict__ lst) {
  constexpr int K  = MODE ? 1024 : 512;
  constexpr int Nn = MODE ? 512 : 1024;
  constexpr int NT = Nn / 128;          // n-tiles: 8 (moe1) / 4 (moe2)
  constexpr int NI = K / 32;            // K-steps: 16 / 32
  int fidx = blockIdx.x;
  int e = fidx & 7;                     // expert == XCD (id % 8 round-robin)
  int r = fidx >> 3;
  int nt = r % NT;
  int mt = r / NT;                      // [0, 64)
  int c = cnt[e];
  int m0 = mt * 64;
  if (m0 >= c) return;
  int off = 0;
#pragma unroll
  for (int i = 0; i < E_; ++i) if (i < e) off += cnt[i];
  int n0 = nt * 128;
  __shared__ u16 As[64][40];
  __shared__ u16 Bs[128][40];
  int tid = threadIdx.x;
  int w = tid >> 6, l = tid & 63;
  int lg = l >> 4, lx = l & 15;
  // staging maps
  int arow = tid >> 2, aseg = (tid & 3) * 8;    // A: 64 rows x 32k, 8 el/thread
  int brow = tid >> 1, bseg = (tid & 1) * 16;   // B: 128 rows x 32k, 16 el/thread
  int ar = m0 + arow; if (ar >= c) ar = c - 1;
  const u16* Ap;
  if (MODE == 0) Ap = Abase + (size_t)(lst[e * N_ + ar] >> 1) * 512 + aseg;
  else           Ap = Abase + (size_t)(off + ar) * 1024 + aseg;
  const u16* Bp = Wt + (size_t)e * K * Nn + (size_t)(n0 + brow) * K + bseg;

  f32x4 acc[4][2];
#pragma unroll
  for (int m = 0; m < 4; ++m)
#pragma unroll
    for (int n = 0; n < 2; ++n) acc[m][n] = (f32x4){0.f, 0.f, 0.f, 0.f};

  short8 pa  = *(const short8*)&Ap[0];
  short8 pb0 = *(const short8*)&Bp[0];
  short8 pb1 = *(const short8*)&Bp[8];
  for (int kk = 0; kk < NI; ++kk) {
    __syncthreads();
    *(short8*)&As[arow][aseg] = pa;
    *(short8*)&Bs[brow][bseg] = pb0;
    *(short8*)&Bs[brow][bseg + 8] = pb1;
    __syncthreads();
    if (kk + 1 < NI) {
      int ko = (kk + 1) * 32;
      pa  = *(const short8*)&Ap[ko];
      pb0 = *(const short8*)&Bp[ko];
      pb1 = *(const short8*)&Bp[ko + 8];
    }
    short8 af[4], bf[2];
#pragma unroll
    for (int m = 0; m < 4; ++m)
      af[m] = *(const short8*)&As[m * 16 + lx][lg * 8];
#pragma unroll
    for (int n = 0; n < 2; ++n)
      bf[n] = *(const short8*)&Bs[w * 32 + n * 16 + lx][lg * 8];
#pragma unroll
    for (int m = 0; m < 4; ++m)
#pragma unroll
      for (int n = 0; n < 2; ++n)
        acc[m][n] = __builtin_amdgcn_mfma_f32_16x16x32_bf16(af[m], bf[n], acc[m][n], 0, 0, 0);
  }
#pragma unroll
  for (int m = 0; m < 4; ++m)
#pragma unroll
    for (int i = 0; i < 4; ++i) {
      int rr = m0 + m * 16 + lg * 4 + i;
      if (rr < c) {
#pragma unroll
        for (int n = 0; n < 2; ++n) {
          int col = n0 + w * 32 + n * 16 + lx;
          float val = acc[m][n][i] + bias[e * Nn + col];
          if (MODE == 0) {
            outp[(size_t)(off + rr) * 1024 + col] = f2bf(fmaxf(val, 0.f));
          } else {
            int p = lst[e * N_ + rr];
            outp[(size_t)p * 512 + col] = f2bf(gp[p] * val);
          }
        }
      }
    }
}

// ---------------------------------------------------------------------------
extern "C" void kernel_launch(void* const* d_in, const int* in_sizes, int n_in,
                              void* d_out, int out_size, void* d_ws, size_t ws_size,
                              hipStream_t stream) {
  const float* src  = (const float*)d_in[0];
  const float* cosb = (const float*)d_in[1];
  const float* sinb = (const float*)d_in[2];
  const float* Wq   = (const float*)d_in[3];
  const float* bq   = (const float*)d_in[4];
  const float* Wk   = (const float*)d_in[5];
  const float* bk   = (const float*)d_in[6];
  const float* Wv   = (const float*)d_in[7];
  const float* bv   = (const float*)d_in[8];
  const float* Wo   = (const float*)d_in[9];
  const float* bo   = (const float*)d_in[10];
  const float* ln1g = (const float*)d_in[11];
  const float* ln1b = (const float*)d_in[12];
  const float* ln2g = (const float*)d_in[13];
  const float* ln2b = (const float*)d_in[14];
  const float* Wg   = (const float*)d_in[15];
  const float* W1   = (const float*)d_in[16];
  const float* B1   = (const float*)d_in[17];
  const float* W2   = (const float*)d_in[18];
  const float* B2   = (const float*)d_in[19];
  float* out = (float*)d_out;
  char* wsb = (char*)d_ws;

  const size_t MB1 = 1u << 20;
  u16* sh   = (u16*)(wsb + 0 * MB1);      // src hi  [0,4M)   ; later ch, then mp
  u16* sl   = (u16*)(wsb + 4 * MB1);      // src lo  [4,8M)   ; later cl
  u16* qhb  = (u16*)(wsb + 8 * MB1);      // [8,12M)          ; later hbf part
  u16* qlb  = (u16*)(wsb + 12 * MB1);
  u16* khb  = (u16*)(wsb + 16 * MB1);
  u16* klb  = (u16*)(wsb + 20 * MB1);
  u16* vbuf = (u16*)(wsb + 24 * MB1);     // [24,28M)
  u16* poh  = (u16*)(wsb + 28 * MB1);     // [28,36M) attn partial hi ; later aob f32, then W2t
  u16* pol  = (u16*)(wsb + 36 * MB1);     // [36,44M) attn partial lo ; later xb f32
  float* pml = (float*)(wsb + 44 * MB1);  // [44,44.5M)       ; later xbf
  float* aob = (float*)(wsb + 28 * MB1);  // [28,36M)
  float* xb  = (float*)(wsb + 36 * MB1);  // [36,44M)
  u16* xbf   = (u16*)(wsb + 44 * MB1);    // [44,48M)
  u16* Wqkv_hi = (u16*)(wsb + 48 * MB1);              // 1.5MB
  u16* Wqkv_lo = (u16*)(wsb + 48 * MB1 + 1572864);    // 1.5MB
  u16* Wo_hi   = (u16*)(wsb + 48 * MB1 + 3145728);    // 0.5MB
  u16* Wo_lo   = (u16*)(wsb + 48 * MB1 + 3670016);    // 0.5MB
  u16* W1t     = (u16*)(wsb + 52 * MB1);  // [52,60M)
  u16* W2t     = (u16*)(wsb + 28 * MB1);  // [28,36M) — written after ln_res (aob dead)
  float* gpb   = (float*)(wsb + 60 * MB1);                 // 32 KB
  int* cnt     = (int*)(wsb + 60 * MB1 + 32768);           // 64 B
  int* lst     = (int*)(wsb + 60 * MB1 + 32768 + 64);      // 128 KB
  int* tope    = (int*)(wsb + 60 * MB1 + 32768 + 64 + 131072);  // 16 KB
  u16* ch  = sh;                          // ctx hi aliases src-split (dead)
  u16* cl  = sl;
  u16* hbf = (u16*)(wsb + 8 * MB1);       // [8,24M) aliases q/k (dead after attn)
  u16* mp  = (u16*)(wsb + 0 * MB1);       // [0,8M)  aliases ch/cl (dead after wo)

  dim3 blk(256);
  src_split<<<dim3(1024), blk, 0, stream>>>(src, sh, sl);
  wsplit_t<<<dim3(8, 8), blk, 0, stream>>>(Wq, Wqkv_hi, Wqkv_lo, 512, 512);
  wsplit_t<<<dim3(8, 8), blk, 0, stream>>>(Wk, Wqkv_hi + 512 * 512, Wqkv_lo + 512 * 512, 512, 512);
  wsplit_t<<<dim3(8, 8), blk, 0, stream>>>(Wv, Wqkv_hi + 1024 * 512, Wqkv_lo + 1024 * 512, 512, 512);
  wsplit_t<<<dim3(8, 8), blk, 0, stream>>>(Wo, Wo_hi, Wo_lo, 512, 512);
  // QKV + RoPE fused (split-bf16, f32-grade)
  qkv_mfma<<<dim3(32, 12), blk, 0, stream>>>(sh, sl, Wqkv_hi, Wqkv_lo, bq, bk, bv,
                                             cosb, sinb, qhb, qlb, khb, klb, vbuf);
  // Attention, KV-split=2, XCD-pinned slabs + merge
  attn_mfma2<<<dim3(1024), blk, 0, stream>>>(qhb, qlb, khb, klb, vbuf, poh, pol, pml);
  merge_attn2<<<dim3(8192), blk, 0, stream>>>(poh, pol, pml, ch, cl);
  // Wo projection (split-bf16)
  wo_mfma<<<dim3(32, 4), blk, 0, stream>>>(ch, cl, Wo_hi, Wo_lo, bo, aob);
  // LN1 (+bf16 copy)
  ln_res<<<dim3(1024), blk, 0, stream>>>(src, aob, ln1g, ln1b, xb, xbf);
  // MoE weight transposes BEFORE the expert GEMMs (no L2 pollution between them)
  wtrans<<<dim3(8, 16, 8), blk, 0, stream>>>(W2, W2t, 1024, 512);
  wtrans<<<dim3(16, 8, 8), blk, 0, stream>>>(W1, W1t, 512, 1024);
  // Gate (atomic-free) + ordered routing
  gate_compute<<<dim3(1024), blk, 0, stream>>>(xb, Wg, gpb, tope);
  route_build<<<dim3(8), blk, 0, stream>>>(tope, cnt, lst);
  // Sparse MoE expert GEMMs — expert pinned to XCD via flat-grid id&7
  moe_mfma<0><<<dim3(8 * 8 * 64), blk, 0, stream>>>(xbf, W1t, B1, gpb, hbf, cnt, lst);
  moe_mfma<1><<<dim3(8 * 4 * 64), blk, 0, stream>>>(hbf, W2t, B2, gpb, mp, cnt, lst);
  ln2_final<<<dim3(1024), blk, 0, stream>>>(xb, mp, ln2g, ln2b, out);
}

// Round 9
// 237.799 us; speedup vs baseline: 4.9253x; 1.0559x over previous
//
#include <hip/hip_runtime.h>
#include <math.h>

// Shapes (fixed)
#define S_  2048
#define B_  2
#define D_  512
#define H_  8
#define DH_ 64
#define E_  8
#define F_  1024
#define N_  4096   // S_*B_
#define NPAIR_ 8192

typedef __attribute__((ext_vector_type(4))) float f32x4;
typedef __attribute__((ext_vector_type(8))) short short8;
typedef unsigned short u16;

__device__ __forceinline__ u16 f2bf(float f) {
  unsigned u = __builtin_bit_cast(unsigned, f);
  u += 0x7fffu + ((u >> 16) & 1u);
  return (u16)(u >> 16);
}
__device__ __forceinline__ float bf2f(u16 h) {
  unsigned u = ((unsigned)h) << 16;
  return __builtin_bit_cast(float, u);
}

// ---------------------------------------------------------------------------
// src -> split bf16 (hi, lo). 2M elements, 8/thread.
// ---------------------------------------------------------------------------
__global__ __launch_bounds__(256) void src_split(const float* __restrict__ in,
                                                 u16* __restrict__ hi,
                                                 u16* __restrict__ lo) {
  size_t i = ((size_t)blockIdx.x * 256 + threadIdx.x) * 8;
  float f[8];
  *(float4*)&f[0] = *(const float4*)&in[i];
  *(float4*)&f[4] = *(const float4*)&in[i + 4];
  short8 h, l;
#pragma unroll
  for (int j = 0; j < 8; ++j) {
    u16 a = f2bf(f[j]);
    h[j] = (short)a;
    l[j] = (short)f2bf(f[j] - bf2f(a));
  }
  *(short8*)&hi[i] = h;
  *(short8*)&lo[i] = l;
}

// ---------------------------------------------------------------------------
// Weight transpose + split: Whi/Wlo[n][k] = split(W[k][n]). W is [K][Nn].
// ---------------------------------------------------------------------------
__global__ __launch_bounds__(256) void wsplit_t(const float* __restrict__ W,
                                                u16* __restrict__ Whi,
                                                u16* __restrict__ Wlo,
                                                int Nn, int K) {
  __shared__ u16 Th[64][72];
  __shared__ u16 Tl[64][72];
  int kb = blockIdx.y * 64, nb = blockIdx.x * 64;
  int r = threadIdx.x >> 2, c0 = (threadIdx.x & 3) * 16;
  const float* wp = &W[(size_t)(kb + r) * Nn + nb + c0];
#pragma unroll
  for (int c = 0; c < 16; c += 4) {
    float4 t = *(const float4*)&wp[c];
    float f[4] = {t.x, t.y, t.z, t.w};
#pragma unroll
    for (int j = 0; j < 4; ++j) {
      u16 a = f2bf(f[j]);
      Th[r][c0 + c + j] = a;
      Tl[r][c0 + c + j] = f2bf(f[j] - bf2f(a));
    }
  }
  __syncthreads();
  short8 h0, h1, l0, l1;
#pragma unroll
  for (int j = 0; j < 8; ++j) {
    h0[j] = (short)Th[c0 + j][r];     h1[j] = (short)Th[c0 + 8 + j][r];
    l0[j] = (short)Tl[c0 + j][r];     l1[j] = (short)Tl[c0 + 8 + j][r];
  }
  size_t ob = (size_t)(nb + r) * K + kb + c0;
  *(short8*)&Whi[ob] = h0;  *(short8*)&Whi[ob + 8] = h1;
  *(short8*)&Wlo[ob] = l0;  *(short8*)&Wlo[ob + 8] = l1;
}

// ---------------------------------------------------------------------------
// Plain bf16 weight transpose for MoE (W1, W2).
// ---------------------------------------------------------------------------
__global__ __launch_bounds__(256) void wtrans(const float* __restrict__ W,
                                              u16* __restrict__ Wt,
                                              int K, int Nn) {
  size_t eo = (size_t)blockIdx.z * K * Nn;
  __shared__ u16 T[64][72];
  int kb = blockIdx.y * 64, nb = blockIdx.x * 64;
  int r = threadIdx.x >> 2, c0 = (threadIdx.x & 3) * 16;
  const float* wp = &W[eo + (size_t)(kb + r) * Nn + nb + c0];
#pragma unroll
  for (int c = 0; c < 16; c += 4) {
    float4 t = *(const float4*)&wp[c];
    T[r][c0 + c + 0] = f2bf(t.x);
    T[r][c0 + c + 1] = f2bf(t.y);
    T[r][c0 + c + 2] = f2bf(t.z);
    T[r][c0 + c + 3] = f2bf(t.w);
  }
  __syncthreads();
  short8 s0, s1;
#pragma unroll
  for (int j = 0; j < 8; ++j) {
    s0[j] = (short)T[c0 + j][r];
    s1[j] = (short)T[c0 + 8 + j][r];
  }
  *(short8*)&Wt[eo + (size_t)(nb + r) * K + kb + c0] = s0;
  *(short8*)&Wt[eo + (size_t)(nb + r) * K + kb + c0 + 8] = s1;
}

// ---------------------------------------------------------------------------
// Fused QKV split-bf16 MFMA GEMM + RoPE. M=4096, N=1536, K=512.
// Register prefetch of next K-step (async-stage split).
// ---------------------------------------------------------------------------
__global__ __launch_bounds__(256) void qkv_mfma(const u16* __restrict__ Ah_g,
                                                const u16* __restrict__ Al_g,
                                                const u16* __restrict__ Bh_g,
                                                const u16* __restrict__ Bl_g,
                                                const float* __restrict__ bq,
                                                const float* __restrict__ bk,
                                                const float* __restrict__ bv,
                                                const float* __restrict__ cosb,
                                                const float* __restrict__ sinb,
                                                u16* __restrict__ qh, u16* __restrict__ ql,
                                                u16* __restrict__ kh, u16* __restrict__ kl,
                                                u16* __restrict__ vb) {
  __shared__ u16 Ah[128][40], Al[128][40], Bh[128][40], Bl[128][40];
  int tid = threadIdx.x;
  int w = tid >> 6, l = tid & 63;
  int wr = w >> 1, wc = w & 1;
  int lg = l >> 4, lx = l & 15;
  int m0 = blockIdx.x * 128, n0 = blockIdx.y * 128;
  int sr = tid >> 1, s16 = (tid & 1) * 16;
  const u16* Aph = Ah_g + (size_t)(m0 + sr) * 512;
  const u16* Apl = Al_g + (size_t)(m0 + sr) * 512;
  const u16* Bph = Bh_g + (size_t)(n0 + sr) * 512;
  const u16* Bpl = Bl_g + (size_t)(n0 + sr) * 512;
  f32x4 acc[4][4];
#pragma unroll
  for (int m = 0; m < 4; ++m)
#pragma unroll
    for (int n = 0; n < 4; ++n) acc[m][n] = (f32x4){0.f, 0.f, 0.f, 0.f};
  short8 ah0 = *(const short8*)&Aph[s16];
  short8 ah1 = *(const short8*)&Aph[s16 + 8];
  short8 al0 = *(const short8*)&Apl[s16];
  short8 al1 = *(const short8*)&Apl[s16 + 8];
  short8 bh0 = *(const short8*)&Bph[s16];
  short8 bh1 = *(const short8*)&Bph[s16 + 8];
  short8 bl0 = *(const short8*)&Bpl[s16];
  short8 bl1 = *(const short8*)&Bpl[s16 + 8];
  for (int k0 = 0; k0 < 512; k0 += 32) {
    __syncthreads();
    *(short8*)&Ah[sr][s16] = ah0; *(short8*)&Ah[sr][s16 + 8] = ah1;
    *(short8*)&Al[sr][s16] = al0; *(short8*)&Al[sr][s16 + 8] = al1;
    *(short8*)&Bh[sr][s16] = bh0; *(short8*)&Bh[sr][s16 + 8] = bh1;
    *(short8*)&Bl[sr][s16] = bl0; *(short8*)&Bl[sr][s16 + 8] = bl1;
    __syncthreads();
    if (k0 + 32 < 512) {                // prefetch next K-step under compute
      int ko = k0 + 32 + s16;
      ah0 = *(const short8*)&Aph[ko]; ah1 = *(const short8*)&Aph[ko + 8];
      al0 = *(const short8*)&Apl[ko]; al1 = *(const short8*)&Apl[ko + 8];
      bh0 = *(const short8*)&Bph[ko]; bh1 = *(const short8*)&Bph[ko + 8];
      bl0 = *(const short8*)&Bpl[ko]; bl1 = *(const short8*)&Bpl[ko + 8];
    }
    short8 fah[4], fal[4], fbh[4], fbl[4];
#pragma unroll
    for (int m = 0; m < 4; ++m) {
      fah[m] = *(const short8*)&Ah[wr * 64 + m * 16 + lx][lg * 8];
      fal[m] = *(const short8*)&Al[wr * 64 + m * 16 + lx][lg * 8];
    }
#pragma unroll
    for (int n = 0; n < 4; ++n) {
      fbh[n] = *(const short8*)&Bh[wc * 64 + n * 16 + lx][lg * 8];
      fbl[n] = *(const short8*)&Bl[wc * 64 + n * 16 + lx][lg * 8];
    }
#pragma unroll
    for (int m = 0; m < 4; ++m)
#pragma unroll
      for (int n = 0; n < 4; ++n) {
        acc[m][n] = __builtin_amdgcn_mfma_f32_16x16x32_bf16(fah[m], fbh[n], acc[m][n], 0, 0, 0);
        acc[m][n] = __builtin_amdgcn_mfma_f32_16x16x32_bf16(fal[m], fbh[n], acc[m][n], 0, 0, 0);
        acc[m][n] = __builtin_amdgcn_mfma_f32_16x16x32_bf16(fah[m], fbl[n], acc[m][n], 0, 0, 0);
      }
  }
  // ---- epilogue ----
  int tcolbase = n0 + wc * 64;
  int tsel = tcolbase >> 9;             // 0=q, 1=k, 2=v
  int hbase = tcolbase & 511;
  const float* bias = (tsel == 0) ? bq : (tsel == 1) ? bk : bv;
  if (tsel == 2) {
#pragma unroll
    for (int m = 0; m < 4; ++m)
#pragma unroll
      for (int i = 0; i < 4; ++i) {
        int row = m0 + wr * 64 + m * 16 + lg * 4 + i;
#pragma unroll
        for (int n = 0; n < 4; ++n) {
          int col = hbase + n * 16 + lx;
          vb[(size_t)row * 512 + col] = f2bf(acc[m][n][i] + bias[col]);
        }
      }
  } else {
    u16* oh = tsel ? kh : qh;
    u16* ol = tsel ? kl : ql;
    float qsc = tsel ? 1.f : 0.125f;
#pragma unroll
    for (int m = 0; m < 4; ++m)
#pragma unroll
      for (int i = 0; i < 4; ++i) {
        int row = m0 + wr * 64 + m * 16 + lg * 4 + i;
        int s = row >> 1;
#pragma unroll
        for (int n = 0; n < 2; ++n) {
          int dln = n * 16 + lx;
          float c  = cosb[s * 64 + dln];
          float sn = sinb[s * 64 + dln];
          float a  = acc[m][n][i]     + bias[hbase + dln];
          float b2 = acc[m][n + 2][i] + bias[hbase + dln + 32];
          float ra = (a * c - b2 * sn) * qsc;
          float rb = (b2 * c + a * sn) * qsc;
          size_t ix = (size_t)row * 512 + hbase + dln;
          u16 rah = f2bf(ra);
          oh[ix] = rah; ol[ix] = f2bf(ra - bf2f(rah));
          u16 rbh = f2bf(rb);
          oh[ix + 32] = rbh; ol[ix + 32] = f2bf(rb - bf2f(rbh));
        }
      }
  }
}

// ---------------------------------------------------------------------------
// MFMA flash attention, KV-split=2, XCD-pinned (b,h,kvh) slabs.
// SWAPPED operands: QK^T computed as mfma(K,Q) -> D[kv][q], so each lane
// holds 16 kv-scores of one q-row (q = lane&15). Softmax is in-register
// (max/sum trees) + 2 shfl_xor (16,32) across the 4 lg lanes. P packed to
// bf16 pairs, staged via tiny XOR-swizzled per-wave LDS, PV = mfma(V^T, P).
// ---------------------------------------------------------------------------
__global__ __launch_bounds__(256) void attn_mfma2(const u16* __restrict__ qh,
                                                  const u16* __restrict__ ql,
                                                  const u16* __restrict__ kh,
                                                  const u16* __restrict__ kl,
                                                  const u16* __restrict__ vbuf,
                                                  u16* __restrict__ poh,
                                                  u16* __restrict__ pol,
                                                  float* __restrict__ pml) {
  __shared__ u16 Khi[64][72];
  __shared__ u16 Klo[64][72];
  __shared__ u16 Vt[64][72];
  __shared__ unsigned P2[4][16][32];   // [wave][q=lx][kv/2, XOR-swizzled]
  int tid = threadIdx.x;
  int w = tid >> 6, l = tid & 63;
  int lg = l >> 4, lx = l & 15;
  int f = blockIdx.x;
  int xcd = f & 7, j = f >> 3;
  int slab = xcd + 8 * (j & 3);   // 0..31 : all qt of a slab share an XCD
  int qt = j >> 2;                // 0..31
  int bh = slab >> 1, kvh = slab & 1;
  int b = bh >> 3, h = bh & 7;

  short8 qfh[2], qfl[2];
  {
    int qrow = qt * 64 + w * 16 + lx;
    size_t qo = (size_t)(qrow * 2 + b) * 512 + h * 64 + lg * 8;
    qfh[0] = *(const short8*)&qh[qo];
    qfh[1] = *(const short8*)&qh[qo + 32];
    qfl[0] = *(const short8*)&ql[qo];
    qfl[1] = *(const short8*)&ql[qo + 32];
  }

  f32x4 o_acc[4];
#pragma unroll
  for (int dg = 0; dg < 4; ++dg) o_acc[dg] = (f32x4){0.f, 0.f, 0.f, 0.f};
  float m_run = -1e30f, l_run = 0.f;

  int kvr = tid >> 2, ds4 = (tid & 3) * 16;
  int kvc = tid & 63, dsg = (tid >> 6) * 16;
  int psw = (lx & 7) << 2;              // P2 bank swizzle (multiple of 4)

  // preload tile 0 into regs
  short8 rkh0, rkh1, rkl0, rkl1, rv0, rv1;
  {
    int t0 = kvh * 1024;
    size_t ko = (size_t)((t0 + kvr) * 2 + b) * 512 + h * 64 + ds4;
    rkh0 = *(const short8*)&kh[ko]; rkh1 = *(const short8*)&kh[ko + 8];
    rkl0 = *(const short8*)&kl[ko]; rkl1 = *(const short8*)&kl[ko + 8];
    size_t vo = (size_t)((t0 + kvc) * 2 + b) * 512 + h * 64 + dsg;
    rv0 = *(const short8*)&vbuf[vo]; rv1 = *(const short8*)&vbuf[vo + 8];
  }

  for (int tt = 0; tt < 1024; tt += 64) {
    __syncthreads();
    // ---- write staged tile from regs ----
    *(short8*)&Khi[kvr][ds4]     = rkh0;
    *(short8*)&Khi[kvr][ds4 + 8] = rkh1;
    *(short8*)&Klo[kvr][ds4]     = rkl0;
    *(short8*)&Klo[kvr][ds4 + 8] = rkl1;
#pragma unroll
    for (int c = 0; c < 8; ++c) {
      Vt[dsg + c][kvc] = (u16)rv0[c];
      Vt[dsg + 8 + c][kvc] = (u16)rv1[c];
    }
    __syncthreads();
    // ---- prefetch next tile (in flight during compute) ----
    if (tt + 64 < 1024) {
      int t0 = kvh * 1024 + tt + 64;
      size_t ko = (size_t)((t0 + kvr) * 2 + b) * 512 + h * 64 + ds4;
      rkh0 = *(const short8*)&kh[ko]; rkh1 = *(const short8*)&kh[ko + 8];
      rkl0 = *(const short8*)&kl[ko]; rkl1 = *(const short8*)&kl[ko + 8];
      size_t vo = (size_t)((t0 + kvc) * 2 + b) * 512 + h * 64 + dsg;
      rv0 = *(const short8*)&vbuf[vo]; rv1 = *(const short8*)&vbuf[vo + 8];
    }

    // ---- QK^T, swapped: D[kv][q], lane holds kv=16cg+4lg+i, q=lx ----
    f32x4 sc[4];
#pragma unroll
    for (int cg = 0; cg < 4; ++cg) {
      short8 kf0 = *(const short8*)&Khi[cg * 16 + lx][lg * 8];
      short8 kf1 = *(const short8*)&Khi[cg * 16 + lx][32 + lg * 8];
      short8 kg0 = *(const short8*)&Klo[cg * 16 + lx][lg * 8];
      short8 kg1 = *(const short8*)&Klo[cg * 16 + lx][32 + lg * 8];
      f32x4 a = (f32x4){0.f, 0.f, 0.f, 0.f};
      a = __builtin_amdgcn_mfma_f32_16x16x32_bf16(kf0, qfh[0], a, 0, 0, 0);
      a = __builtin_amdgcn_mfma_f32_16x16x32_bf16(kf1, qfh[1], a, 0, 0, 0);
      a = __builtin_amdgcn_mfma_f32_16x16x32_bf16(kf0, qfl[0], a, 0, 0, 0);
      a = __builtin_amdgcn_mfma_f32_16x16x32_bf16(kf1, qfl[1], a, 0, 0, 0);
      a = __builtin_amdgcn_mfma_f32_16x16x32_bf16(kg0, qfh[0], a, 0, 0, 0);
      a = __builtin_amdgcn_mfma_f32_16x16x32_bf16(kg1, qfh[1], a, 0, 0, 0);
      sc[cg] = a;
    }

    // ---- in-register softmax for q = lx ----
    float tm = sc[0][0];
#pragma unroll
    for (int cg = 0; cg < 4; ++cg)
#pragma unroll
      for (int i = 0; i < 4; ++i) tm = fmaxf(tm, sc[cg][i]);
    tm = fmaxf(tm, __shfl_xor(tm, 16));
    tm = fmaxf(tm, __shfl_xor(tm, 32));
    float mn = fmaxf(m_run, tm);
    float corr = __expf(m_run - mn);
    m_run = mn;
    float ts = 0.f;
#pragma unroll
    for (int cg = 0; cg < 4; ++cg)
#pragma unroll
      for (int i = 0; i < 4; ++i) {
        float pv = __expf(sc[cg][i] - mn);
        sc[cg][i] = pv;
        ts += pv;
      }
    ts += __shfl_xor(ts, 16);
    ts += __shfl_xor(ts, 32);
    l_run = l_run * corr + ts;
#pragma unroll
    for (int dg = 0; dg < 4; ++dg) o_acc[dg] *= corr;

    // ---- pack P to bf16 pairs, store to swizzled per-wave LDS ----
#pragma unroll
    for (int cg = 0; cg < 4; ++cg)
#pragma unroll
      for (int t = 0; t < 2; ++t) {
        unsigned dw = (unsigned)f2bf(sc[cg][2 * t]) |
                      ((unsigned)f2bf(sc[cg][2 * t + 1]) << 16);
        P2[w][lx][(8 * cg + 2 * lg + t) ^ psw] = dw;
      }
    short8 pf0 = *(const short8*)&P2[w][lx][(4 * lg) ^ psw];
    short8 pf1 = *(const short8*)&P2[w][lx][(16 + 4 * lg) ^ psw];

    // ---- PV, swapped: A=V^T frag, B=P frag -> D[d][q] ----
#pragma unroll
    for (int dg = 0; dg < 4; ++dg) {
      short8 v0 = *(const short8*)&Vt[dg * 16 + lx][lg * 8];
      short8 v1 = *(const short8*)&Vt[dg * 16 + lx][32 + lg * 8];
      o_acc[dg] = __builtin_amdgcn_mfma_f32_16x16x32_bf16(v0, pf0, o_acc[dg], 0, 0, 0);
      o_acc[dg] = __builtin_amdgcn_mfma_f32_16x16x32_bf16(v1, pf1, o_acc[dg], 0, 0, 0);
    }
  }

  // ---- epilogue: lane holds ctx^T[d=16dg+4lg+i][q=lx] ----
  {
    int qrow = qt * 64 + w * 16 + lx;
    int row2 = qrow * 2 + b;
    size_t base = (size_t)kvh * ((size_t)N_ * D_) + (size_t)row2 * 512 + h * 64;
#pragma unroll
    for (int dg = 0; dg < 4; ++dg)
#pragma unroll
      for (int i = 0; i < 4; ++i) {
        int d = dg * 16 + 4 * lg + i;
        float val = o_acc[dg][i];
        u16 hi = f2bf(val);
        poh[base + d] = hi;
        pol[base + d] = f2bf(val - bf2f(hi));
      }
    if (lg == 0) {
      int u = row2 * 8 + h;
      pml[(size_t)kvh * 65536 + u * 2 + 0] = m_run;
      pml[(size_t)kvh * 65536 + u * 2 + 1] = l_run;
    }
  }
}

// Merge the two KV halves -> split-bf16 ctx.
__global__ __launch_bounds__(256) void merge_attn2(const u16* __restrict__ poh,
                                                   const u16* __restrict__ pol,
                                                   const float* __restrict__ pml,
                                                   u16* __restrict__ ch,
                                                   u16* __restrict__ cl) {
  int u = blockIdx.x * 4 + (threadIdx.x >> 6);
  int lane = threadIdx.x & 63;
  float m0 = pml[u * 2], l0 = pml[u * 2 + 1];
  float m1 = pml[65536 + u * 2], l1 = pml[65536 + u * 2 + 1];
  float m = fmaxf(m0, m1);
  float e0 = __expf(m0 - m), e1 = __expf(m1 - m);
  float inv = 1.f / (l0 * e0 + l1 * e1);
  int n = u >> 3, h = u & 7;
  size_t base = (size_t)n * 512 + h * 64 + lane;
  const size_t PO1 = (size_t)N_ * D_;
  float v0 = bf2f(poh[base]) + bf2f(pol[base]);
  float v1 = bf2f(poh[PO1 + base]) + bf2f(pol[PO1 + base]);
  float val = (v0 * e0 + v1 * e1) * inv;
  u16 hi = f2bf(val);
  ch[base] = hi;
  cl[base] = f2bf(val - bf2f(hi));
}

// ---------------------------------------------------------------------------
// Wo projection: split-bf16 MFMA GEMM, M=4096, N=512, K=512, f32 out.
// Register prefetch of next K-step.
// ---------------------------------------------------------------------------
__global__ __launch_bounds__(256) void wo_mfma(const u16* __restrict__ Ah_g,
                                               const u16* __restrict__ Al_g,
                                               const u16* __restrict__ Bh_g,
                                               const u16* __restrict__ Bl_g,
                                               const float* __restrict__ bias,
                                               float* __restrict__ C) {
  __shared__ u16 Ah[128][40], Al[128][40], Bh[128][40], Bl[128][40];
  int tid = threadIdx.x;
  int w = tid >> 6, l = tid & 63;
  int wr = w >> 1, wc = w & 1;
  int lg = l >> 4, lx = l & 15;
  int m0 = blockIdx.x * 128, n0 = blockIdx.y * 128;
  int sr = tid >> 1, s16 = (tid & 1) * 16;
  const u16* Aph = Ah_g + (size_t)(m0 + sr) * 512;
  const u16* Apl = Al_g + (size_t)(m0 + sr) * 512;
  const u16* Bph = Bh_g + (size_t)(n0 + sr) * 512;
  const u16* Bpl = Bl_g + (size_t)(n0 + sr) * 512;
  f32x4 acc[4][4];
#pragma unroll
  for (int m = 0; m < 4; ++m)
#pragma unroll
    for (int n = 0; n < 4; ++n) acc[m][n] = (f32x4){0.f, 0.f, 0.f, 0.f};
  short8 ah0 = *(const short8*)&Aph[s16];
  short8 ah1 = *(const short8*)&Aph[s16 + 8];
  short8 al0 = *(const short8*)&Apl[s16];
  short8 al1 = *(const short8*)&Apl[s16 + 8];
  short8 bh0 = *(const short8*)&Bph[s16];
  short8 bh1 = *(const short8*)&Bph[s16 + 8];
  short8 bl0 = *(const short8*)&Bpl[s16];
  short8 bl1 = *(const short8*)&Bpl[s16 + 8];
  for (int k0 = 0; k0 < 512; k0 += 32) {
    __syncthreads();
    *(short8*)&Ah[sr][s16] = ah0; *(short8*)&Ah[sr][s16 + 8] = ah1;
    *(short8*)&Al[sr][s16] = al0; *(short8*)&Al[sr][s16 + 8] = al1;
    *(short8*)&Bh[sr][s16] = bh0; *(short8*)&Bh[sr][s16 + 8] = bh1;
    *(short8*)&Bl[sr][s16] = bl0; *(short8*)&Bl[sr][s16 + 8] = bl1;
    __syncthreads();
    if (k0 + 32 < 512) {
      int ko = k0 + 32 + s16;
      ah0 = *(const short8*)&Aph[ko]; ah1 = *(const short8*)&Aph[ko + 8];
      al0 = *(const short8*)&Apl[ko]; al1 = *(const short8*)&Apl[ko + 8];
      bh0 = *(const short8*)&Bph[ko]; bh1 = *(const short8*)&Bph[ko + 8];
      bl0 = *(const short8*)&Bpl[ko]; bl1 = *(const short8*)&Bpl[ko + 8];
    }
    short8 fah[4], fal[4], fbh[4], fbl[4];
#pragma unroll
    for (int m = 0; m < 4; ++m) {
      fah[m] = *(const short8*)&Ah[wr * 64 + m * 16 + lx][lg * 8];
      fal[m] = *(const short8*)&Al[wr * 64 + m * 16 + lx][lg * 8];
    }
#pragma unroll
    for (int n = 0; n < 4; ++n) {
      fbh[n] = *(const short8*)&Bh[wc * 64 + n * 16 + lx][lg * 8];
      fbl[n] = *(const short8*)&Bl[wc * 64 + n * 16 + lx][lg * 8];
    }
#pragma unroll
    for (int m = 0; m < 4; ++m)
#pragma unroll
      for (int n = 0; n < 4; ++n) {
        acc[m][n] = __builtin_amdgcn_mfma_f32_16x16x32_bf16(fah[m], fbh[n], acc[m][n], 0, 0, 0);
        acc[m][n] = __builtin_amdgcn_mfma_f32_16x16x32_bf16(fal[m], fbh[n], acc[m][n], 0, 0, 0);
        acc[m][n] = __builtin_amdgcn_mfma_f32_16x16x32_bf16(fah[m], fbl[n], acc[m][n], 0, 0, 0);
      }
  }
#pragma unroll
  for (int m = 0; m < 4; ++m)
#pragma unroll
    for (int i = 0; i < 4; ++i) {
      int row = m0 + wr * 64 + m * 16 + lg * 4 + i;
#pragma unroll
      for (int n = 0; n < 4; ++n) {
        int col = n0 + wc * 64 + n * 16 + lx;
        C[(size_t)row * 512 + col] = acc[m][n][i] + bias[col];
      }
    }
}

// ---------------------------------------------------------------------------
// LayerNorm with residual + bf16 copy.
// ---------------------------------------------------------------------------
__global__ __launch_bounds__(256) void ln_res(const float* __restrict__ a,
                                              const float* __restrict__ b,
                                              const float* __restrict__ g,
                                              const float* __restrict__ beta,
                                              float* __restrict__ out,
                                              u16* __restrict__ obf) {
  int n = blockIdx.x * 4 + (threadIdx.x >> 6);
  int lane = threadIdx.x & 63;
  float v[8];
  float s = 0.f;
#pragma unroll
  for (int i = 0; i < 8; ++i) {
    int d = lane + 64 * i;
    v[i] = a[(size_t)n * D_ + d] + b[(size_t)n * D_ + d];
    s += v[i];
  }
#pragma unroll
  for (int m = 32; m; m >>= 1) s += __shfl_xor(s, m);
  float mean = s * (1.f / D_);
  float s2 = 0.f;
#pragma unroll
  for (int i = 0; i < 8; ++i) { float t = v[i] - mean; s2 += t * t; }
#pragma unroll
  for (int m = 32; m; m >>= 1) s2 += __shfl_xor(s2, m);
  float r = rsqrtf(s2 * (1.f / D_) + 1e-5f);
#pragma unroll
  for (int i = 0; i < 8; ++i) {
    int d = lane + 64 * i;
    float val = (v[i] - mean) * r * g[d] + beta[d];
    out[(size_t)n * D_ + d] = val;
    obf[(size_t)n * D_ + d] = f2bf(val);
  }
}

__global__ __launch_bounds__(256) void ln2_final(const float* __restrict__ x,
                                                 const u16* __restrict__ mp,
                                                 const float* __restrict__ g,
                                                 const float* __restrict__ beta,
                                                 float* __restrict__ out) {
  int n = blockIdx.x * 4 + (threadIdx.x >> 6);
  int lane = threadIdx.x & 63;
  float v[8];
  float s = 0.f;
#pragma unroll
  for (int i = 0; i < 8; ++i) {
    int d = lane + 64 * i;
    v[i] = x[(size_t)n * D_ + d] + bf2f(mp[(size_t)(2 * n) * D_ + d]) +
           bf2f(mp[(size_t)(2 * n + 1) * D_ + d]);
    s += v[i];
  }
#pragma unroll
  for (int m = 32; m; m >>= 1) s += __shfl_xor(s, m);
  float mean = s * (1.f / D_);
  float s2 = 0.f;
#pragma unroll
  for (int i = 0; i < 8; ++i) { float t = v[i] - mean; s2 += t * t; }
#pragma unroll
  for (int m = 32; m; m >>= 1) s2 += __shfl_xor(s2, m);
  float r = rsqrtf(s2 * (1.f / D_) + 1e-5f);
#pragma unroll
  for (int i = 0; i < 8; ++i) {
    int d = lane + 64 * i;
    out[(size_t)n * D_ + d] = (v[i] - mean) * r * g[d] + beta[d];
  }
}

// ---------------------------------------------------------------------------
// Gate phase A: per-token top-2 computation. NO atomics.
// ---------------------------------------------------------------------------
__global__ __launch_bounds__(256) void gate_compute(const float* __restrict__ x,
                                                    const float* __restrict__ Wg,
                                                    float* __restrict__ gp,
                                                    int* __restrict__ tope) {
  int n = blockIdx.x * 4 + (threadIdx.x >> 6);
  int lane = threadIdx.x & 63;
  float p[E_] = {};
  for (int d = lane; d < D_; d += 64) {
    float xv = x[(size_t)n * D_ + d];
    const float* wr = &Wg[(size_t)d * E_];
#pragma unroll
    for (int e = 0; e < E_; ++e) p[e] += xv * wr[e];
  }
#pragma unroll
  for (int e = 0; e < E_; ++e)
#pragma unroll
    for (int m = 32; m; m >>= 1) p[e] += __shfl_xor(p[e], m);
  if (lane == 0) {
    float mx = p[0];
#pragma unroll
    for (int e = 1; e < E_; ++e) mx = fmaxf(mx, p[e]);
    float q[E_];
#pragma unroll
    for (int e = 0; e < E_; ++e) q[e] = expf(p[e] - mx);
    int e1 = 0;
#pragma unroll
    for (int e = 1; e < E_; ++e) if (q[e] > q[e1]) e1 = e;
    int e2 = (e1 == 0) ? 1 : 0;
#pragma unroll
    for (int e = 0; e < E_; ++e) if (e != e1 && q[e] > q[e2]) e2 = e;
    float denom = q[e1] + q[e2];
    gp[n * 2] = q[e1] / denom;
    gp[n * 2 + 1] = q[e2] / denom;
    tope[n] = e1 | (e2 << 8);
  }
}

// ---------------------------------------------------------------------------
// Gate phase B: per-expert ordered compaction. One block per expert.
// ---------------------------------------------------------------------------
__global__ __launch_bounds__(256) void route_build(const int* __restrict__ tope,
                                                   int* __restrict__ cnt,
                                                   int* __restrict__ lst) {
  int e = blockIdx.x;
  __shared__ int wsum[4];
  __shared__ int basem;
  int tid = threadIdx.x;
  int w = tid >> 6, lane = tid & 63;
  if (tid == 0) basem = 0;
  __syncthreads();
  for (int c0 = 0; c0 < N_; c0 += 256) {
    int n = c0 + tid;
    int te = tope[n];
    int e1 = te & 0xff, e2 = (te >> 8) & 0xff;
    bool m2 = (e2 == e);
    bool flag = (e1 == e) || m2;
    unsigned long long mask = __ballot(flag);
    int wpre = __popcll(mask & ((1ull << lane) - 1ull));
    if (lane == 0) wsum[w] = __popcll(mask);
    __syncthreads();
    int woff = 0;
    for (int i = 0; i < w; ++i) woff += wsum[i];
    int total = wsum[0] + wsum[1] + wsum[2] + wsum[3];
    if (flag) lst[e * N_ + basem + woff + wpre] = n * 2 + (m2 ? 1 : 0);
    __syncthreads();
    if (tid == 0) basem += total;
    __syncthreads();
  }
  if (tid == 0) cnt[e] = basem;
}

// ---------------------------------------------------------------------------
// bf16 MFMA MoE GEMM, 64x128 tile, BK=32, 4 waves (each 64x32 out).
// Flat grid, expert = blockIdx & 7 -> expert pinned to one XCD (L2 locality).
// ---------------------------------------------------------------------------
template <int MODE>
__global__ __launch_bounds__(256) void moe_mfma(const u16* __restrict__ Abase,
                                                const u16* __restrict__ Wt,
                                                const float* __restrict__ bias,
                                                const float* __restrict__ gp,
                                                u16* __restrict__ outp,
                                                const int* __restrict__ cnt,
                                                const int* __restrict__ lst) {
  constexpr int K  = MODE ? 1024 : 512;
  constexpr int Nn = MODE ? 512 : 1024;
  constexpr int NT = Nn / 128;
  constexpr int NI = K / 32;
  int fidx = blockIdx.x;
  int e = fidx & 7;
  int r = fidx >> 3;
  int nt = r % NT;
  int mt = r / NT;
  int c = cnt[e];
  int m0 = mt * 64;
  if (m0 >= c) return;
  int off = 0;
#pragma unroll
  for (int i = 0; i < E_; ++i) if (i < e) off += cnt[i];
  int n0 = nt * 128;
  __shared__ u16 As[64][40];
  __shared__ u16 Bs[128][40];
  int tid = threadIdx.x;
  int w = tid >> 6, l = tid & 63;
  int lg = l >> 4, lx = l & 15;
  int arow = tid >> 2, aseg = (tid & 3) * 8;
  int brow = tid >> 1, bseg = (tid & 1) * 16;
  int ar = m0 + arow; if (ar >= c) ar = c - 1;
  const u16* Ap;
  if (MODE == 0) Ap = Abase + (size_t)(lst[e * N_ + ar] >> 1) * 512 + aseg;
  else           Ap = Abase + (size_t)(off + ar) * 1024 + aseg;
  const u16* Bp = Wt + (size_t)e * K * Nn + (size_t)(n0 + brow) * K + bseg;

  f32x4 acc[4][2];
#pragma unroll
  for (int m = 0; m < 4; ++m)
#pragma unroll
    for (int n = 0; n < 2; ++n) acc[m][n] = (f32x4){0.f, 0.f, 0.f, 0.f};

  short8 pa  = *(const short8*)&Ap[0];
  short8 pb0 = *(const short8*)&Bp[0];
  short8 pb1 = *(const short8*)&Bp[8];
  for (int kk = 0; kk < NI; ++kk) {
    __syncthreads();
    *(short8*)&As[arow][aseg] = pa;
    *(short8*)&Bs[brow][bseg] = pb0;
    *(short8*)&Bs[brow][bseg + 8] = pb1;
    __syncthreads();
    if (kk + 1 < NI) {
      int ko = (kk + 1) * 32;
      pa  = *(const short8*)&Ap[ko];
      pb0 = *(const short8*)&Bp[ko];
      pb1 = *(const short8*)&Bp[ko + 8];
    }
    short8 af[4], bf[2];
#pragma unroll
    for (int m = 0; m < 4; ++m)
      af[m] = *(const short8*)&As[m * 16 + lx][lg * 8];
#pragma unroll
    for (int n = 0; n < 2; ++n)
      bf[n] = *(const short8*)&Bs[w * 32 + n * 16 + lx][lg * 8];
#pragma unroll
    for (int m = 0; m < 4; ++m)
#pragma unroll
      for (int n = 0; n < 2; ++n)
        acc[m][n] = __builtin_amdgcn_mfma_f32_16x16x32_bf16(af[m], bf[n], acc[m][n], 0, 0, 0);
  }
#pragma unroll
  for (int m = 0; m < 4; ++m)
#pragma unroll
    for (int i = 0; i < 4; ++i) {
      int rr = m0 + m * 16 + lg * 4 + i;
      if (rr < c) {
#pragma unroll
        for (int n = 0; n < 2; ++n) {
          int col = n0 + w * 32 + n * 16 + lx;
          float val = acc[m][n][i] + bias[e * Nn + col];
          if (MODE == 0) {
            outp[(size_t)(off + rr) * 1024 + col] = f2bf(fmaxf(val, 0.f));
          } else {
            int p = lst[e * N_ + rr];
            outp[(size_t)p * 512 + col] = f2bf(gp[p] * val);
          }
        }
      }
    }
}

// ---------------------------------------------------------------------------
extern "C" void kernel_launch(void* const* d_in, const int* in_sizes, int n_in,
                              void* d_out, int out_size, void* d_ws, size_t ws_size,
                              hipStream_t stream) {
  const float* src  = (const float*)d_in[0];
  const float* cosb = (const float*)d_in[1];
  const float* sinb = (const float*)d_in[2];
  const float* Wq   = (const float*)d_in[3];
  const float* bq   = (const float*)d_in[4];
  const float* Wk   = (const float*)d_in[5];
  const float* bk   = (const float*)d_in[6];
  const float* Wv   = (const float*)d_in[7];
  const float* bv   = (const float*)d_in[8];
  const float* Wo   = (const float*)d_in[9];
  const float* bo   = (const float*)d_in[10];
  const float* ln1g = (const float*)d_in[11];
  const float* ln1b = (const float*)d_in[12];
  const float* ln2g = (const float*)d_in[13];
  const float* ln2b = (const float*)d_in[14];
  const float* Wg   = (const float*)d_in[15];
  const float* W1   = (const float*)d_in[16];
  const float* B1   = (const float*)d_in[17];
  const float* W2   = (const float*)d_in[18];
  const float* B2   = (const float*)d_in[19];
  float* out = (float*)d_out;
  char* wsb = (char*)d_ws;

  const size_t MB1 = 1u << 20;
  u16* sh   = (u16*)(wsb + 0 * MB1);      // src hi  [0,4M)   ; later ch, then mp
  u16* sl   = (u16*)(wsb + 4 * MB1);      // src lo  [4,8M)   ; later cl
  u16* qhb  = (u16*)(wsb + 8 * MB1);      // [8,12M)          ; later hbf part
  u16* qlb  = (u16*)(wsb + 12 * MB1);
  u16* khb  = (u16*)(wsb + 16 * MB1);
  u16* klb  = (u16*)(wsb + 20 * MB1);
  u16* vbuf = (u16*)(wsb + 24 * MB1);     // [24,28M)
  u16* poh  = (u16*)(wsb + 28 * MB1);     // [28,36M) attn partial hi ; later aob f32, then W2t
  u16* pol  = (u16*)(wsb + 36 * MB1);     // [36,44M) attn partial lo ; later xb f32
  float* pml = (float*)(wsb + 44 * MB1);  // [44,44.5M)       ; later xbf
  float* aob = (float*)(wsb + 28 * MB1);  // [28,36M)
  float* xb  = (float*)(wsb + 36 * MB1);  // [36,44M)
  u16* xbf   = (u16*)(wsb + 44 * MB1);    // [44,48M)
  u16* Wqkv_hi = (u16*)(wsb + 48 * MB1);              // 1.5MB
  u16* Wqkv_lo = (u16*)(wsb + 48 * MB1 + 1572864);    // 1.5MB
  u16* Wo_hi   = (u16*)(wsb + 48 * MB1 + 3145728);    // 0.5MB
  u16* Wo_lo   = (u16*)(wsb + 48 * MB1 + 3670016);    // 0.5MB
  u16* W1t     = (u16*)(wsb + 52 * MB1);  // [52,60M)
  u16* W2t     = (u16*)(wsb + 28 * MB1);  // [28,36M) — written after ln_res (aob dead)
  float* gpb   = (float*)(wsb + 60 * MB1);                 // 32 KB
  int* cnt     = (int*)(wsb + 60 * MB1 + 32768);           // 64 B
  int* lst     = (int*)(wsb + 60 * MB1 + 32768 + 64);      // 128 KB
  int* tope    = (int*)(wsb + 60 * MB1 + 32768 + 64 + 131072);  // 16 KB
  u16* ch  = sh;                          // ctx hi aliases src-split (dead)
  u16* cl  = sl;
  u16* hbf = (u16*)(wsb + 8 * MB1);       // [8,24M) aliases q/k (dead after attn)
  u16* mp  = (u16*)(wsb + 0 * MB1);       // [0,8M)  aliases ch/cl (dead after wo)

  dim3 blk(256);
  src_split<<<dim3(1024), blk, 0, stream>>>(src, sh, sl);
  wsplit_t<<<dim3(8, 8), blk, 0, stream>>>(Wq, Wqkv_hi, Wqkv_lo, 512, 512);
  wsplit_t<<<dim3(8, 8), blk, 0, stream>>>(Wk, Wqkv_hi + 512 * 512, Wqkv_lo + 512 * 512, 512, 512);
  wsplit_t<<<dim3(8, 8), blk, 0, stream>>>(Wv, Wqkv_hi + 1024 * 512, Wqkv_lo + 1024 * 512, 512, 512);
  wsplit_t<<<dim3(8, 8), blk, 0, stream>>>(Wo, Wo_hi, Wo_lo, 512, 512);
  // QKV + RoPE fused (split-bf16, f32-grade)
  qkv_mfma<<<dim3(32, 12), blk, 0, stream>>>(sh, sl, Wqkv_hi, Wqkv_lo, bq, bk, bv,
                                             cosb, sinb, qhb, qlb, khb, klb, vbuf);
  // Attention, KV-split=2, XCD-pinned slabs, swapped-MFMA softmax + merge
  attn_mfma2<<<dim3(1024), blk, 0, stream>>>(qhb, qlb, khb, klb, vbuf, poh, pol, pml);
  merge_attn2<<<dim3(8192), blk, 0, stream>>>(poh, pol, pml, ch, cl);
  // Wo projection (split-bf16)
  wo_mfma<<<dim3(32, 4), blk, 0, stream>>>(ch, cl, Wo_hi, Wo_lo, bo, aob);
  // LN1 (+bf16 copy)
  ln_res<<<dim3(1024), blk, 0, stream>>>(src, aob, ln1g, ln1b, xb, xbf);
  // MoE weight transposes BEFORE the expert GEMMs
  wtrans<<<dim3(8, 16, 8), blk, 0, stream>>>(W2, W2t, 1024, 512);
  wtrans<<<dim3(16, 8, 8), blk, 0, stream>>>(W1, W1t, 512, 1024);
  // Gate (atomic-free) + ordered routing
  gate_compute<<<dim3(1024), blk, 0, stream>>>(xb, Wg, gpb, tope);
  route_build<<<dim3(8), blk, 0, stream>>>(tope, cnt, lst);
  // Sparse MoE expert GEMMs — expert pinned to XCD via flat-grid id&7
  moe_mfma<0><<<dim3(8 * 8 * 64), blk, 0, stream>>>(xbf, W1t, B1, gpb, hbf, cnt, lst);
  moe_mfma<1><<<dim3(8 * 4 * 64), blk, 0, stream>>>(hbf, W2t, B2, gpb, mp, cnt, lst);
  ln2_final<<<dim3(1024), blk, 0, stream>>>(xb, mp, ln2g, ln2b, out);
}